// Round 2
// baseline (2611.614 us; speedup 1.0000x reference)
//
#include <hip/hip_runtime.h>
#include <hip/hip_bf16.h>

// Fetcher: SOC-token extraction -> [self-attn + cross-attn(img) + GELU-FFN] -> scatter-back.
// Round 1: f32 global I/O (inputs are float32 per reference), bf16 internal staging, all-VALU.

#define B_    8
#define S_    4096
#define D_    768
#define N_    1024
#define FF_   3072
#define H_    12
#define DH_   64
#define KCAP  640
#define SOC_TOK 3
#define EOS_TOK 2

typedef __hip_bfloat16 bf16;

__device__ __forceinline__ float u2f(unsigned int u){ union{unsigned int i; float f;} c; c.i=u; return c.f; }
__device__ __forceinline__ void unpack8(uint4 w, float* f){
  f[0]=u2f(w.x<<16); f[1]=u2f(w.x&0xffff0000u);
  f[2]=u2f(w.y<<16); f[3]=u2f(w.y&0xffff0000u);
  f[4]=u2f(w.z<<16); f[5]=u2f(w.z&0xffff0000u);
  f[6]=u2f(w.w<<16); f[7]=u2f(w.w&0xffff0000u);
}
__device__ __forceinline__ bf16 f2b(float x){ return __float2bfloat16(x); }
__device__ __forceinline__ float b2f(bf16 x){ return __bfloat162float(x); }

__device__ __forceinline__ void load8(const bf16* p, float* f){
  uint4 w = *(const uint4*)p; unpack8(w, f);
}
__device__ __forceinline__ void load8(const float* p, float* f){
  float4 a = *(const float4*)p; float4 b = *(const float4*)(p+4);
  f[0]=a.x; f[1]=a.y; f[2]=a.z; f[3]=a.w; f[4]=b.x; f[5]=b.y; f[6]=b.z; f[7]=b.w;
}

// ---------------- scan: soc mask (before first EOS), slots, src list, counts ----------------
__global__ __launch_bounds__(256) void scan_k(const int* __restrict__ seq,
                                              int* __restrict__ pos, int* __restrict__ src,
                                              int* __restrict__ counts){
  int b = blockIdx.x, tid = threadIdx.x;
  __shared__ int sd[256];
  __shared__ int carryE, carryS;
  if (tid==0){ carryE=0; carryS=0; }
  __syncthreads();
  for (int c=0; c<S_; c+=256){
    int s   = c + tid;
    int tok = seq[b*S_ + s];
    int isE = (tok==EOS_TOK) ? 1 : 0;
    int isS = (tok==SOC_TOK) ? 1 : 0;
    sd[tid]=isE; __syncthreads();
    for (int off=1; off<256; off<<=1){ int t_=(tid>=off)?sd[tid-off]:0; __syncthreads(); sd[tid]+=t_; __syncthreads(); }
    int eIncl = sd[tid];
    int eTot  = sd[255];
    int valid = (isS && (carryE + eIncl)==0) ? 1 : 0;   // at a SOC pos isE==0, so inclusive==exclusive
    __syncthreads();
    sd[tid]=valid; __syncthreads();
    for (int off=1; off<256; off<<=1){ int t_=(tid>=off)?sd[tid-off]:0; __syncthreads(); sd[tid]+=t_; __syncthreads(); }
    int vIncl = sd[tid];
    int vTot  = sd[255];
    if (valid){
      int slot = carryS + vIncl - 1;
      pos[b*S_ + s] = slot;
      if (slot < KCAP) src[b*KCAP + slot] = s;
    } else {
      pos[b*S_ + s] = -1;
    }
    __syncthreads();
    if (tid==0){ carryE += eTot; carryS += vTot; }
    __syncthreads();
  }
  if (tid==0) counts[b] = (carryS < KCAP) ? carryS : KCAP;
}

// ---------------- gather: X_f32[b,k,:] = hid[b,src[b,k],:] or 0 ----------------
__global__ __launch_bounds__(256) void gather_k(const float* __restrict__ hid,
                                                const int* __restrict__ src,
                                                const int* __restrict__ counts,
                                                float* __restrict__ X){
  int bk = blockIdx.x; int b = bk / KCAP; int k = bk % KCAP;
  int tid = threadIdx.x;
  int cnt = counts[b];
  float* xr = X + (size_t)bk*D_;
  if (k < cnt){
    int s = src[b*KCAP + k];
    const float* hr = hid + ((size_t)b*S_ + s)*D_;
    xr[tid] = hr[tid]; xr[tid+256] = hr[tid+256]; xr[tid+512] = hr[tid+512];
  } else {
    xr[tid] = 0.f; xr[tid+256] = 0.f; xr[tid+512] = 0.f;
  }
}

// ---------------- layernorm: T0_f32 = LN(X_f32)*g + b ----------------
__global__ __launch_bounds__(256) void ln_k(const float* __restrict__ X, float* __restrict__ Y,
                                            const float* __restrict__ g, const float* __restrict__ bt){
  int r = blockIdx.x; int tid = threadIdx.x;
  const float* xr = X + (size_t)r*D_;
  float v0=xr[tid], v1=xr[tid+256], v2=xr[tid+512];
  float s1=v0+v1+v2, s2=v0*v0+v1*v1+v2*v2;
  for (int off=32; off; off>>=1){ s1+=__shfl_xor(s1,off); s2+=__shfl_xor(s2,off); }
  __shared__ float red[8];
  __shared__ float mu_s, rs_s;
  int w=tid>>6, ln=tid&63;
  if (ln==0){ red[w]=s1; red[4+w]=s2; }
  __syncthreads();
  if (tid==0){
    float S1=red[0]+red[1]+red[2]+red[3];
    float S2=red[4]+red[5]+red[6]+red[7];
    float mu = S1*(1.f/D_);
    float var= S2*(1.f/D_) - mu*mu;
    mu_s=mu; rs_s=rsqrtf(var + 1e-5f);
  }
  __syncthreads();
  float mu=mu_s, rs=rs_s;
  float* yr = Y + (size_t)r*D_;
  yr[tid]     = (v0-mu)*rs*g[tid]     + bt[tid];
  yr[tid+256] = (v1-mu)*rs*g[tid+256] + bt[tid+256];
  yr[tid+512] = (v2-mu)*rs*g[tid+512] + bt[tid+512];
}

// ---------------- GEMM: C = A[MxK] @ B[KxN], f32 acc ----------------
// MODE 0: C_bf16 = A@B ; MODE 1: C_f32 += A@B (residual) ; MODE 2: C_bf16 = gelu(A@B)
template<int MODE, typename TA>
__global__ __launch_bounds__(256) void gemm_k(const TA* __restrict__ A, const float* __restrict__ Bw,
                                              void* __restrict__ Cp, int M, int N, int Kd){
  __shared__ float As[32][64];   // [k][m]
  __shared__ float Bs[32][64];   // [k][n]
  int nbx = N >> 6;
  int bx = blockIdx.x % nbx, by = blockIdx.x / nbx;
  int tid = threadIdx.x;
  int tx = tid & 15, ty = tid >> 4;
  float acc[4][4] = {};
  int ar = tid>>2, ac = (tid&3)*8;   // A: 64 rows x 32 k, 8 elems per thread
  int br = tid>>3, bc = (tid&7)*8;   // B: 32 rows x 64 n
  const TA*    Abase = A  + (size_t)(by*64 + ar)*Kd + ac;
  const float* Bbase = Bw + (size_t)br*N + bx*64 + bc;
  for (int kt=0; kt<Kd; kt+=32){
    float fa[8], fb[8];
    load8(Abase + kt, fa);
    load8(Bbase + (size_t)kt*N, fb);
    #pragma unroll
    for (int j=0;j<8;++j) As[ac+j][ar] = fa[j];
    #pragma unroll
    for (int j=0;j<8;++j) Bs[br][bc+j] = fb[j];
    __syncthreads();
    #pragma unroll
    for (int kk=0; kk<32; ++kk){
      float4 a4 = *(const float4*)(&As[kk][ty*4]);
      float4 b4 = *(const float4*)(&Bs[kk][tx*4]);
      float av[4]={a4.x,a4.y,a4.z,a4.w};
      float bv[4]={b4.x,b4.y,b4.z,b4.w};
      #pragma unroll
      for (int i=0;i<4;++i)
        #pragma unroll
        for (int j=0;j<4;++j) acc[i][j] += av[i]*bv[j];
    }
    __syncthreads();
  }
  int row0 = by*64 + ty*4, col0 = bx*64 + tx*4;
  if (MODE==0){
    bf16* C = (bf16*)Cp;
    #pragma unroll
    for (int i=0;i<4;++i)
      #pragma unroll
      for (int j=0;j<4;++j) C[(size_t)(row0+i)*N + col0+j] = f2b(acc[i][j]);
  } else if (MODE==1){
    float* C = (float*)Cp;
    #pragma unroll
    for (int i=0;i<4;++i)
      #pragma unroll
      for (int j=0;j<4;++j) C[(size_t)(row0+i)*N + col0+j] += acc[i][j];
  } else {
    bf16* C = (bf16*)Cp;
    #pragma unroll
    for (int i=0;i<4;++i)
      #pragma unroll
      for (int j=0;j<4;++j){
        float a = acc[i][j];
        float ge = 0.5f*a*(1.f + tanhf(0.7978845608028654f*(a + 0.044715f*a*a*a)));
        C[(size_t)(row0+i)*N + col0+j] = f2b(ge);
      }
  }
}

// ---------------- attention: 1 wave handles 8 queries of one (b,h); flash-style ----------------
template<int MASKED>
__global__ __launch_bounds__(64) void attn_k(const bf16* __restrict__ Q, const bf16* __restrict__ Kb,
                                             const bf16* __restrict__ Vb, bf16* __restrict__ O,
                                             const int* __restrict__ counts, int Lk){
  int lane = threadIdx.x;
  int bid  = blockIdx.x;
  int qt = bid % (KCAP/8);
  int h  = (bid/(KCAP/8)) % H_;
  int b  = bid/((KCAP/8)*H_);
  __shared__ float qsT[64][8];   // [d][j]
  __shared__ float plT[64][8];   // [key_in_tile][j]
  int nvalid = MASKED ? counts[b] : Lk;
  #pragma unroll
  for (int j=0;j<8;++j)
    qsT[lane][j] = b2f(Q[((size_t)(b*KCAP + qt*8 + j))*D_ + h*DH_ + lane]) * 0.125f; // 1/sqrt(64)
  __syncthreads();
  float o[8]={}, m[8], l[8]={};
  #pragma unroll
  for (int j=0;j<8;++j) m[j] = -1e30f;
  int ntiles = (nvalid + 63) >> 6;
  for (int t=0; t<ntiles; ++t){
    int key = t*64 + lane;
    float s[8];
    #pragma unroll
    for (int j=0;j<8;++j) s[j] = -1e30f;
    if (key < nvalid){
      #pragma unroll
      for (int j=0;j<8;++j) s[j] = 0.f;
      const uint4* kp = (const uint4*)(Kb + ((size_t)(b*Lk + key))*D_ + h*DH_);
      #pragma unroll
      for (int u=0; u<8; ++u){
        uint4 w = kp[u]; float f[8]; unpack8(w, f);
        #pragma unroll
        for (int dd=0; dd<8; ++dd){
          int d = u*8 + dd;
          float4 qa = *(const float4*)(&qsT[d][0]);
          float4 qb = *(const float4*)(&qsT[d][4]);
          s[0]+=qa.x*f[dd]; s[1]+=qa.y*f[dd]; s[2]+=qa.z*f[dd]; s[3]+=qa.w*f[dd];
          s[4]+=qb.x*f[dd]; s[5]+=qb.y*f[dd]; s[6]+=qb.z*f[dd]; s[7]+=qb.w*f[dd];
        }
      }
    }
    float scl[8];
    #pragma unroll
    for (int j=0;j<8;++j){
      float sj = s[j];
      float tm = sj;
      for (int off=32; off; off>>=1) tm = fmaxf(tm, __shfl_xor(tm,off));
      float nm = fmaxf(m[j], tm);
      float p  = __expf(sj - nm);           // -1e30 -> 0
      float ps = p;
      for (int off=32; off; off>>=1) ps += __shfl_xor(ps,off);
      float sc = __expf(m[j] - nm);         // first tile: exp(-huge)=0
      l[j] = l[j]*sc + ps;
      m[j] = nm;
      scl[j] = sc;
      plT[lane][j] = p;
    }
    __syncthreads();
    #pragma unroll
    for (int j=0;j<8;++j) o[j] *= scl[j];
    int lim = MASKED ? min(64, nvalid - t*64) : 64;
    for (int kk=0; kk<lim; ++kk){
      float vd = b2f(Vb[((size_t)(b*Lk + t*64 + kk))*D_ + h*DH_ + lane]);
      float4 pa = *(const float4*)(&plT[kk][0]);
      float4 pb = *(const float4*)(&plT[kk][4]);
      o[0]+=pa.x*vd; o[1]+=pa.y*vd; o[2]+=pa.z*vd; o[3]+=pa.w*vd;
      o[4]+=pb.x*vd; o[5]+=pb.y*vd; o[6]+=pb.z*vd; o[7]+=pb.w*vd;
    }
    __syncthreads();
  }
  #pragma unroll
  for (int j=0;j<8;++j)
    O[((size_t)(b*KCAP + qt*8 + j))*D_ + h*DH_ + lane] = f2b(o[j] / l[j]);
}

// ---------------- scatter back: out0 = where(soc, x[pos], hid) ----------------
__global__ __launch_bounds__(256) void scatter_k(const int* __restrict__ pos, const float* __restrict__ X,
                                                 const float* __restrict__ hid, float* __restrict__ out0){
  int bs = blockIdx.x; int tid = threadIdx.x;
  int b = bs >> 12;   // S_ = 4096
  int p = pos[bs];
  float* orow = out0 + (size_t)bs*D_;
  if (p >= 0){
    int pc = p < KCAP ? p : (KCAP-1);
    const float* xr = X + ((size_t)(b*KCAP + pc))*D_;
    orow[tid]     = xr[tid];
    orow[tid+256] = xr[tid+256];
    orow[tid+512] = xr[tid+512];
  } else {
    const float* hr = hid + (size_t)bs*D_;
    orow[tid]     = hr[tid];
    orow[tid+256] = hr[tid+256];
    orow[tid+512] = hr[tid+512];
  }
}

// ---------------- emit x (second output) ----------------
__global__ __launch_bounds__(256) void xout_k(const float* __restrict__ X, float* __restrict__ out1){
  int i = blockIdx.x*256 + threadIdx.x;
  out1[i] = X[i];
}

extern "C" void kernel_launch(void* const* d_in, const int* in_sizes, int n_in,
                              void* d_out, int out_size, void* d_ws, size_t ws_size,
                              hipStream_t stream){
  const float* img  = (const float*)d_in[0];
  const float* hid  = (const float*)d_in[1];
  const int*   seq  = (const int*)  d_in[2];
  const float* wq_s = (const float*)d_in[3];
  const float* wk_s = (const float*)d_in[4];
  const float* wv_s = (const float*)d_in[5];
  const float* wo_s = (const float*)d_in[6];
  const float* wq_c = (const float*)d_in[7];
  const float* wk_c = (const float*)d_in[8];
  const float* wv_c = (const float*)d_in[9];
  const float* wo_c = (const float*)d_in[10];
  const float* wff1 = (const float*)d_in[11];
  const float* wff2 = (const float*)d_in[12];
  const float* ln1s = (const float*)d_in[13];
  const float* ln1b = (const float*)d_in[14];
  const float* ln2s = (const float*)d_in[15];
  const float* ln2b = (const float*)d_in[16];
  const float* ln3s = (const float*)d_in[17];
  const float* ln3b = (const float*)d_in[18];
  // d_in[19] = cap (always 640; hard-coded as KCAP)

  char* ws = (char*)d_ws;
  int*   pos    = (int*)  (ws + 0);          //   131072 B
  int*   src    = (int*)  (ws + 131072);     //    20480 B
  int*   counts = (int*)  (ws + 151552);     //      256 B
  float* X      = (float*)(ws + 151808);     // 15728640 B  [B,K,D] f32 master
  float* T0     = (float*)(ws + 15880448);   // 15728640 B  LN out (f32)
  bf16*  Qb     = (bf16*) (ws + 31609088);   //  7864320 B
  bf16*  Kb     = (bf16*) (ws + 39473408);   // 12582912 B  [B,N,D] capacity
  bf16*  Vb     = (bf16*) (ws + 52056320);   // 12582912 B
  bf16*  AO     = (bf16*) (ws + 64639232);   //  7864320 B
  bf16*  MID    = Qb;                        // 31457280 B aliased over Qb..Vb (dead by FFN)

  float* out0 = (float*)d_out;
  float* out1 = out0 + (size_t)B_*S_*D_;

  const int MKD = B_*KCAP;                   // 5120 rows
  const int GQ   = (MKD/64)*(D_/64);         // 960
  const int GFF1 = (MKD/64)*(FF_/64);        // 3840
  const int GIMG = ((B_*N_)/64)*(D_/64);     // 1536
  const int GATT = B_*H_*(KCAP/8);           // 7680

  scan_k  <<<B_,       256, 0, stream>>>(seq, pos, src, counts);
  gather_k<<<B_*KCAP,  256, 0, stream>>>(hid, src, counts, X);

  // ---- self-attention block ----
  ln_k    <<<MKD, 256, 0, stream>>>(X, T0, ln1s, ln1b);
  gemm_k<0,float><<<GQ, 256, 0, stream>>>(T0, wq_s, Qb, MKD, D_, D_);
  gemm_k<0,float><<<GQ, 256, 0, stream>>>(T0, wk_s, Kb, MKD, D_, D_);
  gemm_k<0,float><<<GQ, 256, 0, stream>>>(T0, wv_s, Vb, MKD, D_, D_);
  attn_k<1><<<GATT, 64, 0, stream>>>(Qb, Kb, Vb, AO, counts, KCAP);
  gemm_k<1,bf16> <<<GQ, 256, 0, stream>>>(AO, wo_s, X, MKD, D_, D_);

  // ---- cross-attention block ----
  ln_k    <<<MKD, 256, 0, stream>>>(X, T0, ln2s, ln2b);
  gemm_k<0,float><<<GQ,   256, 0, stream>>>(T0,  wq_c, Qb, MKD,   D_, D_);
  gemm_k<0,float><<<GIMG, 256, 0, stream>>>(img, wk_c, Kb, B_*N_, D_, D_);
  gemm_k<0,float><<<GIMG, 256, 0, stream>>>(img, wv_c, Vb, B_*N_, D_, D_);
  attn_k<0><<<GATT, 64, 0, stream>>>(Qb, Kb, Vb, AO, counts, N_);
  gemm_k<1,bf16> <<<GQ, 256, 0, stream>>>(AO, wo_c, X, MKD, D_, D_);

  // ---- FFN block ----
  ln_k    <<<MKD, 256, 0, stream>>>(X, T0, ln3s, ln3b);
  gemm_k<2,float><<<GFF1, 256, 0, stream>>>(T0,  wff1, MID, MKD, FF_, D_);
  gemm_k<1,bf16> <<<GQ,   256, 0, stream>>>(MID, wff2, X,   MKD, D_,  FF_);

  // ---- outputs ----
  scatter_k<<<B_*S_, 256, 0, stream>>>(pos, X, hid, out0);
  xout_k  <<<(MKD*D_)/256, 256, 0, stream>>>(X, out1);
}

// Round 3
// 719.461 us; speedup vs baseline: 3.6300x; 3.6300x over previous
//
#include <hip/hip_runtime.h>
#include <hip/hip_bf16.h>

// Fetcher: SOC extraction -> [self-attn + cross-attn(img) + GELU-FFN] -> scatter-back.
// Round 2: MFMA (16x16x32 bf16) GEMMs + MFMA flash attention. f32 global I/O.

#define B_    8
#define S_    4096
#define D_    768
#define N_    1024
#define FF_   3072
#define H_    12
#define DH_   64
#define KCAP  640
#define SOC_TOK 3
#define EOS_TOK 2

typedef __hip_bfloat16 bf16;
typedef unsigned short u16;
typedef __attribute__((ext_vector_type(8))) short short8;
typedef __attribute__((ext_vector_type(4))) float f32x4;

__device__ __forceinline__ float u16tof(u16 s){ union{unsigned u; float f;} c; c.u = ((unsigned)s)<<16; return c.f; }
__device__ __forceinline__ u16 ftou16(float x){ union{bf16 b; u16 s;} c; c.b = __float2bfloat16(x); return c.s; }
__device__ __forceinline__ unsigned pk2(float lo, float hi){ return (unsigned)ftou16(lo) | ((unsigned)ftou16(hi)<<16); }

__device__ __forceinline__ f32x4 MFMA(short8 a, short8 b, f32x4 c){
  return __builtin_amdgcn_mfma_f32_16x16x32_bf16(a, b, c, 0, 0, 0);
}

// 8 elems -> packed bf16 uint4
__device__ __forceinline__ uint4 ld8(const u16* p){ return *(const uint4*)p; }
__device__ __forceinline__ uint4 ld8(const float* p){
  float4 a = *(const float4*)p; float4 b = *(const float4*)(p+4);
  uint4 r; r.x = pk2(a.x,a.y); r.y = pk2(a.z,a.w); r.z = pk2(b.x,b.y); r.w = pk2(b.z,b.w);
  return r;
}

// ---------------- scan ----------------
__global__ __launch_bounds__(256) void scan_k(const int* __restrict__ seq,
                                              int* __restrict__ pos, int* __restrict__ src,
                                              int* __restrict__ counts){
  int b = blockIdx.x, tid = threadIdx.x;
  __shared__ int sd[256];
  __shared__ int carryE, carryS;
  if (tid==0){ carryE=0; carryS=0; }
  __syncthreads();
  for (int c=0; c<S_; c+=256){
    int s   = c + tid;
    int tok = seq[b*S_ + s];
    int isE = (tok==EOS_TOK) ? 1 : 0;
    int isS = (tok==SOC_TOK) ? 1 : 0;
    sd[tid]=isE; __syncthreads();
    for (int off=1; off<256; off<<=1){ int t_=(tid>=off)?sd[tid-off]:0; __syncthreads(); sd[tid]+=t_; __syncthreads(); }
    int eIncl = sd[tid];
    int eTot  = sd[255];
    int valid = (isS && (carryE + eIncl)==0) ? 1 : 0;
    __syncthreads();
    sd[tid]=valid; __syncthreads();
    for (int off=1; off<256; off<<=1){ int t_=(tid>=off)?sd[tid-off]:0; __syncthreads(); sd[tid]+=t_; __syncthreads(); }
    int vIncl = sd[tid];
    int vTot  = sd[255];
    if (valid){
      int slot = carryS + vIncl - 1;
      pos[b*S_ + s] = slot;
      if (slot < KCAP) src[b*KCAP + slot] = s;
    } else {
      pos[b*S_ + s] = -1;
    }
    __syncthreads();
    if (tid==0){ carryE += eTot; carryS += vTot; }
    __syncthreads();
  }
  if (tid==0) counts[b] = (carryS < KCAP) ? carryS : KCAP;
}

// ---------------- gather ----------------
__global__ __launch_bounds__(256) void gather_k(const float* __restrict__ hid,
                                                const int* __restrict__ src,
                                                const int* __restrict__ counts,
                                                float* __restrict__ X){
  int bk = blockIdx.x; int b = bk / KCAP; int k = bk % KCAP;
  int tid = threadIdx.x;
  int cnt = counts[b];
  float* xr = X + (size_t)bk*D_;
  if (k < cnt){
    int s = src[b*KCAP + k];
    const float* hr = hid + ((size_t)b*S_ + s)*D_;
    xr[tid] = hr[tid]; xr[tid+256] = hr[tid+256]; xr[tid+512] = hr[tid+512];
  } else {
    xr[tid] = 0.f; xr[tid+256] = 0.f; xr[tid+512] = 0.f;
  }
}

// ---------------- weight transpose+cvt: in f32 [K][N] -> out bf16 [N][K] ----------------
__global__ __launch_bounds__(256) void transpose_k(const float* __restrict__ in, u16* __restrict__ out,
                                                   int K, int N){
  __shared__ float tile[32][33];
  int nbx = N >> 5;
  int bx = blockIdx.x % nbx, by = blockIdx.x / nbx;
  int tx = threadIdx.x & 31, ty = threadIdx.x >> 5;   // ty 0..7
  #pragma unroll
  for (int i=0;i<4;++i)
    tile[ty + i*8][tx] = in[(size_t)(by*32 + ty + i*8)*N + bx*32 + tx];
  __syncthreads();
  #pragma unroll
  for (int i=0;i<4;++i)
    out[(size_t)(bx*32 + ty + i*8)*K + by*32 + tx] = ftou16(tile[tx][ty + i*8]);
}

// ---------------- layernorm: T0_bf16 = LN(X_f32)*g + b ----------------
__global__ __launch_bounds__(256) void ln_k(const float* __restrict__ X, u16* __restrict__ Y,
                                            const float* __restrict__ g, const float* __restrict__ bt){
  int r = blockIdx.x; int tid = threadIdx.x;
  const float* xr = X + (size_t)r*D_;
  float v0=xr[tid], v1=xr[tid+256], v2=xr[tid+512];
  float s1=v0+v1+v2, s2=v0*v0+v1*v1+v2*v2;
  for (int off=32; off; off>>=1){ s1+=__shfl_xor(s1,off); s2+=__shfl_xor(s2,off); }
  __shared__ float red[8];
  __shared__ float mu_s, rs_s;
  int w=tid>>6, ln=tid&63;
  if (ln==0){ red[w]=s1; red[4+w]=s2; }
  __syncthreads();
  if (tid==0){
    float S1=red[0]+red[1]+red[2]+red[3];
    float S2=red[4]+red[5]+red[6]+red[7];
    float mu = S1*(1.f/D_);
    float var= S2*(1.f/D_) - mu*mu;
    mu_s=mu; rs_s=rsqrtf(var + 1e-5f);
  }
  __syncthreads();
  float mu=mu_s, rs=rs_s;
  u16* yr = Y + (size_t)r*D_;
  yr[tid]     = ftou16((v0-mu)*rs*g[tid]     + bt[tid]);
  yr[tid+256] = ftou16((v1-mu)*rs*g[tid+256] + bt[tid+256]);
  yr[tid+512] = ftou16((v2-mu)*rs*g[tid+512] + bt[tid+512]);
}

// ---------------- MFMA GEMM: C[M][N] = A[M][K] @ Bt[N][K]^T ----------------
// MODE 0: C_bf16 = A@B ; 1: C_f32 += ; 2: C_bf16 = gelu(A@B) ; 3: C_bf16 stored transposed (V^T, [b][768][Lkv])
template<int MODE, typename TA>
__global__ __launch_bounds__(256) void gemm_k(const TA* __restrict__ A, const u16* __restrict__ Bt,
                                              void* __restrict__ Cp, int M, int N, int K, int Lkv){
  __shared__ __align__(16) u16 As[64][40];
  __shared__ __align__(16) u16 Bs[128][40];
  int nbx = N >> 7;
  int bx = blockIdx.x % nbx, by = blockIdx.x / nbx;
  int tid = threadIdx.x;
  int w = tid>>6, l = tid&63, g = l>>4, c = l&15;
  int wr = w&1, wc = w>>1;
  f32x4 acc[2][4] = {};
  int arow = tid & 63,  acol = (tid>>6)*8;   // A tile 64x32: 8 elems/thread
  int brow = tid >> 1,  bcol = (tid&1)*16;   // B tile 128x32: 16 elems/thread
  const TA*  Ap = A  + (size_t)(by*64  + arow)*K + acol;
  const u16* Bp = Bt + (size_t)(bx*128 + brow)*K + bcol;
  for (int kt=0; kt<K; kt+=32){
    uint4 ua = ld8(Ap + kt);
    uint4 ub0 = *(const uint4*)(Bp + kt);
    uint4 ub1 = *(const uint4*)(Bp + kt + 8);
    *(uint4*)&As[arow][acol]   = ua;
    *(uint4*)&Bs[brow][bcol]   = ub0;
    *(uint4*)&Bs[brow][bcol+8] = ub1;
    __syncthreads();
    short8 af[2], bfr[4];
    #pragma unroll
    for (int mi=0;mi<2;++mi) af[mi]  = *(const short8*)&As[wr*32 + mi*16 + c][g*8];
    #pragma unroll
    for (int ni=0;ni<4;++ni) bfr[ni] = *(const short8*)&Bs[wc*64 + ni*16 + c][g*8];
    #pragma unroll
    for (int mi=0;mi<2;++mi)
      #pragma unroll
      for (int ni=0;ni<4;++ni) acc[mi][ni] = MFMA(af[mi], bfr[ni], acc[mi][ni]);
    __syncthreads();
  }
  int row0 = by*64 + wr*32, col0 = bx*128 + wc*64;
  #pragma unroll
  for (int mi=0;mi<2;++mi)
    #pragma unroll
    for (int ni=0;ni<4;++ni)
      #pragma unroll
      for (int r=0;r<4;++r){
        int row = row0 + mi*16 + g*4 + r;
        int col = col0 + ni*16 + c;
        float v = acc[mi][ni][r];
        if (MODE==0){
          ((u16*)Cp)[(size_t)row*N + col] = ftou16(v);
        } else if (MODE==1){
          ((float*)Cp)[(size_t)row*N + col] += v;
        } else if (MODE==2){
          float ge = 0.5f*v*(1.f + tanhf(0.7978845608028654f*(v + 0.044715f*v*v*v)));
          ((u16*)Cp)[(size_t)row*N + col] = ftou16(ge);
        } else {
          int bb = row / Lkv; int key = row - bb*Lkv;
          ((u16*)Cp)[((size_t)(bb*D_ + col))*Lkv + key] = ftou16(v);
        }
      }
}

// ---------------- MFMA flash attention ----------------
// Q [b*KCAP + q][768], K [b*Lk + key][768], Vt [b*768 + d][Lk]. 4 waves/block share (b,h).
template<int MASKED>
__global__ __launch_bounds__(256) void attn_k(const u16* __restrict__ Q, const u16* __restrict__ Kb,
                                              const u16* __restrict__ Vt, u16* __restrict__ O,
                                              const int* __restrict__ counts, int Lk){
  __shared__ __align__(16) u16 P[4][16][72];
  int tid = threadIdx.x;
  int w = tid>>6, l = tid&63, g = l>>4, c = l&15;
  int qg = blockIdx.x % 10;
  int bh = blockIdx.x / 10;
  int h = bh % H_, b = bh / H_;
  int q0 = (qg*4 + w)*16;
  int cnt = MASKED ? counts[b] : Lk;
  int nt = (cnt + 63) >> 6;

  const u16* Qrow = Q + ((size_t)(b*KCAP + q0 + c))*D_ + h*DH_;
  short8 qf0 = *(const short8*)(Qrow + g*8);
  short8 qf1 = *(const short8*)(Qrow + 32 + g*8);

  f32x4 o[4] = {};
  float m_[4], l_[4] = {};
  #pragma unroll
  for (int r=0;r<4;++r) m_[r] = -1e30f;

  for (int t=0; t<nt; ++t){
    int kb = t*64;
    // ---- QK^T for 64 keys ----
    float pv[4][4];   // [nb][r]
    #pragma unroll
    for (int nb=0;nb<4;++nb){
      const u16* Krow = Kb + ((size_t)(b*Lk + kb + nb*16 + c))*D_ + h*DH_;
      short8 k0 = *(const short8*)(Krow + g*8);
      short8 k1 = *(const short8*)(Krow + 32 + g*8);
      f32x4 z = {0.f,0.f,0.f,0.f};
      z = MFMA(qf0, k0, z);
      z = MFMA(qf1, k1, z);
      bool msk = MASKED && (kb + nb*16 + c >= cnt);
      #pragma unroll
      for (int r=0;r<4;++r) pv[nb][r] = msk ? -1e30f : z[r]*0.125f;
    }
    // ---- online softmax (row q = g*4+r lives in 16-lane group g, reg r) ----
    float tm[4], scl[4], ps[4];
    #pragma unroll
    for (int r=0;r<4;++r){
      float v = fmaxf(fmaxf(pv[0][r],pv[1][r]), fmaxf(pv[2][r],pv[3][r]));
      v = fmaxf(v, __shfl_xor(v,1)); v = fmaxf(v, __shfl_xor(v,2));
      v = fmaxf(v, __shfl_xor(v,4)); v = fmaxf(v, __shfl_xor(v,8));
      tm[r] = v;
    }
    #pragma unroll
    for (int r=0;r<4;++r){
      float nm = fmaxf(m_[r], tm[r]);
      scl[r] = __expf(m_[r] - nm);
      m_[r] = nm;
    }
    #pragma unroll
    for (int r=0;r<4;++r){
      float acc2 = 0.f;
      #pragma unroll
      for (int nb=0;nb<4;++nb){
        float e = __expf(pv[nb][r] - m_[r]);
        pv[nb][r] = e; acc2 += e;
      }
      ps[r] = acc2;
    }
    #pragma unroll
    for (int r=0;r<4;++r){
      float v = ps[r];
      v += __shfl_xor(v,1); v += __shfl_xor(v,2);
      v += __shfl_xor(v,4); v += __shfl_xor(v,8);
      l_[r] = l_[r]*scl[r] + v;
    }
    #pragma unroll
    for (int nbd=0;nbd<4;++nbd)
      #pragma unroll
      for (int r=0;r<4;++r) o[nbd][r] *= scl[r];
    // ---- P -> LDS (D-layout -> A-layout) ----
    #pragma unroll
    for (int nb=0;nb<4;++nb)
      #pragma unroll
      for (int r=0;r<4;++r) P[w][g*4 + r][nb*16 + c] = ftou16(pv[nb][r]);
    short8 pa0 = *(const short8*)&P[w][c][g*8];
    short8 pa1 = *(const short8*)&P[w][c][32 + g*8];
    // ---- PV ----
    #pragma unroll
    for (int nbd=0;nbd<4;++nbd){
      const u16* Vrow = Vt + ((size_t)(b*D_ + h*DH_ + nbd*16 + c))*Lk + kb;
      short8 v0 = *(const short8*)(Vrow + g*8);
      short8 v1 = *(const short8*)(Vrow + 32 + g*8);
      o[nbd] = MFMA(pa0, v0, o[nbd]);
      o[nbd] = MFMA(pa1, v1, o[nbd]);
    }
  }
  // ---- normalize + store ----
  #pragma unroll
  for (int nbd=0;nbd<4;++nbd)
    #pragma unroll
    for (int r=0;r<4;++r)
      O[((size_t)(b*KCAP + q0 + g*4 + r))*D_ + h*DH_ + nbd*16 + c] = ftou16(o[nbd][r] / l_[r]);
}

// ---------------- scatter back ----------------
__global__ __launch_bounds__(256) void scatter_k(const int* __restrict__ pos, const float* __restrict__ X,
                                                 const float* __restrict__ hid, float* __restrict__ out0){
  int bs = blockIdx.x; int tid = threadIdx.x;
  int b = bs >> 12;
  int p = pos[bs];
  float* orow = out0 + (size_t)bs*D_;
  if (p >= 0){
    int pc = p < KCAP ? p : (KCAP-1);
    const float* xr = X + ((size_t)(b*KCAP + pc))*D_;
    orow[tid]     = xr[tid];
    orow[tid+256] = xr[tid+256];
    orow[tid+512] = xr[tid+512];
  } else {
    const float* hr = hid + (size_t)bs*D_;
    orow[tid]     = hr[tid];
    orow[tid+256] = hr[tid+256];
    orow[tid+512] = hr[tid+512];
  }
}

__global__ __launch_bounds__(256) void xout_k(const float* __restrict__ X, float* __restrict__ out1){
  int i = blockIdx.x*256 + threadIdx.x;
  out1[i] = X[i];
}

extern "C" void kernel_launch(void* const* d_in, const int* in_sizes, int n_in,
                              void* d_out, int out_size, void* d_ws, size_t ws_size,
                              hipStream_t stream){
  const float* img  = (const float*)d_in[0];
  const float* hid  = (const float*)d_in[1];
  const int*   seq  = (const int*)  d_in[2];
  const float* W[10] = { (const float*)d_in[3], (const float*)d_in[4], (const float*)d_in[5], (const float*)d_in[6],
                         (const float*)d_in[7], (const float*)d_in[8], (const float*)d_in[9], (const float*)d_in[10],
                         (const float*)d_in[11], (const float*)d_in[12] };
  const float* ln1s = (const float*)d_in[13];
  const float* ln1b = (const float*)d_in[14];
  const float* ln2s = (const float*)d_in[15];
  const float* ln2b = (const float*)d_in[16];
  const float* ln3s = (const float*)d_in[17];
  const float* ln3b = (const float*)d_in[18];

  char* ws = (char*)d_ws;
  int*   pos    = (int*)  (ws + 0);          //   131072
  int*   src    = (int*)  (ws + 131072);     //    20480
  int*   counts = (int*)  (ws + 151552);     //      256
  float* X      = (float*)(ws + 151808);     // 15728640
  u16*   T0     = (u16*)  (ws + 15880448);   //  7864320
  u16*   Qb     = (u16*)  (ws + 23744768);   //  7864320
  u16*   Kb     = (u16*)  (ws + 31609088);   // 12582912 ([B,8192?] max 8192x768)
  u16*   Vt     = (u16*)  (ws + 44192000);   // 12582912 ([B,768,1024] max)
  u16*   AO     = (u16*)  (ws + 56774912);   //  7864320
  u16*   Wt     = (u16*)  (ws + 64639232);   // 18874368 (transposed bf16 weights) -> 83513600 total
  u16*   MID    = Qb;                        // 31457280, aliases Qb..Vt (dead during FFN)

  // transposed weight offsets (elements)
  u16* wq_st = Wt + 0ull*589824;
  u16* wk_st = Wt + 1ull*589824;
  u16* wv_st = Wt + 2ull*589824;
  u16* wo_st = Wt + 3ull*589824;
  u16* wq_ct = Wt + 4ull*589824;
  u16* wk_ct = Wt + 5ull*589824;
  u16* wv_ct = Wt + 6ull*589824;
  u16* wo_ct = Wt + 7ull*589824;
  u16* wff1t = Wt + 8ull*589824;             // [3072][768]
  u16* wff2t = wff1t + 2359296;              // [768][3072]

  float* out0 = (float*)d_out;
  float* out1 = out0 + (size_t)B_*S_*D_;

  const int MKD = B_*KCAP;   // 5120

  // weight transpose+bf16 (once per launch, ~19MB)
  for (int i=0;i<8;++i)
    transpose_k<<<(768/32)*(768/32), 256, 0, stream>>>(W[i], Wt + (size_t)i*589824, 768, 768);
  transpose_k<<<(3072/32)*(768/32), 256, 0, stream>>>(W[8], wff1t, 768, 3072);
  transpose_k<<<(768/32)*(3072/32), 256, 0, stream>>>(W[9], wff2t, 3072, 768);

  scan_k  <<<B_,      256, 0, stream>>>(seq, pos, src, counts);
  gather_k<<<B_*KCAP, 256, 0, stream>>>(hid, src, counts, X);

  const int G_MD  = (MKD/64)*(D_/128);       // 480  (M=5120, N=768)
  const int G_IMG = ((B_*N_)/64)*(D_/128);   // 768  (M=8192, N=768)
  const int G_FF1 = (MKD/64)*(FF_/128);      // 960  (M=5120, N=3072)
  const int G_ATT = B_*H_*(KCAP/64);         // 960

  // ---- self-attention block ----
  ln_k<<<MKD, 256, 0, stream>>>(X, T0, ln1s, ln1b);
  gemm_k<0,u16><<<G_MD, 256, 0, stream>>>(T0, wq_st, Qb, MKD, D_, D_, 0);
  gemm_k<0,u16><<<G_MD, 256, 0, stream>>>(T0, wk_st, Kb, MKD, D_, D_, 0);
  gemm_k<3,u16><<<G_MD, 256, 0, stream>>>(T0, wv_st, Vt, MKD, D_, D_, KCAP);
  attn_k<1><<<G_ATT, 256, 0, stream>>>(Qb, Kb, Vt, AO, counts, KCAP);
  gemm_k<1,u16><<<G_MD, 256, 0, stream>>>(AO, wo_st, X, MKD, D_, D_, 0);

  // ---- cross-attention block ----
  ln_k<<<MKD, 256, 0, stream>>>(X, T0, ln2s, ln2b);
  gemm_k<0,u16>  <<<G_MD,  256, 0, stream>>>(T0,  wq_ct, Qb, MKD,   D_, D_, 0);
  gemm_k<0,float><<<G_IMG, 256, 0, stream>>>(img, wk_ct, Kb, B_*N_, D_, D_, 0);
  gemm_k<3,float><<<G_IMG, 256, 0, stream>>>(img, wv_ct, Vt, B_*N_, D_, D_, N_);
  attn_k<0><<<G_ATT, 256, 0, stream>>>(Qb, Kb, Vt, AO, counts, N_);
  gemm_k<1,u16><<<G_MD, 256, 0, stream>>>(AO, wo_ct, X, MKD, D_, D_, 0);

  // ---- FFN block ----
  ln_k<<<MKD, 256, 0, stream>>>(X, T0, ln3s, ln3b);
  gemm_k<2,u16><<<G_FF1, 256, 0, stream>>>(T0,  wff1t, MID, MKD, FF_, D_, 0);
  gemm_k<1,u16><<<G_MD,  256, 0, stream>>>(MID, wff2t, X,   MKD, D_, FF_, 0);

  // ---- outputs ----
  scatter_k<<<B_*S_, 256, 0, stream>>>(pos, X, hid, out0);
  xout_k  <<<(MKD*D_)/256, 256, 0, stream>>>(X, out1);
}

// Round 4
// 640.808 us; speedup vs baseline: 4.0755x; 1.1227x over previous
//
#include <hip/hip_runtime.h>
#include <hip/hip_bf16.h>

// Fetcher: SOC extraction -> [self-attn + cross-attn(img) + GELU-FFN] -> scatter-back.
// Round 3: global_load_lds staged MFMA GEMM (128x128, swizzled LDS) + LDS-staged MFMA flash attn.

#define B_    8
#define S_    4096
#define D_    768
#define N_    1024
#define FF_   3072
#define H_    12
#define DH_   64
#define KCAP  640
#define SOC_TOK 3
#define EOS_TOK 2

typedef __hip_bfloat16 bf16;
typedef unsigned short u16;
typedef __attribute__((ext_vector_type(8))) short short8;
typedef __attribute__((ext_vector_type(4))) float f32x4;

__device__ __forceinline__ u16 ftou16(float x){ union{bf16 b; u16 s;} c; c.b = __float2bfloat16(x); return c.s; }
__device__ __forceinline__ unsigned pk2(float lo, float hi){ return (unsigned)ftou16(lo) | ((unsigned)ftou16(hi)<<16); }

__device__ __forceinline__ f32x4 MFMA(short8 a, short8 b, f32x4 c){
  return __builtin_amdgcn_mfma_f32_16x16x32_bf16(a, b, c, 0, 0, 0);
}

// async global->LDS, 16B per lane; LDS dest = wave-uniform base + lane*16
__device__ __forceinline__ void gld16(const void* gp, void* lp){
  __builtin_amdgcn_global_load_lds(
    reinterpret_cast<const __attribute__((address_space(1))) unsigned int*>((size_t)gp),
    reinterpret_cast<__attribute__((address_space(3))) unsigned int*>((size_t)lp),
    16, 0, 0);
}

// ---------------- scan ----------------
__global__ __launch_bounds__(256) void scan_k(const int* __restrict__ seq,
                                              int* __restrict__ pos, int* __restrict__ src,
                                              int* __restrict__ counts){
  int b = blockIdx.x, tid = threadIdx.x;
  __shared__ int sd[256];
  __shared__ int carryE, carryS;
  if (tid==0){ carryE=0; carryS=0; }
  __syncthreads();
  for (int c=0; c<S_; c+=256){
    int s   = c + tid;
    int tok = seq[b*S_ + s];
    int isE = (tok==EOS_TOK) ? 1 : 0;
    int isS = (tok==SOC_TOK) ? 1 : 0;
    sd[tid]=isE; __syncthreads();
    for (int off=1; off<256; off<<=1){ int t_=(tid>=off)?sd[tid-off]:0; __syncthreads(); sd[tid]+=t_; __syncthreads(); }
    int eIncl = sd[tid];
    int eTot  = sd[255];
    int valid = (isS && (carryE + eIncl)==0) ? 1 : 0;
    __syncthreads();
    sd[tid]=valid; __syncthreads();
    for (int off=1; off<256; off<<=1){ int t_=(tid>=off)?sd[tid-off]:0; __syncthreads(); sd[tid]+=t_; __syncthreads(); }
    int vIncl = sd[tid];
    int vTot  = sd[255];
    if (valid){
      int slot = carryS + vIncl - 1;
      pos[b*S_ + s] = slot;
      if (slot < KCAP) src[b*KCAP + slot] = s;
    } else {
      pos[b*S_ + s] = -1;
    }
    __syncthreads();
    if (tid==0){ carryE += eTot; carryS += vTot; }
    __syncthreads();
  }
  if (tid==0) counts[b] = (carryS < KCAP) ? carryS : KCAP;
}

// ---------------- gather ----------------
__global__ __launch_bounds__(256) void gather_k(const float* __restrict__ hid,
                                                const int* __restrict__ src,
                                                const int* __restrict__ counts,
                                                float* __restrict__ X){
  int bk = blockIdx.x; int b = bk / KCAP; int k = bk % KCAP;
  int tid = threadIdx.x;
  int cnt = counts[b];
  float* xr = X + (size_t)bk*D_;
  if (k < cnt){
    int s = src[b*KCAP + k];
    const float* hr = hid + ((size_t)b*S_ + s)*D_;
    xr[tid] = hr[tid]; xr[tid+256] = hr[tid+256]; xr[tid+512] = hr[tid+512];
  } else {
    xr[tid] = 0.f; xr[tid+256] = 0.f; xr[tid+512] = 0.f;
  }
}

// ---------------- weight transpose+cvt: f32 [K][N] -> bf16 [N][K] ----------------
__global__ __launch_bounds__(256) void transpose_k(const float* __restrict__ in, u16* __restrict__ out,
                                                   int K, int N){
  __shared__ float tile[32][33];
  int nbx = N >> 5;
  int bx = blockIdx.x % nbx, by = blockIdx.x / nbx;
  int tx = threadIdx.x & 31, ty = threadIdx.x >> 5;
  #pragma unroll
  for (int i=0;i<4;++i)
    tile[ty + i*8][tx] = in[(size_t)(by*32 + ty + i*8)*N + bx*32 + tx];
  __syncthreads();
  #pragma unroll
  for (int i=0;i<4;++i)
    out[(size_t)(bx*32 + ty + i*8)*K + by*32 + tx] = ftou16(tile[tx][ty + i*8]);
}

// ---------------- layernorm ----------------
__global__ __launch_bounds__(256) void ln_k(const float* __restrict__ X, u16* __restrict__ Y,
                                            const float* __restrict__ g, const float* __restrict__ bt){
  int r = blockIdx.x; int tid = threadIdx.x;
  const float* xr = X + (size_t)r*D_;
  float v0=xr[tid], v1=xr[tid+256], v2=xr[tid+512];
  float s1=v0+v1+v2, s2=v0*v0+v1*v1+v2*v2;
  for (int off=32; off; off>>=1){ s1+=__shfl_xor(s1,off); s2+=__shfl_xor(s2,off); }
  __shared__ float red[8];
  __shared__ float mu_s, rs_s;
  int w=tid>>6, ln=tid&63;
  if (ln==0){ red[w]=s1; red[4+w]=s2; }
  __syncthreads();
  if (tid==0){
    float S1=red[0]+red[1]+red[2]+red[3];
    float S2=red[4]+red[5]+red[6]+red[7];
    float mu = S1*(1.f/D_);
    float var= S2*(1.f/D_) - mu*mu;
    mu_s=mu; rs_s=rsqrtf(var + 1e-5f);
  }
  __syncthreads();
  float mu=mu_s, rs=rs_s;
  u16* yr = Y + (size_t)r*D_;
  yr[tid]     = ftou16((v0-mu)*rs*g[tid]     + bt[tid]);
  yr[tid+256] = ftou16((v1-mu)*rs*g[tid+256] + bt[tid+256]);
  yr[tid+512] = ftou16((v2-mu)*rs*g[tid+512] + bt[tid+512]);
}

// ---------------- MFMA GEMM: C[M][N] = A[M][K] @ Bt[N][K]^T, 128x128 tile ----------------
// MODE 0: C_bf16 ; 1: C_f32 += ; 2: C_bf16 = gelu ; 3: C_bf16 transposed (V^T [b][768][Lkv])
template<int MODE, typename TA>
__global__ __launch_bounds__(256) void gemm_k(const TA* __restrict__ A, const u16* __restrict__ Bt,
                                              void* __restrict__ Cp, int M, int N, int K, int Lkv){
  __shared__ __align__(16) u16 As[128*32];
  __shared__ __align__(16) u16 Bs[128*32];
  int nbx = N >> 7;
  int bx = blockIdx.x % nbx, by = blockIdx.x / nbx;
  int tid = threadIdx.x;
  int w = tid>>6, l = tid&63, g = l>>4, c = l&15;
  int wr = w&1, wc = w>>1;
  f32x4 acc[4][4] = {};
  for (int kt=0; kt<K; kt+=32){
    // ---- stage A (128x32) ----
    if constexpr (sizeof(TA)==2){
      #pragma unroll
      for (int p=0;p<2;++p){
        int row = w*32 + p*16 + (l>>2);
        int su  = (l&3) ^ ((row>>1)&3);
        gld16((const void*)(A + (size_t)(by*128+row)*K + kt + su*8), (void*)&As[(w*32+p*16)*32]);
      }
    } else {
      int row = tid>>1, half = tid&1;
      const float* ap = (const float*)A + (size_t)(by*128+row)*K + kt + half*16;
      float4 x0 = *(const float4*)ap, x1 = *(const float4*)(ap+4);
      float4 x2 = *(const float4*)(ap+8), x3 = *(const float4*)(ap+12);
      uint4 w0, w1;
      w0.x=pk2(x0.x,x0.y); w0.y=pk2(x0.z,x0.w); w0.z=pk2(x1.x,x1.y); w0.w=pk2(x1.z,x1.w);
      w1.x=pk2(x2.x,x2.y); w1.y=pk2(x2.z,x2.w); w1.z=pk2(x3.x,x3.y); w1.w=pk2(x3.z,x3.w);
      int sw = (row>>1)&3;
      *(uint4*)&As[row*32 + ((half*2  )^sw)*8] = w0;
      *(uint4*)&As[row*32 + ((half*2+1)^sw)*8] = w1;
    }
    // ---- stage B (128x32) ----
    #pragma unroll
    for (int p=0;p<2;++p){
      int row = w*32 + p*16 + (l>>2);
      int su  = (l&3) ^ ((row>>1)&3);
      gld16((const void*)(Bt + (size_t)(bx*128+row)*K + kt + su*8), (void*)&Bs[(w*32+p*16)*32]);
    }
    __syncthreads();
    short8 af[4], bfr[4];
    #pragma unroll
    for (int mi=0;mi<4;++mi){ int row = wr*64 + mi*16 + c; af[mi]  = *(const short8*)&As[row*32 + (g^((row>>1)&3))*8]; }
    #pragma unroll
    for (int ni=0;ni<4;++ni){ int row = wc*64 + ni*16 + c; bfr[ni] = *(const short8*)&Bs[row*32 + (g^((row>>1)&3))*8]; }
    #pragma unroll
    for (int mi=0;mi<4;++mi)
      #pragma unroll
      for (int ni=0;ni<4;++ni) acc[mi][ni] = MFMA(af[mi], bfr[ni], acc[mi][ni]);
    __syncthreads();
  }
  int row0 = by*128 + wr*64, col0 = bx*128 + wc*64;
  #pragma unroll
  for (int mi=0;mi<4;++mi)
    #pragma unroll
    for (int ni=0;ni<4;++ni)
      #pragma unroll
      for (int r=0;r<4;++r){
        int row = row0 + mi*16 + g*4 + r;
        int col = col0 + ni*16 + c;
        float v = acc[mi][ni][r];
        if (MODE==0){
          ((u16*)Cp)[(size_t)row*N + col] = ftou16(v);
        } else if (MODE==1){
          ((float*)Cp)[(size_t)row*N + col] += v;
        } else if (MODE==2){
          float z2 = 1.5957691216057308f*(v + 0.044715f*v*v*v);
          float e  = __expf(z2);
          float th = 1.f - 2.f/(e + 1.f);
          ((u16*)Cp)[(size_t)row*N + col] = ftou16(0.5f*v*(1.f+th));
        } else {
          int bb = row / Lkv; int key = row - bb*Lkv;
          ((u16*)Cp)[((size_t)(bb*D_ + col))*Lkv + key] = ftou16(v);
        }
      }
}

// ---------------- MFMA flash attention, LDS-staged K/V with 2-phase prefetch ----------------
// Q,K: [b*rows + r][768]; Vt: [b*768 + d][Lk]. Block = (b,h,qchunk of 128 q); 4 waves x 32 q.
template<int MASKED>
__global__ __launch_bounds__(256) void attn_k(const u16* __restrict__ Q, const u16* __restrict__ Kb,
                                              const u16* __restrict__ Vt, u16* __restrict__ O,
                                              const int* __restrict__ counts, int Lk){
  __shared__ __align__(16) u16 Ks[2][64*64];
  __shared__ __align__(16) u16 Vs[2][64*64];
  __shared__ __align__(16) u16 P[4][16][72];
  int tid = threadIdx.x;
  int w = tid>>6, l = tid&63, g = l>>4, c = l&15;
  int qc = blockIdx.x % 5;
  int bh = blockIdx.x / 5;
  int h = bh % H_, b = bh / H_;
  int q0 = qc*128 + w*32;
  int cnt = MASKED ? counts[b] : Lk;
  int nt = (cnt + 63) >> 6;

  // Q fragments: 2 m-tiles x 2 k-halves
  short8 qf[2][2];
  #pragma unroll
  for (int mi=0;mi<2;++mi){
    const u16* Qrow = Q + ((size_t)(b*KCAP + q0 + mi*16 + c))*D_ + h*DH_;
    qf[mi][0] = *(const short8*)(Qrow + g*8);
    qf[mi][1] = *(const short8*)(Qrow + 32 + g*8);
  }

  // stage helper (per wave: 8 rows x 2 parts for K and for V)
  int srow8 = (l>>3);          // 0..7
  int sunit = l&7;
  auto STAGE = [&](int buf, int kb){
    #pragma unroll
    for (int p=0;p<2;++p){
      int r0 = w*16 + p*8;
      int rowK = r0 + srow8;
      int su = sunit ^ (rowK&7);
      gld16((const void*)(Kb + ((size_t)(b*Lk + kb + rowK))*D_ + h*DH_ + su*8), (void*)&Ks[buf][r0*64]);
      gld16((const void*)(Vt + ((size_t)(b*D_ + h*DH_ + rowK))*Lk + kb + su*8), (void*)&Vs[buf][r0*64]);
    }
  };

  f32x4 o[2][4] = {};
  float m_[2][4], l_[2][4] = {};
  #pragma unroll
  for (int mi=0;mi<2;++mi)
    #pragma unroll
    for (int r=0;r<4;++r) m_[mi][r] = -1e30f;

  STAGE(0, 0);
  __syncthreads();
  int buf = 0;
  for (int t=0; t<nt; ++t){
    int kb = t*64;
    if (t+1 < nt) STAGE(buf^1, kb+64);
    // ---- K fragments from LDS ----
    short8 fr[4][2];
    #pragma unroll
    for (int nb=0;nb<4;++nb)
      #pragma unroll
      for (int kh=0;kh<2;++kh)
        fr[nb][kh] = *(const short8*)&Ks[buf][(nb*16+c)*64 + (((kh<<2)|g) ^ (c&7))*8];
    // ---- QK^T ----
    f32x4 z[2][4];
    #pragma unroll
    for (int mi=0;mi<2;++mi)
      #pragma unroll
      for (int nb=0;nb<4;++nb){
        f32x4 zz = {0.f,0.f,0.f,0.f};
        zz = MFMA(qf[mi][0], fr[nb][0], zz);
        zz = MFMA(qf[mi][1], fr[nb][1], zz);
        z[mi][nb] = zz;
      }
    float pv[2][4][4];
    #pragma unroll
    for (int nb=0;nb<4;++nb){
      bool msk = MASKED && (kb + nb*16 + c >= cnt);
      #pragma unroll
      for (int mi=0;mi<2;++mi)
        #pragma unroll
        for (int r=0;r<4;++r) pv[mi][nb][r] = msk ? -1e30f : z[mi][nb][r]*0.125f;
    }
    // ---- online softmax ----
    float scl[2][4];
    #pragma unroll
    for (int mi=0;mi<2;++mi){
      #pragma unroll
      for (int r=0;r<4;++r){
        float v = fmaxf(fmaxf(pv[mi][0][r],pv[mi][1][r]), fmaxf(pv[mi][2][r],pv[mi][3][r]));
        v = fmaxf(v, __shfl_xor(v,1)); v = fmaxf(v, __shfl_xor(v,2));
        v = fmaxf(v, __shfl_xor(v,4)); v = fmaxf(v, __shfl_xor(v,8));
        float nm = fmaxf(m_[mi][r], v);
        scl[mi][r] = __expf(m_[mi][r] - nm);
        m_[mi][r] = nm;
      }
      #pragma unroll
      for (int r=0;r<4;++r){
        float acc2 = 0.f;
        #pragma unroll
        for (int nb=0;nb<4;++nb){
          float e = __expf(pv[mi][nb][r] - m_[mi][r]);
          pv[mi][nb][r] = e; acc2 += e;
        }
        acc2 += __shfl_xor(acc2,1); acc2 += __shfl_xor(acc2,2);
        acc2 += __shfl_xor(acc2,4); acc2 += __shfl_xor(acc2,8);
        l_[mi][r] = l_[mi][r]*scl[mi][r] + acc2;
      }
      #pragma unroll
      for (int nbd=0;nbd<4;++nbd)
        #pragma unroll
        for (int r=0;r<4;++r) o[mi][nbd][r] *= scl[mi][r];
    }
    // ---- V fragments from LDS (reuse fr) ----
    #pragma unroll
    for (int nbd=0;nbd<4;++nbd)
      #pragma unroll
      for (int kh=0;kh<2;++kh)
        fr[nbd][kh] = *(const short8*)&Vs[buf][(nbd*16+c)*64 + (((kh<<2)|g) ^ (c&7))*8];
    // ---- P repack + PV per m-tile ----
    #pragma unroll
    for (int mi=0;mi<2;++mi){
      #pragma unroll
      for (int nb=0;nb<4;++nb)
        #pragma unroll
        for (int r=0;r<4;++r) P[w][g*4+r][nb*16+c] = ftou16(pv[mi][nb][r]);
      short8 pa0 = *(const short8*)&P[w][c][g*8];
      short8 pa1 = *(const short8*)&P[w][c][32 + g*8];
      #pragma unroll
      for (int nbd=0;nbd<4;++nbd){
        o[mi][nbd] = MFMA(pa0, fr[nbd][0], o[mi][nbd]);
        o[mi][nbd] = MFMA(pa1, fr[nbd][1], o[mi][nbd]);
      }
    }
    __syncthreads();
    buf ^= 1;
  }
  // ---- normalize + store ----
  #pragma unroll
  for (int mi=0;mi<2;++mi)
    #pragma unroll
    for (int nbd=0;nbd<4;++nbd)
      #pragma unroll
      for (int r=0;r<4;++r)
        O[((size_t)(b*KCAP + q0 + mi*16 + g*4 + r))*D_ + h*DH_ + nbd*16 + c] = ftou16(o[mi][nbd][r] / l_[mi][r]);
}

// ---------------- scatter back ----------------
__global__ __launch_bounds__(256) void scatter_k(const int* __restrict__ pos, const float* __restrict__ X,
                                                 const float* __restrict__ hid, float* __restrict__ out0){
  int bs = blockIdx.x; int tid = threadIdx.x;
  int b = bs >> 12;
  int p = pos[bs];
  float* orow = out0 + (size_t)bs*D_;
  if (p >= 0){
    int pc = p < KCAP ? p : (KCAP-1);
    const float* xr = X + ((size_t)(b*KCAP + pc))*D_;
    orow[tid]     = xr[tid];
    orow[tid+256] = xr[tid+256];
    orow[tid+512] = xr[tid+512];
  } else {
    const float* hr = hid + (size_t)bs*D_;
    orow[tid]     = hr[tid];
    orow[tid+256] = hr[tid+256];
    orow[tid+512] = hr[tid+512];
  }
}

__global__ __launch_bounds__(256) void xout_k(const float* __restrict__ X, float* __restrict__ out1){
  int i = blockIdx.x*256 + threadIdx.x;
  out1[i] = X[i];
}

extern "C" void kernel_launch(void* const* d_in, const int* in_sizes, int n_in,
                              void* d_out, int out_size, void* d_ws, size_t ws_size,
                              hipStream_t stream){
  const float* img  = (const float*)d_in[0];
  const float* hid  = (const float*)d_in[1];
  const int*   seq  = (const int*)  d_in[2];
  const float* W[10] = { (const float*)d_in[3], (const float*)d_in[4], (const float*)d_in[5], (const float*)d_in[6],
                         (const float*)d_in[7], (const float*)d_in[8], (const float*)d_in[9], (const float*)d_in[10],
                         (const float*)d_in[11], (const float*)d_in[12] };
  const float* ln1s = (const float*)d_in[13];
  const float* ln1b = (const float*)d_in[14];
  const float* ln2s = (const float*)d_in[15];
  const float* ln2b = (const float*)d_in[16];
  const float* ln3s = (const float*)d_in[17];
  const float* ln3b = (const float*)d_in[18];

  char* ws = (char*)d_ws;
  int*   pos    = (int*)  (ws + 0);          //   131072
  int*   src    = (int*)  (ws + 131072);     //    20480
  int*   counts = (int*)  (ws + 151552);     //      256
  float* X      = (float*)(ws + 151808);     // 15728640
  u16*   T0     = (u16*)  (ws + 15880448);   //  7864320
  u16*   Qb     = (u16*)  (ws + 23744768);   //  7864320
  u16*   Kb     = (u16*)  (ws + 31609088);   // 12582912
  u16*   Vt     = (u16*)  (ws + 44192000);   // 12582912
  u16*   AO     = (u16*)  (ws + 56774912);   //  7864320
  u16*   Wt     = (u16*)  (ws + 64639232);   // 18874368 -> total 83513600
  u16*   MID    = Qb;                        // 31457280, aliases Qb..Vt (dead during FFN)

  u16* wq_st = Wt + 0ull*589824;
  u16* wk_st = Wt + 1ull*589824;
  u16* wv_st = Wt + 2ull*589824;
  u16* wo_st = Wt + 3ull*589824;
  u16* wq_ct = Wt + 4ull*589824;
  u16* wk_ct = Wt + 5ull*589824;
  u16* wv_ct = Wt + 6ull*589824;
  u16* wo_ct = Wt + 7ull*589824;
  u16* wff1t = Wt + 8ull*589824;             // [3072][768]
  u16* wff2t = wff1t + 2359296;              // [768][3072]

  float* out0 = (float*)d_out;
  float* out1 = out0 + (size_t)B_*S_*D_;

  const int MKD = B_*KCAP;   // 5120

  for (int i=0;i<8;++i)
    transpose_k<<<(768/32)*(768/32), 256, 0, stream>>>(W[i], Wt + (size_t)i*589824, 768, 768);
  transpose_k<<<(3072/32)*(768/32), 256, 0, stream>>>(W[8], wff1t, 768, 3072);
  transpose_k<<<(768/32)*(3072/32), 256, 0, stream>>>(W[9], wff2t, 3072, 768);

  scan_k  <<<B_,      256, 0, stream>>>(seq, pos, src, counts);
  gather_k<<<B_*KCAP, 256, 0, stream>>>(hid, src, counts, X);

  const int G_MD  = (MKD/128)*(D_/128);      // 240
  const int G_IMG = ((B_*N_)/128)*(D_/128);  // 384
  const int G_FF1 = (MKD/128)*(FF_/128);     // 960
  const int G_ATT = B_*H_*5;                 // 480

  // ---- self-attention block ----
  ln_k<<<MKD, 256, 0, stream>>>(X, T0, ln1s, ln1b);
  gemm_k<0,u16><<<G_MD, 256, 0, stream>>>(T0, wq_st, Qb, MKD, D_, D_, 0);
  gemm_k<0,u16><<<G_MD, 256, 0, stream>>>(T0, wk_st, Kb, MKD, D_, D_, 0);
  gemm_k<3,u16><<<G_MD, 256, 0, stream>>>(T0, wv_st, Vt, MKD, D_, D_, KCAP);
  attn_k<1><<<G_ATT, 256, 0, stream>>>(Qb, Kb, Vt, AO, counts, KCAP);
  gemm_k<1,u16><<<G_MD, 256, 0, stream>>>(AO, wo_st, X, MKD, D_, D_, 0);

  // ---- cross-attention block ----
  ln_k<<<MKD, 256, 0, stream>>>(X, T0, ln2s, ln2b);
  gemm_k<0,u16>  <<<G_MD,  256, 0, stream>>>(T0,  wq_ct, Qb, MKD,   D_, D_, 0);
  gemm_k<0,float><<<G_IMG, 256, 0, stream>>>(img, wk_ct, Kb, B_*N_, D_, D_, 0);
  gemm_k<3,float><<<G_IMG, 256, 0, stream>>>(img, wv_ct, Vt, B_*N_, D_, D_, N_);
  attn_k<0><<<G_ATT, 256, 0, stream>>>(Qb, Kb, Vt, AO, counts, N_);
  gemm_k<1,u16><<<G_MD, 256, 0, stream>>>(AO, wo_ct, X, MKD, D_, D_, 0);

  // ---- FFN block ----
  ln_k<<<MKD, 256, 0, stream>>>(X, T0, ln3s, ln3b);
  gemm_k<2,u16><<<G_FF1, 256, 0, stream>>>(T0,  wff1t, MID, MKD, FF_, D_, 0);
  gemm_k<1,u16><<<G_MD,  256, 0, stream>>>(MID, wff2t, X,   MKD, D_, FF_, 0);

  // ---- outputs ----
  scatter_k<<<B_*S_, 256, 0, stream>>>(pos, X, hid, out0);
  xout_k  <<<(MKD*D_)/256, 256, 0, stream>>>(X, out1);
}

// Round 5
// 507.406 us; speedup vs baseline: 5.1470x; 1.2629x over previous
//
#include <hip/hip_runtime.h>
#include <hip/hip_bf16.h>

// Fetcher: SOC extraction -> [self-attn + cross-attn(img) + GELU-FFN] -> scatter-back.
// Round 4: fused QKV/KV projections, BM=64 tiles for N=768 GEMMs (grid-starvation fix),
//          2-phase prefetch GEMM, single fused weight-transpose launch.

#define B_    8
#define S_    4096
#define D_    768
#define N_    1024
#define FF_   3072
#define H_    12
#define DH_   64
#define KCAP  640
#define SOC_TOK 3
#define EOS_TOK 2

typedef __hip_bfloat16 bf16;
typedef unsigned short u16;
typedef __attribute__((ext_vector_type(8))) short short8;
typedef __attribute__((ext_vector_type(4))) float f32x4;

__device__ __forceinline__ u16 ftou16(float x){ union{bf16 b; u16 s;} c; c.b = __float2bfloat16(x); return c.s; }
__device__ __forceinline__ unsigned pk2(float lo, float hi){ return (unsigned)ftou16(lo) | ((unsigned)ftou16(hi)<<16); }

__device__ __forceinline__ f32x4 MFMA(short8 a, short8 b, f32x4 c){
  return __builtin_amdgcn_mfma_f32_16x16x32_bf16(a, b, c, 0, 0, 0);
}

// async global->LDS, 16B per lane; LDS dest = wave-uniform base + lane*16
__device__ __forceinline__ void gld16(const void* gp, void* lp){
  __builtin_amdgcn_global_load_lds(
    reinterpret_cast<const __attribute__((address_space(1))) unsigned int*>((size_t)gp),
    reinterpret_cast<__attribute__((address_space(3))) unsigned int*>((size_t)lp),
    16, 0, 0);
}

// ---------------- scan ----------------
__global__ __launch_bounds__(256) void scan_k(const int* __restrict__ seq,
                                              int* __restrict__ pos, int* __restrict__ src,
                                              int* __restrict__ counts){
  int b = blockIdx.x, tid = threadIdx.x;
  __shared__ int sd[256];
  __shared__ int carryE, carryS;
  if (tid==0){ carryE=0; carryS=0; }
  __syncthreads();
  for (int c=0; c<S_; c+=256){
    int s   = c + tid;
    int tok = seq[b*S_ + s];
    int isE = (tok==EOS_TOK) ? 1 : 0;
    int isS = (tok==SOC_TOK) ? 1 : 0;
    sd[tid]=isE; __syncthreads();
    for (int off=1; off<256; off<<=1){ int t_=(tid>=off)?sd[tid-off]:0; __syncthreads(); sd[tid]+=t_; __syncthreads(); }
    int eIncl = sd[tid];
    int eTot  = sd[255];
    int valid = (isS && (carryE + eIncl)==0) ? 1 : 0;
    __syncthreads();
    sd[tid]=valid; __syncthreads();
    for (int off=1; off<256; off<<=1){ int t_=(tid>=off)?sd[tid-off]:0; __syncthreads(); sd[tid]+=t_; __syncthreads(); }
    int vIncl = sd[tid];
    int vTot  = sd[255];
    if (valid){
      int slot = carryS + vIncl - 1;
      pos[b*S_ + s] = slot;
      if (slot < KCAP) src[b*KCAP + slot] = s;
    } else {
      pos[b*S_ + s] = -1;
    }
    __syncthreads();
    if (tid==0){ carryE += eTot; carryS += vTot; }
    __syncthreads();
  }
  if (tid==0) counts[b] = (carryS < KCAP) ? carryS : KCAP;
}

// ---------------- gather ----------------
__global__ __launch_bounds__(256) void gather_k(const float* __restrict__ hid,
                                                const int* __restrict__ src,
                                                const int* __restrict__ counts,
                                                float* __restrict__ X){
  int bk = blockIdx.x; int b = bk / KCAP; int k = bk % KCAP;
  int tid = threadIdx.x;
  int cnt = counts[b];
  float* xr = X + (size_t)bk*D_;
  if (k < cnt){
    int s = src[b*KCAP + k];
    const float* hr = hid + ((size_t)b*S_ + s)*D_;
    xr[tid] = hr[tid]; xr[tid+256] = hr[tid+256]; xr[tid+512] = hr[tid+512];
  } else {
    xr[tid] = 0.f; xr[tid+256] = 0.f; xr[tid+512] = 0.f;
  }
}

// ---------------- all weight transposes in one launch: f32 [K][N] -> bf16 [N][K] ----------------
struct TransArgs { const float* w[10]; u16* o[10]; };
__global__ __launch_bounds__(256) void transpose_all(TransArgs a){
  __shared__ float tile[32][33];
  int id = blockIdx.x;
  int wi, t, K, N;
  if (id < 4608){ wi = id/576; t = id%576; K = 768; N = 768; }
  else if (id < 6912){ wi = 8; t = id-4608; K = 768; N = 3072; }
  else { wi = 9; t = id-6912; K = 3072; N = 768; }
  const float* in = a.w[wi]; u16* out = a.o[wi];
  int nbx = N >> 5;
  int bx = t % nbx, by = t / nbx;
  int tx = threadIdx.x & 31, ty = threadIdx.x >> 5;
  #pragma unroll
  for (int i=0;i<4;++i)
    tile[ty + i*8][tx] = in[(size_t)(by*32 + ty + i*8)*N + bx*32 + tx];
  __syncthreads();
  #pragma unroll
  for (int i=0;i<4;++i)
    out[(size_t)(bx*32 + ty + i*8)*K + by*32 + tx] = ftou16(tile[tx][ty + i*8]);
}

// ---------------- layernorm ----------------
__global__ __launch_bounds__(256) void ln_k(const float* __restrict__ X, u16* __restrict__ Y,
                                            const float* __restrict__ g, const float* __restrict__ bt){
  int r = blockIdx.x; int tid = threadIdx.x;
  const float* xr = X + (size_t)r*D_;
  float v0=xr[tid], v1=xr[tid+256], v2=xr[tid+512];
  float s1=v0+v1+v2, s2=v0*v0+v1*v1+v2*v2;
  for (int off=32; off; off>>=1){ s1+=__shfl_xor(s1,off); s2+=__shfl_xor(s2,off); }
  __shared__ float red[8];
  __shared__ float mu_s, rs_s;
  int w=tid>>6, ln=tid&63;
  if (ln==0){ red[w]=s1; red[4+w]=s2; }
  __syncthreads();
  if (tid==0){
    float S1=red[0]+red[1]+red[2]+red[3];
    float S2=red[4]+red[5]+red[6]+red[7];
    float mu = S1*(1.f/D_);
    float var= S2*(1.f/D_) - mu*mu;
    mu_s=mu; rs_s=rsqrtf(var + 1e-5f);
  }
  __syncthreads();
  float mu=mu_s, rs=rs_s;
  u16* yr = Y + (size_t)r*D_;
  yr[tid]     = ftou16((v0-mu)*rs*g[tid]     + bt[tid]);
  yr[tid+256] = ftou16((v1-mu)*rs*g[tid+256] + bt[tid+256]);
  yr[tid+512] = ftou16((v2-mu)*rs*g[tid+512] + bt[tid+512]);
}

// ---------------- MFMA GEMM: C[M][N] = A[M][K] @ Bt[N][K]^T, 2-phase prefetch ----------------
// MODE 0: C0_bf16[M][N] ; 1: C0_f32 += ; 2: C0_bf16 = gelu ;
// MODE 4: self QKV (N=2304): cols 0-767->C0(Q), 768-1535->C1(K), 1536-2303->C2 = V^T [b][768][KCAP]
// MODE 5: cross KV (N=1536): cols 0-767->C0(K), 768-1535->C2 = V^T [b][768][1024]
template<int MODE, int BM, typename TA>
__global__ __launch_bounds__(256) void gemm_k(const TA* __restrict__ A, const u16* __restrict__ Bt,
                                              void* __restrict__ C0, void* __restrict__ C1, void* __restrict__ C2,
                                              int M, int N, int K, int Lkv){
  constexpr int MI = (BM==128) ? 4 : 2;
  __shared__ __align__(16) u16 As[2][BM*32];
  __shared__ __align__(16) u16 Bs[2][128*32];
  int nbx = N >> 7;
  int bx = blockIdx.x % nbx, by = blockIdx.x / nbx;
  int tid = threadIdx.x;
  int w = tid>>6, l = tid&63, g = l>>4, c = l&15;
  int wr = w&1, wc = w>>1;
  f32x4 acc[MI][4] = {};
  float4 rg[4];
  const int NK = K/32;

  auto STAGEB = [&](int buf, int kt){
    #pragma unroll
    for (int p=0;p<2;++p){
      int row = w*32 + p*16 + (l>>2);
      int su  = (l&3) ^ ((row>>1)&3);
      gld16((const void*)(Bt + (size_t)(bx*128+row)*K + kt + su*8), (void*)&Bs[buf][(w*32+p*16)*32]);
    }
  };
  auto STAGEA16 = [&](int buf, int kt){
    if constexpr (BM==128){
      #pragma unroll
      for (int p=0;p<2;++p){
        int row = w*32 + p*16 + (l>>2);
        int su  = (l&3) ^ ((row>>1)&3);
        gld16((const void*)((const u16*)A + (size_t)(by*BM+row)*K + kt + su*8), (void*)&As[buf][(w*32+p*16)*32]);
      }
    } else {
      int row = w*16 + (l>>2);
      int su  = (l&3) ^ ((row>>1)&3);
      gld16((const void*)((const u16*)A + (size_t)(by*BM+row)*K + kt + su*8), (void*)&As[buf][(w*16)*32]);
    }
  };
  auto LOADREG = [&](int kt){
    const float* ap = (const float*)A + (size_t)(by*128 + (tid>>1))*K + kt + (tid&1)*16;
    rg[0]=*(const float4*)ap;     rg[1]=*(const float4*)(ap+4);
    rg[2]=*(const float4*)(ap+8); rg[3]=*(const float4*)(ap+12);
  };
  auto WRITEA = [&](int buf){
    int row = tid>>1, half = tid&1;
    uint4 w0,w1;
    w0.x=pk2(rg[0].x,rg[0].y); w0.y=pk2(rg[0].z,rg[0].w); w0.z=pk2(rg[1].x,rg[1].y); w0.w=pk2(rg[1].z,rg[1].w);
    w1.x=pk2(rg[2].x,rg[2].y); w1.y=pk2(rg[2].z,rg[2].w); w1.z=pk2(rg[3].x,rg[3].y); w1.w=pk2(rg[3].z,rg[3].w);
    int sw = (row>>1)&3;
    *(uint4*)&As[buf][row*32 + ((half*2  )^sw)*8] = w0;
    *(uint4*)&As[buf][row*32 + ((half*2+1)^sw)*8] = w1;
  };
  auto COMPUTE = [&](int buf){
    short8 af[MI], bfr[4];
    #pragma unroll
    for (int mi=0;mi<MI;++mi){ int row = wr*(MI*16) + mi*16 + c; af[mi]  = *(const short8*)&As[buf][row*32 + (g^((row>>1)&3))*8]; }
    #pragma unroll
    for (int ni=0;ni<4;++ni){ int row = wc*64 + ni*16 + c;       bfr[ni] = *(const short8*)&Bs[buf][row*32 + (g^((row>>1)&3))*8]; }
    #pragma unroll
    for (int mi=0;mi<MI;++mi)
      #pragma unroll
      for (int ni=0;ni<4;++ni) acc[mi][ni] = MFMA(af[mi], bfr[ni], acc[mi][ni]);
  };

  if constexpr (sizeof(TA)==4){
    LOADREG(0); STAGEB(0,0); WRITEA(0);
  } else {
    STAGEA16(0,0); STAGEB(0,0);
  }
  __syncthreads();
  int buf = 0;
  for (int t=0;t<NK;++t){
    int ktn = (t+1)*32;
    if constexpr (sizeof(TA)==4){
      if (t+1<NK){ LOADREG(ktn); STAGEB(buf^1, ktn); }
      COMPUTE(buf);
      if (t+1<NK) WRITEA(buf^1);
    } else {
      if (t+1<NK){ STAGEA16(buf^1, ktn); STAGEB(buf^1, ktn); }
      COMPUTE(buf);
    }
    __syncthreads();
    buf ^= 1;
  }

  int row0 = by*BM + wr*(MI*16), col0 = bx*128 + wc*64;
  #pragma unroll
  for (int mi=0;mi<MI;++mi)
    #pragma unroll
    for (int ni=0;ni<4;++ni)
      #pragma unroll
      for (int r=0;r<4;++r){
        int row = row0 + mi*16 + g*4 + r;
        int col = col0 + ni*16 + c;
        float v = acc[mi][ni][r];
        if (MODE==0){
          ((u16*)C0)[(size_t)row*N + col] = ftou16(v);
        } else if (MODE==1){
          ((float*)C0)[(size_t)row*N + col] += v;
        } else if (MODE==2){
          float z2 = 1.5957691216057308f*(v + 0.044715f*v*v*v);
          float e  = __expf(z2);
          float th = 1.f - 2.f/(e + 1.f);
          ((u16*)C0)[(size_t)row*N + col] = ftou16(0.5f*v*(1.f+th));
        } else if (MODE==4){
          if (col < 768)       ((u16*)C0)[(size_t)row*768 + col]       = ftou16(v);
          else if (col < 1536) ((u16*)C1)[(size_t)row*768 + col - 768] = ftou16(v);
          else {
            int vv = col - 1536; int bb = row / KCAP; int key = row - bb*KCAP;
            ((u16*)C2)[((size_t)(bb*768 + vv))*KCAP + key] = ftou16(v);
          }
        } else { // MODE 5
          if (col < 768) ((u16*)C0)[(size_t)row*768 + col] = ftou16(v);
          else {
            int vv = col - 768; int bb = row >> 10; int key = row & 1023;
            ((u16*)C2)[((size_t)(bb*768 + vv))*1024 + key] = ftou16(v);
          }
        }
      }
}

// ---------------- MFMA flash attention, LDS-staged K/V with 2-phase prefetch ----------------
template<int MASKED>
__global__ __launch_bounds__(256) void attn_k(const u16* __restrict__ Q, const u16* __restrict__ Kb,
                                              const u16* __restrict__ Vt, u16* __restrict__ O,
                                              const int* __restrict__ counts, int Lk){
  __shared__ __align__(16) u16 Ks[2][64*64];
  __shared__ __align__(16) u16 Vs[2][64*64];
  __shared__ __align__(16) u16 P[4][16][72];
  int tid = threadIdx.x;
  int w = tid>>6, l = tid&63, g = l>>4, c = l&15;
  int qc = blockIdx.x % 5;
  int bh = blockIdx.x / 5;
  int h = bh % H_, b = bh / H_;
  int q0 = qc*128 + w*32;
  int cnt = MASKED ? counts[b] : Lk;
  int nt = (cnt + 63) >> 6;

  short8 qf[2][2];
  #pragma unroll
  for (int mi=0;mi<2;++mi){
    const u16* Qrow = Q + ((size_t)(b*KCAP + q0 + mi*16 + c))*D_ + h*DH_;
    qf[mi][0] = *(const short8*)(Qrow + g*8);
    qf[mi][1] = *(const short8*)(Qrow + 32 + g*8);
  }

  int srow8 = (l>>3);
  int sunit = l&7;
  auto STAGE = [&](int buf, int kb){
    #pragma unroll
    for (int p=0;p<2;++p){
      int r0 = w*16 + p*8;
      int rowK = r0 + srow8;
      int su = sunit ^ (rowK&7);
      gld16((const void*)(Kb + ((size_t)(b*Lk + kb + rowK))*D_ + h*DH_ + su*8), (void*)&Ks[buf][r0*64]);
      gld16((const void*)(Vt + ((size_t)(b*D_ + h*DH_ + rowK))*Lk + kb + su*8), (void*)&Vs[buf][r0*64]);
    }
  };

  f32x4 o[2][4] = {};
  float m_[2][4], l_[2][4] = {};
  #pragma unroll
  for (int mi=0;mi<2;++mi)
    #pragma unroll
    for (int r=0;r<4;++r) m_[mi][r] = -1e30f;

  STAGE(0, 0);
  __syncthreads();
  int buf = 0;
  for (int t=0; t<nt; ++t){
    int kb = t*64;
    if (t+1 < nt) STAGE(buf^1, kb+64);
    short8 fr[4][2];
    #pragma unroll
    for (int nb=0;nb<4;++nb)
      #pragma unroll
      for (int kh=0;kh<2;++kh)
        fr[nb][kh] = *(const short8*)&Ks[buf][(nb*16+c)*64 + (((kh<<2)|g) ^ (c&7))*8];
    f32x4 z[2][4];
    #pragma unroll
    for (int mi=0;mi<2;++mi)
      #pragma unroll
      for (int nb=0;nb<4;++nb){
        f32x4 zz = {0.f,0.f,0.f,0.f};
        zz = MFMA(qf[mi][0], fr[nb][0], zz);
        zz = MFMA(qf[mi][1], fr[nb][1], zz);
        z[mi][nb] = zz;
      }
    float pv[2][4][4];
    #pragma unroll
    for (int nb=0;nb<4;++nb){
      bool msk = MASKED && (kb + nb*16 + c >= cnt);
      #pragma unroll
      for (int mi=0;mi<2;++mi)
        #pragma unroll
        for (int r=0;r<4;++r) pv[mi][nb][r] = msk ? -1e30f : z[mi][nb][r]*0.125f;
    }
    float scl[2][4];
    #pragma unroll
    for (int mi=0;mi<2;++mi){
      #pragma unroll
      for (int r=0;r<4;++r){
        float v = fmaxf(fmaxf(pv[mi][0][r],pv[mi][1][r]), fmaxf(pv[mi][2][r],pv[mi][3][r]));
        v = fmaxf(v, __shfl_xor(v,1)); v = fmaxf(v, __shfl_xor(v,2));
        v = fmaxf(v, __shfl_xor(v,4)); v = fmaxf(v, __shfl_xor(v,8));
        float nm = fmaxf(m_[mi][r], v);
        scl[mi][r] = __expf(m_[mi][r] - nm);
        m_[mi][r] = nm;
      }
      #pragma unroll
      for (int r=0;r<4;++r){
        float acc2 = 0.f;
        #pragma unroll
        for (int nb=0;nb<4;++nb){
          float e = __expf(pv[mi][nb][r] - m_[mi][r]);
          pv[mi][nb][r] = e; acc2 += e;
        }
        acc2 += __shfl_xor(acc2,1); acc2 += __shfl_xor(acc2,2);
        acc2 += __shfl_xor(acc2,4); acc2 += __shfl_xor(acc2,8);
        l_[mi][r] = l_[mi][r]*scl[mi][r] + acc2;
      }
      #pragma unroll
      for (int nbd=0;nbd<4;++nbd)
        #pragma unroll
        for (int r=0;r<4;++r) o[mi][nbd][r] *= scl[mi][r];
    }
    #pragma unroll
    for (int nbd=0;nbd<4;++nbd)
      #pragma unroll
      for (int kh=0;kh<2;++kh)
        fr[nbd][kh] = *(const short8*)&Vs[buf][(nbd*16+c)*64 + (((kh<<2)|g) ^ (c&7))*8];
    #pragma unroll
    for (int mi=0;mi<2;++mi){
      #pragma unroll
      for (int nb=0;nb<4;++nb)
        #pragma unroll
        for (int r=0;r<4;++r) P[w][g*4+r][nb*16+c] = ftou16(pv[mi][nb][r]);
      short8 pa0 = *(const short8*)&P[w][c][g*8];
      short8 pa1 = *(const short8*)&P[w][c][32 + g*8];
      #pragma unroll
      for (int nbd=0;nbd<4;++nbd){
        o[mi][nbd] = MFMA(pa0, fr[nbd][0], o[mi][nbd]);
        o[mi][nbd] = MFMA(pa1, fr[nbd][1], o[mi][nbd]);
      }
    }
    __syncthreads();
    buf ^= 1;
  }
  #pragma unroll
  for (int mi=0;mi<2;++mi)
    #pragma unroll
    for (int nbd=0;nbd<4;++nbd)
      #pragma unroll
      for (int r=0;r<4;++r)
        O[((size_t)(b*KCAP + q0 + mi*16 + g*4 + r))*D_ + h*DH_ + nbd*16 + c] = ftou16(o[mi][nbd][r] / l_[mi][r]);
}

// ---------------- scatter back ----------------
__global__ __launch_bounds__(256) void scatter_k(const int* __restrict__ pos, const float* __restrict__ X,
                                                 const float* __restrict__ hid, float* __restrict__ out0){
  int bs = blockIdx.x; int tid = threadIdx.x;
  int b = bs >> 12;
  int p = pos[bs];
  float* orow = out0 + (size_t)bs*D_;
  if (p >= 0){
    int pc = p < KCAP ? p : (KCAP-1);
    const float* xr = X + ((size_t)(b*KCAP + pc))*D_;
    orow[tid]     = xr[tid];
    orow[tid+256] = xr[tid+256];
    orow[tid+512] = xr[tid+512];
  } else {
    const float* hr = hid + (size_t)bs*D_;
    orow[tid]     = hr[tid];
    orow[tid+256] = hr[tid+256];
    orow[tid+512] = hr[tid+512];
  }
}

__global__ __launch_bounds__(256) void xout_k(const float* __restrict__ X, float* __restrict__ out1){
  int i = blockIdx.x*256 + threadIdx.x;
  out1[i] = X[i];
}

extern "C" void kernel_launch(void* const* d_in, const int* in_sizes, int n_in,
                              void* d_out, int out_size, void* d_ws, size_t ws_size,
                              hipStream_t stream){
  const float* img  = (const float*)d_in[0];
  const float* hid  = (const float*)d_in[1];
  const int*   seq  = (const int*)  d_in[2];
  const float* W[10] = { (const float*)d_in[3], (const float*)d_in[4], (const float*)d_in[5], (const float*)d_in[6],
                         (const float*)d_in[7], (const float*)d_in[8], (const float*)d_in[9], (const float*)d_in[10],
                         (const float*)d_in[11], (const float*)d_in[12] };
  const float* ln1s = (const float*)d_in[13];
  const float* ln1b = (const float*)d_in[14];
  const float* ln2s = (const float*)d_in[15];
  const float* ln2b = (const float*)d_in[16];
  const float* ln3s = (const float*)d_in[17];
  const float* ln3b = (const float*)d_in[18];

  char* ws = (char*)d_ws;
  int*   pos    = (int*)  (ws + 0);          //   131072
  int*   src    = (int*)  (ws + 131072);     //    20480
  int*   counts = (int*)  (ws + 151552);     //      256
  float* X      = (float*)(ws + 151808);     // 15728640
  u16*   T0     = (u16*)  (ws + 15880448);   //  7864320
  u16*   Qb     = (u16*)  (ws + 23744768);   //  7864320
  u16*   Kb     = (u16*)  (ws + 31609088);   // 12582912
  u16*   Vt     = (u16*)  (ws + 44192000);   // 12582912
  u16*   AO     = (u16*)  (ws + 56774912);   //  7864320
  u16*   Wt     = (u16*)  (ws + 64639232);   // 18874368 -> total 83513600
  u16*   MID    = Qb;                        // 31457280, aliases Qb..Vt (dead during FFN)

  // transposed weights: wq_s,wk_s,wv_s contiguous => fused [2304][768]; wk_c,wv_c contiguous => [1536][768]
  u16* wqkv_st = Wt + 0ull*589824;           // rows 0-767 Q, 768-1535 K, 1536-2303 V
  u16* wo_st   = Wt + 3ull*589824;
  u16* wq_ct   = Wt + 4ull*589824;
  u16* wkv_ct  = Wt + 5ull*589824;           // rows 0-767 K, 768-1535 V
  u16* wo_ct   = Wt + 7ull*589824;
  u16* wff1t   = Wt + 8ull*589824;           // [3072][768]
  u16* wff2t   = wff1t + 2359296;            // [768][3072]

  float* out0 = (float*)d_out;
  float* out1 = out0 + (size_t)B_*S_*D_;

  const int MKD = B_*KCAP;   // 5120

  TransArgs ta;
  for (int i=0;i<10;++i) ta.w[i] = W[i];
  for (int i=0;i<8;++i)  ta.o[i] = Wt + (size_t)i*589824;
  ta.o[8] = wff1t; ta.o[9] = wff2t;
  transpose_all<<<9216, 256, 0, stream>>>(ta);

  scan_k  <<<B_,      256, 0, stream>>>(seq, pos, src, counts);
  gather_k<<<B_*KCAP, 256, 0, stream>>>(hid, src, counts, X);

  const int G_QKV = (MKD/128)*(2304/128);    // 40*18 = 720
  const int G_N768= (MKD/64)*(768/128);      // 80*6  = 480
  const int G_KV  = ((B_*N_)/128)*(1536/128);// 64*12 = 768
  const int G_FF1 = (MKD/128)*(FF_/128);     // 40*24 = 960
  const int G_ATT = B_*H_*5;                 // 480

  // ---- self-attention block ----
  ln_k<<<MKD, 256, 0, stream>>>(X, T0, ln1s, ln1b);
  gemm_k<4,128,u16><<<G_QKV, 256, 0, stream>>>(T0, wqkv_st, Qb, Kb, Vt, MKD, 2304, D_, KCAP);
  attn_k<1><<<G_ATT, 256, 0, stream>>>(Qb, Kb, Vt, AO, counts, KCAP);
  gemm_k<1,64,u16><<<G_N768, 256, 0, stream>>>(AO, wo_st, X, nullptr, nullptr, MKD, D_, D_, 0);

  // ---- cross-attention block ----
  ln_k<<<MKD, 256, 0, stream>>>(X, T0, ln2s, ln2b);
  gemm_k<0,64,u16>   <<<G_N768, 256, 0, stream>>>(T0,  wq_ct,  Qb, nullptr, nullptr, MKD,   D_,   D_, 0);
  gemm_k<5,128,float><<<G_KV,   256, 0, stream>>>(img, wkv_ct, Kb, nullptr, Vt,      B_*N_, 1536, D_, N_);
  attn_k<0><<<G_ATT, 256, 0, stream>>>(Qb, Kb, Vt, AO, counts, N_);
  gemm_k<1,64,u16><<<G_N768, 256, 0, stream>>>(AO, wo_ct, X, nullptr, nullptr, MKD, D_, D_, 0);

  // ---- FFN block ----
  ln_k<<<MKD, 256, 0, stream>>>(X, T0, ln3s, ln3b);
  gemm_k<2,128,u16><<<G_FF1,  256, 0, stream>>>(T0,  wff1t, MID, nullptr, nullptr, MKD, FF_, D_,  0);
  gemm_k<1,64,u16> <<<G_N768, 256, 0, stream>>>(MID, wff2t, X,   nullptr, nullptr, MKD, D_,  FF_, 0);

  // ---- outputs ----
  scatter_k<<<B_*S_, 256, 0, stream>>>(pos, X, hid, out0);
  xout_k  <<<(MKD*D_)/256, 256, 0, stream>>>(X, out1);
}

// Round 6
// 495.239 us; speedup vs baseline: 5.2734x; 1.0246x over previous
//
#include <hip/hip_runtime.h>
#include <hip/hip_bf16.h>

// Fetcher: SOC extraction -> [self-attn + cross-attn(img) + GELU-FFN] -> scatter-back.
// Round 5: XCD-chunked block swizzle on all GEMM/attn launches (L2 locality; was 8x HBM overfetch).

#define B_    8
#define S_    4096
#define D_    768
#define N_    1024
#define FF_   3072
#define H_    12
#define DH_   64
#define KCAP  640
#define SOC_TOK 3
#define EOS_TOK 2

typedef __hip_bfloat16 bf16;
typedef unsigned short u16;
typedef __attribute__((ext_vector_type(8))) short short8;
typedef __attribute__((ext_vector_type(4))) float f32x4;

__device__ __forceinline__ u16 ftou16(float x){ union{bf16 b; u16 s;} c; c.b = __float2bfloat16(x); return c.s; }
__device__ __forceinline__ unsigned pk2(float lo, float hi){ return (unsigned)ftou16(lo) | ((unsigned)ftou16(hi)<<16); }

__device__ __forceinline__ f32x4 MFMA(short8 a, short8 b, f32x4 c){
  return __builtin_amdgcn_mfma_f32_16x16x32_bf16(a, b, c, 0, 0, 0);
}

// async global->LDS, 16B per lane; LDS dest = wave-uniform base + lane*16
__device__ __forceinline__ void gld16(const void* gp, void* lp){
  __builtin_amdgcn_global_load_lds(
    reinterpret_cast<const __attribute__((address_space(1))) unsigned int*>((size_t)gp),
    reinterpret_cast<__attribute__((address_space(3))) unsigned int*>((size_t)lp),
    16, 0, 0);
}

// XCD-chunked bijective swizzle (grid must be divisible by 8; all ours are).
// Blocks i, i+8, i+16... (same XCD under round-robin dispatch) get consecutive work ids.
__device__ __forceinline__ int xcd_swz(){
  int id = blockIdx.x;
  return (id & 7) * ((int)gridDim.x >> 3) + (id >> 3);
}

// ---------------- scan ----------------
__global__ __launch_bounds__(256) void scan_k(const int* __restrict__ seq,
                                              int* __restrict__ pos, int* __restrict__ src,
                                              int* __restrict__ counts){
  int b = blockIdx.x, tid = threadIdx.x;
  __shared__ int sd[256];
  __shared__ int carryE, carryS;
  if (tid==0){ carryE=0; carryS=0; }
  __syncthreads();
  for (int c=0; c<S_; c+=256){
    int s   = c + tid;
    int tok = seq[b*S_ + s];
    int isE = (tok==EOS_TOK) ? 1 : 0;
    int isS = (tok==SOC_TOK) ? 1 : 0;
    sd[tid]=isE; __syncthreads();
    for (int off=1; off<256; off<<=1){ int t_=(tid>=off)?sd[tid-off]:0; __syncthreads(); sd[tid]+=t_; __syncthreads(); }
    int eIncl = sd[tid];
    int eTot  = sd[255];
    int valid = (isS && (carryE + eIncl)==0) ? 1 : 0;
    __syncthreads();
    sd[tid]=valid; __syncthreads();
    for (int off=1; off<256; off<<=1){ int t_=(tid>=off)?sd[tid-off]:0; __syncthreads(); sd[tid]+=t_; __syncthreads(); }
    int vIncl = sd[tid];
    int vTot  = sd[255];
    if (valid){
      int slot = carryS + vIncl - 1;
      pos[b*S_ + s] = slot;
      if (slot < KCAP) src[b*KCAP + slot] = s;
    } else {
      pos[b*S_ + s] = -1;
    }
    __syncthreads();
    if (tid==0){ carryE += eTot; carryS += vTot; }
    __syncthreads();
  }
  if (tid==0) counts[b] = (carryS < KCAP) ? carryS : KCAP;
}

// ---------------- gather ----------------
__global__ __launch_bounds__(256) void gather_k(const float* __restrict__ hid,
                                                const int* __restrict__ src,
                                                const int* __restrict__ counts,
                                                float* __restrict__ X){
  int bk = blockIdx.x; int b = bk / KCAP; int k = bk % KCAP;
  int tid = threadIdx.x;
  int cnt = counts[b];
  float* xr = X + (size_t)bk*D_;
  if (k < cnt){
    int s = src[b*KCAP + k];
    const float* hr = hid + ((size_t)b*S_ + s)*D_;
    xr[tid] = hr[tid]; xr[tid+256] = hr[tid+256]; xr[tid+512] = hr[tid+512];
  } else {
    xr[tid] = 0.f; xr[tid+256] = 0.f; xr[tid+512] = 0.f;
  }
}

// ---------------- all weight transposes in one launch: f32 [K][N] -> bf16 [N][K] ----------------
struct TransArgs { const float* w[10]; u16* o[10]; };
__global__ __launch_bounds__(256) void transpose_all(TransArgs a){
  __shared__ float tile[32][33];
  int id = blockIdx.x;
  int wi, t, K, N;
  if (id < 4608){ wi = id/576; t = id%576; K = 768; N = 768; }
  else if (id < 6912){ wi = 8; t = id-4608; K = 768; N = 3072; }
  else { wi = 9; t = id-6912; K = 3072; N = 768; }
  const float* in = a.w[wi]; u16* out = a.o[wi];
  int nbx = N >> 5;
  int bx = t % nbx, by = t / nbx;
  int tx = threadIdx.x & 31, ty = threadIdx.x >> 5;
  #pragma unroll
  for (int i=0;i<4;++i)
    tile[ty + i*8][tx] = in[(size_t)(by*32 + ty + i*8)*N + bx*32 + tx];
  __syncthreads();
  #pragma unroll
  for (int i=0;i<4;++i)
    out[(size_t)(bx*32 + ty + i*8)*K + by*32 + tx] = ftou16(tile[tx][ty + i*8]);
}

// ---------------- layernorm ----------------
__global__ __launch_bounds__(256) void ln_k(const float* __restrict__ X, u16* __restrict__ Y,
                                            const float* __restrict__ g, const float* __restrict__ bt){
  int r = blockIdx.x; int tid = threadIdx.x;
  const float* xr = X + (size_t)r*D_;
  float v0=xr[tid], v1=xr[tid+256], v2=xr[tid+512];
  float s1=v0+v1+v2, s2=v0*v0+v1*v1+v2*v2;
  for (int off=32; off; off>>=1){ s1+=__shfl_xor(s1,off); s2+=__shfl_xor(s2,off); }
  __shared__ float red[8];
  __shared__ float mu_s, rs_s;
  int w=tid>>6, ln=tid&63;
  if (ln==0){ red[w]=s1; red[4+w]=s2; }
  __syncthreads();
  if (tid==0){
    float S1=red[0]+red[1]+red[2]+red[3];
    float S2=red[4]+red[5]+red[6]+red[7];
    float mu = S1*(1.f/D_);
    float var= S2*(1.f/D_) - mu*mu;
    mu_s=mu; rs_s=rsqrtf(var + 1e-5f);
  }
  __syncthreads();
  float mu=mu_s, rs=rs_s;
  u16* yr = Y + (size_t)r*D_;
  yr[tid]     = ftou16((v0-mu)*rs*g[tid]     + bt[tid]);
  yr[tid+256] = ftou16((v1-mu)*rs*g[tid+256] + bt[tid+256]);
  yr[tid+512] = ftou16((v2-mu)*rs*g[tid+512] + bt[tid+512]);
}

// ---------------- MFMA GEMM: C[M][N] = A[M][K] @ Bt[N][K]^T, 2-phase prefetch ----------------
// MODE 0: C0_bf16[M][N] ; 1: C0_f32 += ; 2: C0_bf16 = gelu ;
// MODE 4: self QKV (N=2304): cols 0-767->C0(Q), 768-1535->C1(K), 1536-2303->C2 = V^T [b][768][KCAP]
// MODE 5: cross KV (N=1536): cols 0-767->C0(K), 768-1535->C2 = V^T [b][768][1024]
template<int MODE, int BM, typename TA>
__global__ __launch_bounds__(256) void gemm_k(const TA* __restrict__ A, const u16* __restrict__ Bt,
                                              void* __restrict__ C0, void* __restrict__ C1, void* __restrict__ C2,
                                              int M, int N, int K, int Lkv){
  constexpr int MI = (BM==128) ? 4 : 2;
  __shared__ __align__(16) u16 As[2][BM*32];
  __shared__ __align__(16) u16 Bs[2][128*32];
  int nbx = N >> 7;
  int wgid = xcd_swz();
  int bx = wgid % nbx, by = wgid / nbx;
  int tid = threadIdx.x;
  int w = tid>>6, l = tid&63, g = l>>4, c = l&15;
  int wr = w&1, wc = w>>1;
  f32x4 acc[MI][4] = {};
  float4 rg[4];
  const int NK = K/32;

  auto STAGEB = [&](int buf, int kt){
    #pragma unroll
    for (int p=0;p<2;++p){
      int row = w*32 + p*16 + (l>>2);
      int su  = (l&3) ^ ((row>>1)&3);
      gld16((const void*)(Bt + (size_t)(bx*128+row)*K + kt + su*8), (void*)&Bs[buf][(w*32+p*16)*32]);
    }
  };
  auto STAGEA16 = [&](int buf, int kt){
    if constexpr (BM==128){
      #pragma unroll
      for (int p=0;p<2;++p){
        int row = w*32 + p*16 + (l>>2);
        int su  = (l&3) ^ ((row>>1)&3);
        gld16((const void*)((const u16*)A + (size_t)(by*BM+row)*K + kt + su*8), (void*)&As[buf][(w*32+p*16)*32]);
      }
    } else {
      int row = w*16 + (l>>2);
      int su  = (l&3) ^ ((row>>1)&3);
      gld16((const void*)((const u16*)A + (size_t)(by*BM+row)*K + kt + su*8), (void*)&As[buf][(w*16)*32]);
    }
  };
  auto LOADREG = [&](int kt){
    const float* ap = (const float*)A + (size_t)(by*128 + (tid>>1))*K + kt + (tid&1)*16;
    rg[0]=*(const float4*)ap;     rg[1]=*(const float4*)(ap+4);
    rg[2]=*(const float4*)(ap+8); rg[3]=*(const float4*)(ap+12);
  };
  auto WRITEA = [&](int buf){
    int row = tid>>1, half = tid&1;
    uint4 w0,w1;
    w0.x=pk2(rg[0].x,rg[0].y); w0.y=pk2(rg[0].z,rg[0].w); w0.z=pk2(rg[1].x,rg[1].y); w0.w=pk2(rg[1].z,rg[1].w);
    w1.x=pk2(rg[2].x,rg[2].y); w1.y=pk2(rg[2].z,rg[2].w); w1.z=pk2(rg[3].x,rg[3].y); w1.w=pk2(rg[3].z,rg[3].w);
    int sw = (row>>1)&3;
    *(uint4*)&As[buf][row*32 + ((half*2  )^sw)*8] = w0;
    *(uint4*)&As[buf][row*32 + ((half*2+1)^sw)*8] = w1;
  };
  auto COMPUTE = [&](int buf){
    short8 af[MI], bfr[4];
    #pragma unroll
    for (int mi=0;mi<MI;++mi){ int row = wr*(MI*16) + mi*16 + c; af[mi]  = *(const short8*)&As[buf][row*32 + (g^((row>>1)&3))*8]; }
    #pragma unroll
    for (int ni=0;ni<4;++ni){ int row = wc*64 + ni*16 + c;       bfr[ni] = *(const short8*)&Bs[buf][row*32 + (g^((row>>1)&3))*8]; }
    #pragma unroll
    for (int mi=0;mi<MI;++mi)
      #pragma unroll
      for (int ni=0;ni<4;++ni) acc[mi][ni] = MFMA(af[mi], bfr[ni], acc[mi][ni]);
  };

  if constexpr (sizeof(TA)==4){
    LOADREG(0); STAGEB(0,0); WRITEA(0);
  } else {
    STAGEA16(0,0); STAGEB(0,0);
  }
  __syncthreads();
  int buf = 0;
  for (int t=0;t<NK;++t){
    int ktn = (t+1)*32;
    if constexpr (sizeof(TA)==4){
      if (t+1<NK){ LOADREG(ktn); STAGEB(buf^1, ktn); }
      COMPUTE(buf);
      if (t+1<NK) WRITEA(buf^1);
    } else {
      if (t+1<NK){ STAGEA16(buf^1, ktn); STAGEB(buf^1, ktn); }
      COMPUTE(buf);
    }
    __syncthreads();
    buf ^= 1;
  }

  int row0 = by*BM + wr*(MI*16), col0 = bx*128 + wc*64;
  #pragma unroll
  for (int mi=0;mi<MI;++mi)
    #pragma unroll
    for (int ni=0;ni<4;++ni)
      #pragma unroll
      for (int r=0;r<4;++r){
        int row = row0 + mi*16 + g*4 + r;
        int col = col0 + ni*16 + c;
        float v = acc[mi][ni][r];
        if (MODE==0){
          ((u16*)C0)[(size_t)row*N + col] = ftou16(v);
        } else if (MODE==1){
          ((float*)C0)[(size_t)row*N + col] += v;
        } else if (MODE==2){
          float z2 = 1.5957691216057308f*(v + 0.044715f*v*v*v);
          float e  = __expf(z2);
          float th = 1.f - 2.f/(e + 1.f);
          ((u16*)C0)[(size_t)row*N + col] = ftou16(0.5f*v*(1.f+th));
        } else if (MODE==4){
          if (col < 768)       ((u16*)C0)[(size_t)row*768 + col]       = ftou16(v);
          else if (col < 1536) ((u16*)C1)[(size_t)row*768 + col - 768] = ftou16(v);
          else {
            int vv = col - 1536; int bb = row / KCAP; int key = row - bb*KCAP;
            ((u16*)C2)[((size_t)(bb*768 + vv))*KCAP + key] = ftou16(v);
          }
        } else { // MODE 5
          if (col < 768) ((u16*)C0)[(size_t)row*768 + col] = ftou16(v);
          else {
            int vv = col - 768; int bb = row >> 10; int key = row & 1023;
            ((u16*)C2)[((size_t)(bb*768 + vv))*1024 + key] = ftou16(v);
          }
        }
      }
}

// ---------------- MFMA flash attention, LDS-staged K/V with 2-phase prefetch ----------------
template<int MASKED>
__global__ __launch_bounds__(256) void attn_k(const u16* __restrict__ Q, const u16* __restrict__ Kb,
                                              const u16* __restrict__ Vt, u16* __restrict__ O,
                                              const int* __restrict__ counts, int Lk){
  __shared__ __align__(16) u16 Ks[2][64*64];
  __shared__ __align__(16) u16 Vs[2][64*64];
  __shared__ __align__(16) u16 P[4][16][72];
  int tid = threadIdx.x;
  int w = tid>>6, l = tid&63, g = l>>4, c = l&15;
  int wgid = xcd_swz();
  int qc = wgid % 5;
  int bh = wgid / 5;
  int h = bh % H_, b = bh / H_;
  int q0 = qc*128 + w*32;
  int cnt = MASKED ? counts[b] : Lk;
  int nt = (cnt + 63) >> 6;

  short8 qf[2][2];
  #pragma unroll
  for (int mi=0;mi<2;++mi){
    const u16* Qrow = Q + ((size_t)(b*KCAP + q0 + mi*16 + c))*D_ + h*DH_;
    qf[mi][0] = *(const short8*)(Qrow + g*8);
    qf[mi][1] = *(const short8*)(Qrow + 32 + g*8);
  }

  int srow8 = (l>>3);
  int sunit = l&7;
  auto STAGE = [&](int buf, int kb){
    #pragma unroll
    for (int p=0;p<2;++p){
      int r0 = w*16 + p*8;
      int rowK = r0 + srow8;
      int su = sunit ^ (rowK&7);
      gld16((const void*)(Kb + ((size_t)(b*Lk + kb + rowK))*D_ + h*DH_ + su*8), (void*)&Ks[buf][r0*64]);
      gld16((const void*)(Vt + ((size_t)(b*D_ + h*DH_ + rowK))*Lk + kb + su*8), (void*)&Vs[buf][r0*64]);
    }
  };

  f32x4 o[2][4] = {};
  float m_[2][4], l_[2][4] = {};
  #pragma unroll
  for (int mi=0;mi<2;++mi)
    #pragma unroll
    for (int r=0;r<4;++r) m_[mi][r] = -1e30f;

  STAGE(0, 0);
  __syncthreads();
  int buf = 0;
  for (int t=0; t<nt; ++t){
    int kb = t*64;
    if (t+1 < nt) STAGE(buf^1, kb+64);
    short8 fr[4][2];
    #pragma unroll
    for (int nb=0;nb<4;++nb)
      #pragma unroll
      for (int kh=0;kh<2;++kh)
        fr[nb][kh] = *(const short8*)&Ks[buf][(nb*16+c)*64 + (((kh<<2)|g) ^ (c&7))*8];
    f32x4 z[2][4];
    #pragma unroll
    for (int mi=0;mi<2;++mi)
      #pragma unroll
      for (int nb=0;nb<4;++nb){
        f32x4 zz = {0.f,0.f,0.f,0.f};
        zz = MFMA(qf[mi][0], fr[nb][0], zz);
        zz = MFMA(qf[mi][1], fr[nb][1], zz);
        z[mi][nb] = zz;
      }
    float pv[2][4][4];
    #pragma unroll
    for (int nb=0;nb<4;++nb){
      bool msk = MASKED && (kb + nb*16 + c >= cnt);
      #pragma unroll
      for (int mi=0;mi<2;++mi)
        #pragma unroll
        for (int r=0;r<4;++r) pv[mi][nb][r] = msk ? -1e30f : z[mi][nb][r]*0.125f;
    }
    float scl[2][4];
    #pragma unroll
    for (int mi=0;mi<2;++mi){
      #pragma unroll
      for (int r=0;r<4;++r){
        float v = fmaxf(fmaxf(pv[mi][0][r],pv[mi][1][r]), fmaxf(pv[mi][2][r],pv[mi][3][r]));
        v = fmaxf(v, __shfl_xor(v,1)); v = fmaxf(v, __shfl_xor(v,2));
        v = fmaxf(v, __shfl_xor(v,4)); v = fmaxf(v, __shfl_xor(v,8));
        float nm = fmaxf(m_[mi][r], v);
        scl[mi][r] = __expf(m_[mi][r] - nm);
        m_[mi][r] = nm;
      }
      #pragma unroll
      for (int r=0;r<4;++r){
        float acc2 = 0.f;
        #pragma unroll
        for (int nb=0;nb<4;++nb){
          float e = __expf(pv[mi][nb][r] - m_[mi][r]);
          pv[mi][nb][r] = e; acc2 += e;
        }
        acc2 += __shfl_xor(acc2,1); acc2 += __shfl_xor(acc2,2);
        acc2 += __shfl_xor(acc2,4); acc2 += __shfl_xor(acc2,8);
        l_[mi][r] = l_[mi][r]*scl[mi][r] + acc2;
      }
      #pragma unroll
      for (int nbd=0;nbd<4;++nbd)
        #pragma unroll
        for (int r=0;r<4;++r) o[mi][nbd][r] *= scl[mi][r];
    }
    #pragma unroll
    for (int nbd=0;nbd<4;++nbd)
      #pragma unroll
      for (int kh=0;kh<2;++kh)
        fr[nbd][kh] = *(const short8*)&Vs[buf][(nbd*16+c)*64 + (((kh<<2)|g) ^ (c&7))*8];
    #pragma unroll
    for (int mi=0;mi<2;++mi){
      #pragma unroll
      for (int nb=0;nb<4;++nb)
        #pragma unroll
        for (int r=0;r<4;++r) P[w][g*4+r][nb*16+c] = ftou16(pv[mi][nb][r]);
      short8 pa0 = *(const short8*)&P[w][c][g*8];
      short8 pa1 = *(const short8*)&P[w][c][32 + g*8];
      #pragma unroll
      for (int nbd=0;nbd<4;++nbd){
        o[mi][nbd] = MFMA(pa0, fr[nbd][0], o[mi][nbd]);
        o[mi][nbd] = MFMA(pa1, fr[nbd][1], o[mi][nbd]);
      }
    }
    __syncthreads();
    buf ^= 1;
  }
  #pragma unroll
  for (int mi=0;mi<2;++mi)
    #pragma unroll
    for (int nbd=0;nbd<4;++nbd)
      #pragma unroll
      for (int r=0;r<4;++r)
        O[((size_t)(b*KCAP + q0 + mi*16 + g*4 + r))*D_ + h*DH_ + nbd*16 + c] = ftou16(o[mi][nbd][r] / l_[mi][r]);
}

// ---------------- scatter back ----------------
__global__ __launch_bounds__(256) void scatter_k(const int* __restrict__ pos, const float* __restrict__ X,
                                                 const float* __restrict__ hid, float* __restrict__ out0){
  int bs = blockIdx.x; int tid = threadIdx.x;
  int b = bs >> 12;
  int p = pos[bs];
  float* orow = out0 + (size_t)bs*D_;
  if (p >= 0){
    int pc = p < KCAP ? p : (KCAP-1);
    const float* xr = X + ((size_t)(b*KCAP + pc))*D_;
    orow[tid]     = xr[tid];
    orow[tid+256] = xr[tid+256];
    orow[tid+512] = xr[tid+512];
  } else {
    const float* hr = hid + (size_t)bs*D_;
    orow[tid]     = hr[tid];
    orow[tid+256] = hr[tid+256];
    orow[tid+512] = hr[tid+512];
  }
}

__global__ __launch_bounds__(256) void xout_k(const float* __restrict__ X, float* __restrict__ out1){
  int i = blockIdx.x*256 + threadIdx.x;
  out1[i] = X[i];
}

extern "C" void kernel_launch(void* const* d_in, const int* in_sizes, int n_in,
                              void* d_out, int out_size, void* d_ws, size_t ws_size,
                              hipStream_t stream){
  const float* img  = (const float*)d_in[0];
  const float* hid  = (const float*)d_in[1];
  const int*   seq  = (const int*)  d_in[2];
  const float* W[10] = { (const float*)d_in[3], (const float*)d_in[4], (const float*)d_in[5], (const float*)d_in[6],
                         (const float*)d_in[7], (const float*)d_in[8], (const float*)d_in[9], (const float*)d_in[10],
                         (const float*)d_in[11], (const float*)d_in[12] };
  const float* ln1s = (const float*)d_in[13];
  const float* ln1b = (const float*)d_in[14];
  const float* ln2s = (const float*)d_in[15];
  const float* ln2b = (const float*)d_in[16];
  const float* ln3s = (const float*)d_in[17];
  const float* ln3b = (const float*)d_in[18];

  char* ws = (char*)d_ws;
  int*   pos    = (int*)  (ws + 0);          //   131072
  int*   src    = (int*)  (ws + 131072);     //    20480
  int*   counts = (int*)  (ws + 151552);     //      256
  float* X      = (float*)(ws + 151808);     // 15728640
  u16*   T0     = (u16*)  (ws + 15880448);   //  7864320
  u16*   Qb     = (u16*)  (ws + 23744768);   //  7864320
  u16*   Kb     = (u16*)  (ws + 31609088);   // 12582912
  u16*   Vt     = (u16*)  (ws + 44192000);   // 12582912
  u16*   AO     = (u16*)  (ws + 56774912);   //  7864320
  u16*   Wt     = (u16*)  (ws + 64639232);   // 18874368 -> total 83513600
  u16*   MID    = Qb;                        // 31457280, aliases Qb..Vt (dead during FFN)

  // transposed weights: wq_s,wk_s,wv_s contiguous => fused [2304][768]; wk_c,wv_c contiguous => [1536][768]
  u16* wqkv_st = Wt + 0ull*589824;           // rows 0-767 Q, 768-1535 K, 1536-2303 V
  u16* wo_st   = Wt + 3ull*589824;
  u16* wq_ct   = Wt + 4ull*589824;
  u16* wkv_ct  = Wt + 5ull*589824;           // rows 0-767 K, 768-1535 V
  u16* wo_ct   = Wt + 7ull*589824;
  u16* wff1t   = Wt + 8ull*589824;           // [3072][768]
  u16* wff2t   = wff1t + 2359296;            // [768][3072]

  float* out0 = (float*)d_out;
  float* out1 = out0 + (size_t)B_*S_*D_;

  const int MKD = B_*KCAP;   // 5120

  TransArgs ta;
  for (int i=0;i<10;++i) ta.w[i] = W[i];
  for (int i=0;i<8;++i)  ta.o[i] = Wt + (size_t)i*589824;
  ta.o[8] = wff1t; ta.o[9] = wff2t;
  transpose_all<<<9216, 256, 0, stream>>>(ta);

  scan_k  <<<B_,      256, 0, stream>>>(seq, pos, src, counts);
  gather_k<<<B_*KCAP, 256, 0, stream>>>(hid, src, counts, X);

  const int G_QKV = (MKD/128)*(2304/128);    // 40*18 = 720
  const int G_N768= (MKD/64)*(768/128);      // 80*6  = 480
  const int G_KV  = ((B_*N_)/128)*(1536/128);// 64*12 = 768
  const int G_FF1 = (MKD/128)*(FF_/128);     // 40*24 = 960
  const int G_ATT = B_*H_*5;                 // 480

  // ---- self-attention block ----
  ln_k<<<MKD, 256, 0, stream>>>(X, T0, ln1s, ln1b);
  gemm_k<4,128,u16><<<G_QKV, 256, 0, stream>>>(T0, wqkv_st, Qb, Kb, Vt, MKD, 2304, D_, KCAP);
  attn_k<1><<<G_ATT, 256, 0, stream>>>(Qb, Kb, Vt, AO, counts, KCAP);
  gemm_k<1,64,u16><<<G_N768, 256, 0, stream>>>(AO, wo_st, X, nullptr, nullptr, MKD, D_, D_, 0);

  // ---- cross-attention block ----
  ln_k<<<MKD, 256, 0, stream>>>(X, T0, ln2s, ln2b);
  gemm_k<0,64,u16>   <<<G_N768, 256, 0, stream>>>(T0,  wq_ct,  Qb, nullptr, nullptr, MKD,   D_,   D_, 0);
  gemm_k<5,128,float><<<G_KV,   256, 0, stream>>>(img, wkv_ct, Kb, nullptr, Vt,      B_*N_, 1536, D_, N_);
  attn_k<0><<<G_ATT, 256, 0, stream>>>(Qb, Kb, Vt, AO, counts, N_);
  gemm_k<1,64,u16><<<G_N768, 256, 0, stream>>>(AO, wo_ct, X, nullptr, nullptr, MKD, D_, D_, 0);

  // ---- FFN block ----
  ln_k<<<MKD, 256, 0, stream>>>(X, T0, ln3s, ln3b);
  gemm_k<2,128,u16><<<G_FF1,  256, 0, stream>>>(T0,  wff1t, MID, nullptr, nullptr, MKD, FF_, D_,  0);
  gemm_k<1,64,u16> <<<G_N768, 256, 0, stream>>>(MID, wff2t, X,   nullptr, nullptr, MKD, D_,  FF_, 0);

  // ---- outputs ----
  scatter_k<<<B_*S_, 256, 0, stream>>>(pos, X, hid, out0);
  xout_k  <<<(MKD*D_)/256, 256, 0, stream>>>(X, out1);
}

// Round 7
// 478.413 us; speedup vs baseline: 5.4589x; 1.0352x over previous
//
#include <hip/hip_runtime.h>
#include <hip/hip_bf16.h>

// Fetcher: SOC extraction -> [self-attn + cross-attn(img) + GELU-FFN] -> scatter-back.
// Round 6: counted-vmcnt distance-2 prefetch (3 LDS buffers) in GEMM + attention.
//          Raw s_barrier (memory clobber) instead of __syncthreads: prefetch stays in flight.

#define B_    8
#define S_    4096
#define D_    768
#define N_    1024
#define FF_   3072
#define H_    12
#define DH_   64
#define KCAP  640
#define SOC_TOK 3
#define EOS_TOK 2

typedef __hip_bfloat16 bf16;
typedef unsigned short u16;
typedef __attribute__((ext_vector_type(8))) short short8;
typedef __attribute__((ext_vector_type(4))) float f32x4;

__device__ __forceinline__ u16 ftou16(float x){ union{bf16 b; u16 s;} c; c.b = __float2bfloat16(x); return c.s; }
__device__ __forceinline__ unsigned pk2(float lo, float hi){ return (unsigned)ftou16(lo) | ((unsigned)ftou16(hi)<<16); }

__device__ __forceinline__ f32x4 MFMA(short8 a, short8 b, f32x4 c){
  return __builtin_amdgcn_mfma_f32_16x16x32_bf16(a, b, c, 0, 0, 0);
}

// async global->LDS, 16B per lane; LDS dest = wave-uniform base + lane*16
__device__ __forceinline__ void gld16(const void* gp, void* lp){
  __builtin_amdgcn_global_load_lds(
    reinterpret_cast<const __attribute__((address_space(1))) unsigned int*>((size_t)gp),
    reinterpret_cast<__attribute__((address_space(3))) unsigned int*>((size_t)lp),
    16, 0, 0);
}

// counted vmem wait + raw workgroup barrier (no implicit vmcnt(0) drain)
template<int N> __device__ __forceinline__ void vwait(){
  asm volatile("s_waitcnt vmcnt(%0)" :: "i"(N) : "memory");
}
__device__ __forceinline__ void wgbar(){ asm volatile("s_barrier" ::: "memory"); }

// XCD-chunked bijective swizzle (grid divisible by 8).
__device__ __forceinline__ int xcd_swz(){
  int id = blockIdx.x;
  return (id & 7) * ((int)gridDim.x >> 3) + (id >> 3);
}

// ---------------- scan ----------------
__global__ __launch_bounds__(256) void scan_k(const int* __restrict__ seq,
                                              int* __restrict__ pos, int* __restrict__ src,
                                              int* __restrict__ counts){
  int b = blockIdx.x, tid = threadIdx.x;
  __shared__ int sd[256];
  __shared__ int carryE, carryS;
  if (tid==0){ carryE=0; carryS=0; }
  __syncthreads();
  for (int c=0; c<S_; c+=256){
    int s   = c + tid;
    int tok = seq[b*S_ + s];
    int isE = (tok==EOS_TOK) ? 1 : 0;
    int isS = (tok==SOC_TOK) ? 1 : 0;
    sd[tid]=isE; __syncthreads();
    for (int off=1; off<256; off<<=1){ int t_=(tid>=off)?sd[tid-off]:0; __syncthreads(); sd[tid]+=t_; __syncthreads(); }
    int eIncl = sd[tid];
    int eTot  = sd[255];
    int valid = (isS && (carryE + eIncl)==0) ? 1 : 0;
    __syncthreads();
    sd[tid]=valid; __syncthreads();
    for (int off=1; off<256; off<<=1){ int t_=(tid>=off)?sd[tid-off]:0; __syncthreads(); sd[tid]+=t_; __syncthreads(); }
    int vIncl = sd[tid];
    int vTot  = sd[255];
    if (valid){
      int slot = carryS + vIncl - 1;
      pos[b*S_ + s] = slot;
      if (slot < KCAP) src[b*KCAP + slot] = s;
    } else {
      pos[b*S_ + s] = -1;
    }
    __syncthreads();
    if (tid==0){ carryE += eTot; carryS += vTot; }
    __syncthreads();
  }
  if (tid==0) counts[b] = (carryS < KCAP) ? carryS : KCAP;
}

// ---------------- gather ----------------
__global__ __launch_bounds__(256) void gather_k(const float* __restrict__ hid,
                                                const int* __restrict__ src,
                                                const int* __restrict__ counts,
                                                float* __restrict__ X){
  int bk = blockIdx.x; int b = bk / KCAP; int k = bk % KCAP;
  int tid = threadIdx.x;
  int cnt = counts[b];
  float* xr = X + (size_t)bk*D_;
  if (k < cnt){
    int s = src[b*KCAP + k];
    const float* hr = hid + ((size_t)b*S_ + s)*D_;
    xr[tid] = hr[tid]; xr[tid+256] = hr[tid+256]; xr[tid+512] = hr[tid+512];
  } else {
    xr[tid] = 0.f; xr[tid+256] = 0.f; xr[tid+512] = 0.f;
  }
}

// ---------------- all weight transposes in one launch: f32 [K][N] -> bf16 [N][K] ----------------
struct TransArgs { const float* w[10]; u16* o[10]; };
__global__ __launch_bounds__(256) void transpose_all(TransArgs a){
  __shared__ float tile[32][33];
  int id = blockIdx.x;
  int wi, t, K, N;
  if (id < 4608){ wi = id/576; t = id%576; K = 768; N = 768; }
  else if (id < 6912){ wi = 8; t = id-4608; K = 768; N = 3072; }
  else { wi = 9; t = id-6912; K = 3072; N = 768; }
  const float* in = a.w[wi]; u16* out = a.o[wi];
  int nbx = N >> 5;
  int bx = t % nbx, by = t / nbx;
  int tx = threadIdx.x & 31, ty = threadIdx.x >> 5;
  #pragma unroll
  for (int i=0;i<4;++i)
    tile[ty + i*8][tx] = in[(size_t)(by*32 + ty + i*8)*N + bx*32 + tx];
  __syncthreads();
  #pragma unroll
  for (int i=0;i<4;++i)
    out[(size_t)(bx*32 + ty + i*8)*K + by*32 + tx] = ftou16(tile[tx][ty + i*8]);
}

// ---------------- layernorm ----------------
__global__ __launch_bounds__(256) void ln_k(const float* __restrict__ X, u16* __restrict__ Y,
                                            const float* __restrict__ g, const float* __restrict__ bt){
  int r = blockIdx.x; int tid = threadIdx.x;
  const float* xr = X + (size_t)r*D_;
  float v0=xr[tid], v1=xr[tid+256], v2=xr[tid+512];
  float s1=v0+v1+v2, s2=v0*v0+v1*v1+v2*v2;
  for (int off=32; off; off>>=1){ s1+=__shfl_xor(s1,off); s2+=__shfl_xor(s2,off); }
  __shared__ float red[8];
  __shared__ float mu_s, rs_s;
  int w=tid>>6, ln=tid&63;
  if (ln==0){ red[w]=s1; red[4+w]=s2; }
  __syncthreads();
  if (tid==0){
    float S1=red[0]+red[1]+red[2]+red[3];
    float S2=red[4]+red[5]+red[6]+red[7];
    float mu = S1*(1.f/D_);
    float var= S2*(1.f/D_) - mu*mu;
    mu_s=mu; rs_s=rsqrtf(var + 1e-5f);
  }
  __syncthreads();
  float mu=mu_s, rs=rs_s;
  u16* yr = Y + (size_t)r*D_;
  yr[tid]     = ftou16((v0-mu)*rs*g[tid]     + bt[tid]);
  yr[tid+256] = ftou16((v1-mu)*rs*g[tid+256] + bt[tid+256]);
  yr[tid+512] = ftou16((v2-mu)*rs*g[tid+512] + bt[tid+512]);
}

// ---------------- MFMA GEMM: C[M][N] = A[M][K] @ Bt[N][K]^T ----------------
// bf16-A path: 3-buffer distance-2 counted-vmcnt pipeline. f32-A path: 2-buffer __syncthreads.
// MODE 0: C0_bf16[M][N] ; 1: C0_f32 += ; 2: C0_bf16 = gelu ;
// MODE 4: self QKV (N=2304): cols 0-767->C0(Q), 768-1535->C1(K), 1536-2303->C2 = V^T [b][768][KCAP]
// MODE 5: cross KV (N=1536): cols 0-767->C0(K), 768-1535->C2 = V^T [b][768][1024]
template<int MODE, int BM, typename TA>
__global__ __launch_bounds__(256) void gemm_k(const TA* __restrict__ A, const u16* __restrict__ Bt,
                                              void* __restrict__ C0, void* __restrict__ C1, void* __restrict__ C2,
                                              int M, int N, int K, int Lkv){
  constexpr int MI  = (BM==128) ? 4 : 2;
  constexpr int LPS = (BM==128) ? 4 : 3;   // gld16 per wave per step (A + B)
  __shared__ __align__(16) u16 As[3][BM*32];
  __shared__ __align__(16) u16 Bs[3][128*32];
  int nbx = N >> 7;
  int wgid = xcd_swz();
  int bx = wgid % nbx, by = wgid / nbx;
  int tid = threadIdx.x;
  int w = tid>>6, l = tid&63, g = l>>4, c = l&15;
  int wr = w&1, wc = w>>1;
  f32x4 acc[MI][4] = {};
  float4 rg[4];
  const int NK = K/32;

  auto STAGEB = [&](int buf, int kt){
    #pragma unroll
    for (int p=0;p<2;++p){
      int row = w*32 + p*16 + (l>>2);
      int su  = (l&3) ^ ((row>>1)&3);
      gld16((const void*)(Bt + (size_t)(bx*128+row)*K + kt + su*8), (void*)&Bs[buf][(w*32+p*16)*32]);
    }
  };
  auto STAGEA16 = [&](int buf, int kt){
    if constexpr (BM==128){
      #pragma unroll
      for (int p=0;p<2;++p){
        int row = w*32 + p*16 + (l>>2);
        int su  = (l&3) ^ ((row>>1)&3);
        gld16((const void*)((const u16*)A + (size_t)(by*BM+row)*K + kt + su*8), (void*)&As[buf][(w*32+p*16)*32]);
      }
    } else {
      int row = w*16 + (l>>2);
      int su  = (l&3) ^ ((row>>1)&3);
      gld16((const void*)((const u16*)A + (size_t)(by*BM+row)*K + kt + su*8), (void*)&As[buf][(w*16)*32]);
    }
  };
  auto LOADREG = [&](int kt){
    const float* ap = (const float*)A + (size_t)(by*128 + (tid>>1))*K + kt + (tid&1)*16;
    rg[0]=*(const float4*)ap;     rg[1]=*(const float4*)(ap+4);
    rg[2]=*(const float4*)(ap+8); rg[3]=*(const float4*)(ap+12);
  };
  auto WRITEA = [&](int buf){
    int row = tid>>1, half = tid&1;
    uint4 w0,w1;
    w0.x=pk2(rg[0].x,rg[0].y); w0.y=pk2(rg[0].z,rg[0].w); w0.z=pk2(rg[1].x,rg[1].y); w0.w=pk2(rg[1].z,rg[1].w);
    w1.x=pk2(rg[2].x,rg[2].y); w1.y=pk2(rg[2].z,rg[2].w); w1.z=pk2(rg[3].x,rg[3].y); w1.w=pk2(rg[3].z,rg[3].w);
    int sw = (row>>1)&3;
    *(uint4*)&As[buf][row*32 + ((half*2  )^sw)*8] = w0;
    *(uint4*)&As[buf][row*32 + ((half*2+1)^sw)*8] = w1;
  };
  auto COMPUTE = [&](int buf){
    short8 af[MI], bfr[4];
    #pragma unroll
    for (int mi=0;mi<MI;++mi){ int row = wr*(MI*16) + mi*16 + c; af[mi]  = *(const short8*)&As[buf][row*32 + (g^((row>>1)&3))*8]; }
    #pragma unroll
    for (int ni=0;ni<4;++ni){ int row = wc*64 + ni*16 + c;       bfr[ni] = *(const short8*)&Bs[buf][row*32 + (g^((row>>1)&3))*8]; }
    #pragma unroll
    for (int mi=0;mi<MI;++mi)
      #pragma unroll
      for (int ni=0;ni<4;++ni) acc[mi][ni] = MFMA(af[mi], bfr[ni], acc[mi][ni]);
  };

  if constexpr (sizeof(TA)==4){
    // f32-A path: 2-buffer, __syncthreads (compiler-managed waits)
    LOADREG(0); STAGEB(0,0); WRITEA(0);
    __syncthreads();
    int buf = 0;
    for (int t=0;t<NK;++t){
      int ktn = (t+1)*32;
      if (t+1<NK){ LOADREG(ktn); STAGEB(buf^1, ktn); }
      COMPUTE(buf);
      if (t+1<NK) WRITEA(buf^1);
      __syncthreads();
      buf ^= 1;
    }
  } else {
    // bf16-A path: 3-buffer distance-2 counted-vmcnt pipeline
    STAGEA16(0,0);  STAGEB(0,0);      // oldest LPS
    STAGEA16(1,32); STAGEB(1,32);     // next LPS
    vwait<LPS>();                     // buf0 landed (per wave)
    wgbar();                          // all waves' buf0 landed
    int buf = 0;
    for (int t=0;t<NK;++t){
      if (t+2 < NK){
        int nb = buf+2; if (nb>=3) nb-=3;
        STAGEA16(nb,(t+2)*32); STAGEB(nb,(t+2)*32);
      }
      COMPUTE(buf);
      if (t < NK-2) vwait<LPS>(); else vwait<0>();
      wgbar();
      ++buf; if (buf==3) buf=0;
    }
  }

  int row0 = by*BM + wr*(MI*16), col0 = bx*128 + wc*64;
  #pragma unroll
  for (int mi=0;mi<MI;++mi)
    #pragma unroll
    for (int ni=0;ni<4;++ni)
      #pragma unroll
      for (int r=0;r<4;++r){
        int row = row0 + mi*16 + g*4 + r;
        int col = col0 + ni*16 + c;
        float v = acc[mi][ni][r];
        if (MODE==0){
          ((u16*)C0)[(size_t)row*N + col] = ftou16(v);
        } else if (MODE==1){
          ((float*)C0)[(size_t)row*N + col] += v;
        } else if (MODE==2){
          float z2 = 1.5957691216057308f*(v + 0.044715f*v*v*v);
          float e  = __expf(z2);
          float th = 1.f - 2.f/(e + 1.f);
          ((u16*)C0)[(size_t)row*N + col] = ftou16(0.5f*v*(1.f+th));
        } else if (MODE==4){
          if (col < 768)       ((u16*)C0)[(size_t)row*768 + col]       = ftou16(v);
          else if (col < 1536) ((u16*)C1)[(size_t)row*768 + col - 768] = ftou16(v);
          else {
            int vv = col - 1536; int bb = row / KCAP; int key = row - bb*KCAP;
            ((u16*)C2)[((size_t)(bb*768 + vv))*KCAP + key] = ftou16(v);
          }
        } else { // MODE 5
          if (col < 768) ((u16*)C0)[(size_t)row*768 + col] = ftou16(v);
          else {
            int vv = col - 768; int bb = row >> 10; int key = row & 1023;
            ((u16*)C2)[((size_t)(bb*768 + vv))*1024 + key] = ftou16(v);
          }
        }
      }
}

// ---------------- MFMA flash attention: 3-buffer distance-2 counted-vmcnt K/V pipeline ----------------
template<int MASKED>
__global__ __launch_bounds__(256) void attn_k(const u16* __restrict__ Q, const u16* __restrict__ Kb,
                                              const u16* __restrict__ Vt, u16* __restrict__ O,
                                              const int* __restrict__ counts, int Lk){
  __shared__ __align__(16) u16 Ks[3][64*64];
  __shared__ __align__(16) u16 Vs[3][64*64];
  __shared__ __align__(16) u16 P[4][16][72];
  int tid = threadIdx.x;
  int w = tid>>6, l = tid&63, g = l>>4, c = l&15;
  int wgid = xcd_swz();
  int qc = wgid % 5;
  int bh = wgid / 5;
  int h = bh % H_, b = bh / H_;
  int q0 = qc*128 + w*32;
  int cnt = MASKED ? counts[b] : Lk;
  int nt = (cnt + 63) >> 6;

  short8 qf[2][2];
  #pragma unroll
  for (int mi=0;mi<2;++mi){
    const u16* Qrow = Q + ((size_t)(b*KCAP + q0 + mi*16 + c))*D_ + h*DH_;
    qf[mi][0] = *(const short8*)(Qrow + g*8);
    qf[mi][1] = *(const short8*)(Qrow + 32 + g*8);
  }

  int srow8 = (l>>3);
  int sunit = l&7;
  auto STAGE = [&](int buf, int kb){    // 4 gld16 per wave
    #pragma unroll
    for (int p=0;p<2;++p){
      int r0 = w*16 + p*8;
      int rowK = r0 + srow8;
      int su = sunit ^ (rowK&7);
      gld16((const void*)(Kb + ((size_t)(b*Lk + kb + rowK))*D_ + h*DH_ + su*8), (void*)&Ks[buf][r0*64]);
      gld16((const void*)(Vt + ((size_t)(b*D_ + h*DH_ + rowK))*Lk + kb + su*8), (void*)&Vs[buf][r0*64]);
    }
  };

  f32x4 o[2][4] = {};
  float m_[2][4], l_[2][4] = {};
  #pragma unroll
  for (int mi=0;mi<2;++mi)
    #pragma unroll
    for (int r=0;r<4;++r) m_[mi][r] = -1e30f;

  STAGE(0, 0);
  if (nt > 1){ STAGE(1, 64); vwait<4>(); } else { vwait<0>(); }
  wgbar();
  int buf = 0;
  for (int t=0; t<nt; ++t){
    int kb = t*64;
    if (t+2 < nt){
      int nb = buf+2; if (nb>=3) nb-=3;
      STAGE(nb, kb+128);
    }
    short8 fr[4][2];
    #pragma unroll
    for (int nb=0;nb<4;++nb)
      #pragma unroll
      for (int kh=0;kh<2;++kh)
        fr[nb][kh] = *(const short8*)&Ks[buf][(nb*16+c)*64 + (((kh<<2)|g) ^ (c&7))*8];
    f32x4 z[2][4];
    #pragma unroll
    for (int mi=0;mi<2;++mi)
      #pragma unroll
      for (int nb=0;nb<4;++nb){
        f32x4 zz = {0.f,0.f,0.f,0.f};
        zz = MFMA(qf[mi][0], fr[nb][0], zz);
        zz = MFMA(qf[mi][1], fr[nb][1], zz);
        z[mi][nb] = zz;
      }
    float pv[2][4][4];
    #pragma unroll
    for (int nb=0;nb<4;++nb){
      bool msk = MASKED && (kb + nb*16 + c >= cnt);
      #pragma unroll
      for (int mi=0;mi<2;++mi)
        #pragma unroll
        for (int r=0;r<4;++r) pv[mi][nb][r] = msk ? -1e30f : z[mi][nb][r]*0.125f;
    }
    float scl[2][4];
    #pragma unroll
    for (int mi=0;mi<2;++mi){
      #pragma unroll
      for (int r=0;r<4;++r){
        float v = fmaxf(fmaxf(pv[mi][0][r],pv[mi][1][r]), fmaxf(pv[mi][2][r],pv[mi][3][r]));
        v = fmaxf(v, __shfl_xor(v,1)); v = fmaxf(v, __shfl_xor(v,2));
        v = fmaxf(v, __shfl_xor(v,4)); v = fmaxf(v, __shfl_xor(v,8));
        float nm = fmaxf(m_[mi][r], v);
        scl[mi][r] = __expf(m_[mi][r] - nm);
        m_[mi][r] = nm;
      }
      #pragma unroll
      for (int r=0;r<4;++r){
        float acc2 = 0.f;
        #pragma unroll
        for (int nb=0;nb<4;++nb){
          float e = __expf(pv[mi][nb][r] - m_[mi][r]);
          pv[mi][nb][r] = e; acc2 += e;
        }
        acc2 += __shfl_xor(acc2,1); acc2 += __shfl_xor(acc2,2);
        acc2 += __shfl_xor(acc2,4); acc2 += __shfl_xor(acc2,8);
        l_[mi][r] = l_[mi][r]*scl[mi][r] + acc2;
      }
      #pragma unroll
      for (int nbd=0;nbd<4;++nbd)
        #pragma unroll
        for (int r=0;r<4;++r) o[mi][nbd][r] *= scl[mi][r];
    }
    #pragma unroll
    for (int nbd=0;nbd<4;++nbd)
      #pragma unroll
      for (int kh=0;kh<2;++kh)
        fr[nbd][kh] = *(const short8*)&Vs[buf][(nbd*16+c)*64 + (((kh<<2)|g) ^ (c&7))*8];
    #pragma unroll
    for (int mi=0;mi<2;++mi){
      #pragma unroll
      for (int nb=0;nb<4;++nb)
        #pragma unroll
        for (int r=0;r<4;++r) P[w][g*4+r][nb*16+c] = ftou16(pv[mi][nb][r]);
      short8 pa0 = *(const short8*)&P[w][c][g*8];
      short8 pa1 = *(const short8*)&P[w][c][32 + g*8];
      #pragma unroll
      for (int nbd=0;nbd<4;++nbd){
        o[mi][nbd] = MFMA(pa0, fr[nbd][0], o[mi][nbd]);
        o[mi][nbd] = MFMA(pa1, fr[nbd][1], o[mi][nbd]);
      }
    }
    if (t < nt-2) vwait<4>(); else vwait<0>();
    wgbar();
    ++buf; if (buf==3) buf=0;
  }
  #pragma unroll
  for (int mi=0;mi<2;++mi)
    #pragma unroll
    for (int nbd=0;nbd<4;++nbd)
      #pragma unroll
      for (int r=0;r<4;++r)
        O[((size_t)(b*KCAP + q0 + mi*16 + g*4 + r))*D_ + h*DH_ + nbd*16 + c] = ftou16(o[mi][nbd][r] / l_[mi][r]);
}

// ---------------- scatter back ----------------
__global__ __launch_bounds__(256) void scatter_k(const int* __restrict__ pos, const float* __restrict__ X,
                                                 const float* __restrict__ hid, float* __restrict__ out0){
  int bs = blockIdx.x; int tid = threadIdx.x;
  int b = bs >> 12;
  int p = pos[bs];
  float* orow = out0 + (size_t)bs*D_;
  if (p >= 0){
    int pc = p < KCAP ? p : (KCAP-1);
    const float* xr = X + ((size_t)(b*KCAP + pc))*D_;
    orow[tid]     = xr[tid];
    orow[tid+256] = xr[tid+256];
    orow[tid+512] = xr[tid+512];
  } else {
    const float* hr = hid + (size_t)bs*D_;
    orow[tid]     = hr[tid];
    orow[tid+256] = hr[tid+256];
    orow[tid+512] = hr[tid+512];
  }
}

__global__ __launch_bounds__(256) void xout_k(const float* __restrict__ X, float* __restrict__ out1){
  int i = blockIdx.x*256 + threadIdx.x;
  out1[i] = X[i];
}

extern "C" void kernel_launch(void* const* d_in, const int* in_sizes, int n_in,
                              void* d_out, int out_size, void* d_ws, size_t ws_size,
                              hipStream_t stream){
  const float* img  = (const float*)d_in[0];
  const float* hid  = (const float*)d_in[1];
  const int*   seq  = (const int*)  d_in[2];
  const float* W[10] = { (const float*)d_in[3], (const float*)d_in[4], (const float*)d_in[5], (const float*)d_in[6],
                         (const float*)d_in[7], (const float*)d_in[8], (const float*)d_in[9], (const float*)d_in[10],
                         (const float*)d_in[11], (const float*)d_in[12] };
  const float* ln1s = (const float*)d_in[13];
  const float* ln1b = (const float*)d_in[14];
  const float* ln2s = (const float*)d_in[15];
  const float* ln2b = (const float*)d_in[16];
  const float* ln3s = (const float*)d_in[17];
  const float* ln3b = (const float*)d_in[18];

  char* ws = (char*)d_ws;
  int*   pos    = (int*)  (ws + 0);          //   131072
  int*   src    = (int*)  (ws + 131072);     //    20480
  int*   counts = (int*)  (ws + 151552);     //      256
  float* X      = (float*)(ws + 151808);     // 15728640
  u16*   T0     = (u16*)  (ws + 15880448);   //  7864320
  u16*   Qb     = (u16*)  (ws + 23744768);   //  7864320
  u16*   Kb     = (u16*)  (ws + 31609088);   // 12582912
  u16*   Vt     = (u16*)  (ws + 44192000);   // 12582912
  u16*   AO     = (u16*)  (ws + 56774912);   //  7864320
  u16*   Wt     = (u16*)  (ws + 64639232);   // 18874368 -> total 83513600
  u16*   MID    = Qb;                        // 31457280, aliases Qb..Vt (dead during FFN)

  u16* wqkv_st = Wt + 0ull*589824;           // rows 0-767 Q, 768-1535 K, 1536-2303 V
  u16* wo_st   = Wt + 3ull*589824;
  u16* wq_ct   = Wt + 4ull*589824;
  u16* wkv_ct  = Wt + 5ull*589824;           // rows 0-767 K, 768-1535 V
  u16* wo_ct   = Wt + 7ull*589824;
  u16* wff1t   = Wt + 8ull*589824;           // [3072][768]
  u16* wff2t   = wff1t + 2359296;            // [768][3072]

  float* out0 = (float*)d_out;
  float* out1 = out0 + (size_t)B_*S_*D_;

  const int MKD = B_*KCAP;   // 5120

  TransArgs ta;
  for (int i=0;i<10;++i) ta.w[i] = W[i];
  for (int i=0;i<8;++i)  ta.o[i] = Wt + (size_t)i*589824;
  ta.o[8] = wff1t; ta.o[9] = wff2t;
  transpose_all<<<9216, 256, 0, stream>>>(ta);

  scan_k  <<<B_,      256, 0, stream>>>(seq, pos, src, counts);
  gather_k<<<B_*KCAP, 256, 0, stream>>>(hid, src, counts, X);

  const int G_QKV = (MKD/128)*(2304/128);    // 720
  const int G_N768= (MKD/64)*(768/128);      // 480
  const int G_KV  = ((B_*N_)/128)*(1536/128);// 768
  const int G_FF1 = (MKD/128)*(FF_/128);     // 960
  const int G_ATT = B_*H_*5;                 // 480

  // ---- self-attention block ----
  ln_k<<<MKD, 256, 0, stream>>>(X, T0, ln1s, ln1b);
  gemm_k<4,128,u16><<<G_QKV, 256, 0, stream>>>(T0, wqkv_st, Qb, Kb, Vt, MKD, 2304, D_, KCAP);
  attn_k<1><<<G_ATT, 256, 0, stream>>>(Qb, Kb, Vt, AO, counts, KCAP);
  gemm_k<1,64,u16><<<G_N768, 256, 0, stream>>>(AO, wo_st, X, nullptr, nullptr, MKD, D_, D_, 0);

  // ---- cross-attention block ----
  ln_k<<<MKD, 256, 0, stream>>>(X, T0, ln2s, ln2b);
  gemm_k<0,64,u16>   <<<G_N768, 256, 0, stream>>>(T0,  wq_ct,  Qb, nullptr, nullptr, MKD,   D_,   D_, 0);
  gemm_k<5,128,float><<<G_KV,   256, 0, stream>>>(img, wkv_ct, Kb, nullptr, Vt,      B_*N_, 1536, D_, N_);
  attn_k<0><<<G_ATT, 256, 0, stream>>>(Qb, Kb, Vt, AO, counts, N_);
  gemm_k<1,64,u16><<<G_N768, 256, 0, stream>>>(AO, wo_ct, X, nullptr, nullptr, MKD, D_, D_, 0);

  // ---- FFN block ----
  ln_k<<<MKD, 256, 0, stream>>>(X, T0, ln3s, ln3b);
  gemm_k<2,128,u16><<<G_FF1,  256, 0, stream>>>(T0,  wff1t, MID, nullptr, nullptr, MKD, FF_, D_,  0);
  gemm_k<1,64,u16> <<<G_N768, 256, 0, stream>>>(MID, wff2t, X,   nullptr, nullptr, MKD, D_,  FF_, 0);

  // ---- outputs ----
  scatter_k<<<B_*S_, 256, 0, stream>>>(pos, X, hid, out0);
  xout_k  <<<(MKD*D_)/256, 256, 0, stream>>>(X, out1);
}

// Round 8
// 474.448 us; speedup vs baseline: 5.5045x; 1.0084x over previous
//
#include <hip/hip_runtime.h>
#include <hip/hip_bf16.h>

// Fetcher: SOC extraction -> [self-attn + cross-attn(img) + GELU-FFN] -> scatter-back.
// Round 7: machine-filling round. BM=64 (4 blocks/CU) for all GEMMs, q_c+imgKV fused
//          dual dispatch, scan+transpose fused, gather+ln1 fused, FF2 writes out1 (MODE 6).

#define B_    8
#define S_    4096
#define D_    768
#define N_    1024
#define FF_   3072
#define H_    12
#define DH_   64
#define KCAP  640
#define SOC_TOK 3
#define EOS_TOK 2

typedef __hip_bfloat16 bf16;
typedef unsigned short u16;
typedef __attribute__((ext_vector_type(8))) short short8;
typedef __attribute__((ext_vector_type(4))) float f32x4;

__device__ __forceinline__ u16 ftou16(float x){ union{bf16 b; u16 s;} c; c.b = __float2bfloat16(x); return c.s; }
__device__ __forceinline__ unsigned pk2(float lo, float hi){ return (unsigned)ftou16(lo) | ((unsigned)ftou16(hi)<<16); }

__device__ __forceinline__ f32x4 MFMA(short8 a, short8 b, f32x4 c){
  return __builtin_amdgcn_mfma_f32_16x16x32_bf16(a, b, c, 0, 0, 0);
}

__device__ __forceinline__ void gld16(const void* gp, void* lp){
  __builtin_amdgcn_global_load_lds(
    reinterpret_cast<const __attribute__((address_space(1))) unsigned int*>((size_t)gp),
    reinterpret_cast<__attribute__((address_space(3))) unsigned int*>((size_t)lp),
    16, 0, 0);
}

template<int N> __device__ __forceinline__ void vwait(){
  asm volatile("s_waitcnt vmcnt(%0)" :: "i"(N) : "memory");
}
__device__ __forceinline__ void wgbar(){ asm volatile("s_barrier" ::: "memory"); }

// XCD-chunked bijective swizzle (grid divisible by 8).
__device__ __forceinline__ int xcd_swz(){
  int id = blockIdx.x;
  return (id & 7) * ((int)gridDim.x >> 3) + (id >> 3);
}

// ---------------- scan body ----------------
__device__ void scan_body(const int* __restrict__ seq, int* __restrict__ pos,
                          int* __restrict__ src, int* __restrict__ counts, int b){
  int tid = threadIdx.x;
  __shared__ int sd[256];
  __shared__ int carryE, carryS;
  if (tid==0){ carryE=0; carryS=0; }
  __syncthreads();
  for (int c=0; c<S_; c+=256){
    int s   = c + tid;
    int tok = seq[b*S_ + s];
    int isE = (tok==EOS_TOK) ? 1 : 0;
    int isS = (tok==SOC_TOK) ? 1 : 0;
    sd[tid]=isE; __syncthreads();
    for (int off=1; off<256; off<<=1){ int t_=(tid>=off)?sd[tid-off]:0; __syncthreads(); sd[tid]+=t_; __syncthreads(); }
    int eIncl = sd[tid];
    int eTot  = sd[255];
    int valid = (isS && (carryE + eIncl)==0) ? 1 : 0;
    __syncthreads();
    sd[tid]=valid; __syncthreads();
    for (int off=1; off<256; off<<=1){ int t_=(tid>=off)?sd[tid-off]:0; __syncthreads(); sd[tid]+=t_; __syncthreads(); }
    int vIncl = sd[tid];
    int vTot  = sd[255];
    if (valid){
      int slot = carryS + vIncl - 1;
      pos[b*S_ + s] = slot;
      if (slot < KCAP) src[b*KCAP + slot] = s;
    } else {
      pos[b*S_ + s] = -1;
    }
    __syncthreads();
    if (tid==0){ carryE += eTot; carryS += vTot; }
    __syncthreads();
  }
  if (tid==0) counts[b] = (carryS < KCAP) ? carryS : KCAP;
}

// ---------------- transpose (f32 [K][N] -> bf16 [N][K]) + scan, one launch ----------------
struct TransArgs { const float* w[10]; u16* o[10]; };
__global__ __launch_bounds__(256) void transpose_scan_k(TransArgs a, const int* __restrict__ seq,
                                                        int* __restrict__ pos, int* __restrict__ src,
                                                        int* __restrict__ counts){
  int id = blockIdx.x;
  if (id >= 9216){ scan_body(seq, pos, src, counts, id - 9216); return; }
  __shared__ float tile[32][33];
  int wi, t, K, N;
  if (id < 4608){ wi = id/576; t = id%576; K = 768; N = 768; }
  else if (id < 6912){ wi = 8; t = id-4608; K = 768; N = 3072; }
  else { wi = 9; t = id-6912; K = 3072; N = 768; }
  const float* in = a.w[wi]; u16* out = a.o[wi];
  int nbx = N >> 5;
  int bx = t % nbx, by = t / nbx;
  int tx = threadIdx.x & 31, ty = threadIdx.x >> 5;
  #pragma unroll
  for (int i=0;i<4;++i)
    tile[ty + i*8][tx] = in[(size_t)(by*32 + ty + i*8)*N + bx*32 + tx];
  __syncthreads();
  #pragma unroll
  for (int i=0;i<4;++i)
    out[(size_t)(bx*32 + ty + i*8)*K + by*32 + tx] = ftou16(tile[tx][ty + i*8]);
}

// ---------------- gather + LN1 fused: X=gather(hid); T0=LN(X) ----------------
__global__ __launch_bounds__(256) void gather_ln_k(const float* __restrict__ hid,
                                                   const int* __restrict__ src,
                                                   const int* __restrict__ counts,
                                                   const float* __restrict__ g, const float* __restrict__ bt,
                                                   float* __restrict__ X, u16* __restrict__ T0){
  int bk = blockIdx.x; int b = bk / KCAP; int k = bk % KCAP;
  int tid = threadIdx.x;
  float v0, v1, v2;
  if (k < counts[b]){
    const float* hr = hid + ((size_t)b*S_ + src[b*KCAP + k])*D_;
    v0 = hr[tid]; v1 = hr[tid+256]; v2 = hr[tid+512];
  } else { v0 = v1 = v2 = 0.f; }
  float* xr = X + (size_t)bk*D_;
  xr[tid] = v0; xr[tid+256] = v1; xr[tid+512] = v2;
  float s1=v0+v1+v2, s2=v0*v0+v1*v1+v2*v2;
  for (int off=32; off; off>>=1){ s1+=__shfl_xor(s1,off); s2+=__shfl_xor(s2,off); }
  __shared__ float red[8];
  __shared__ float mu_s, rs_s;
  int w=tid>>6, ln=tid&63;
  if (ln==0){ red[w]=s1; red[4+w]=s2; }
  __syncthreads();
  if (tid==0){
    float S1=red[0]+red[1]+red[2]+red[3];
    float S2=red[4]+red[5]+red[6]+red[7];
    float mu = S1*(1.f/D_);
    float var= S2*(1.f/D_) - mu*mu;
    mu_s=mu; rs_s=rsqrtf(var + 1e-5f);
  }
  __syncthreads();
  float mu=mu_s, rs=rs_s;
  u16* yr = T0 + (size_t)bk*D_;
  yr[tid]     = ftou16((v0-mu)*rs*g[tid]     + bt[tid]);
  yr[tid+256] = ftou16((v1-mu)*rs*g[tid+256] + bt[tid+256]);
  yr[tid+512] = ftou16((v2-mu)*rs*g[tid+512] + bt[tid+512]);
}

// ---------------- layernorm ----------------
__global__ __launch_bounds__(256) void ln_k(const float* __restrict__ X, u16* __restrict__ Y,
                                            const float* __restrict__ g, const float* __restrict__ bt){
  int r = blockIdx.x; int tid = threadIdx.x;
  const float* xr = X + (size_t)r*D_;
  float v0=xr[tid], v1=xr[tid+256], v2=xr[tid+512];
  float s1=v0+v1+v2, s2=v0*v0+v1*v1+v2*v2;
  for (int off=32; off; off>>=1){ s1+=__shfl_xor(s1,off); s2+=__shfl_xor(s2,off); }
  __shared__ float red[8];
  __shared__ float mu_s, rs_s;
  int w=tid>>6, ln=tid&63;
  if (ln==0){ red[w]=s1; red[4+w]=s2; }
  __syncthreads();
  if (tid==0){
    float S1=red[0]+red[1]+red[2]+red[3];
    float S2=red[4]+red[5]+red[6]+red[7];
    float mu = S1*(1.f/D_);
    float var= S2*(1.f/D_) - mu*mu;
    mu_s=mu; rs_s=rsqrtf(var + 1e-5f);
  }
  __syncthreads();
  float mu=mu_s, rs=rs_s;
  u16* yr = Y + (size_t)r*D_;
  yr[tid]     = ftou16((v0-mu)*rs*g[tid]     + bt[tid]);
  yr[tid+256] = ftou16((v1-mu)*rs*g[tid+256] + bt[tid+256]);
  yr[tid+512] = ftou16((v2-mu)*rs*g[tid+512] + bt[tid+512]);
}

// ---------------- MFMA GEMM body: C[M][N] = A[M][K] @ Bt[N][K]^T, BM=64, BN=128 ----------------
// MODE 0: C0_bf16 ; 1: C0_f32 += ; 2: C0_bf16 = gelu ; 6: C0_f32 +=, C1_f32 = result
// MODE 4: self QKV (N=2304): cols 0-767->C0(Q), 768-1535->C1(K), 1536-2303->C2 = V^T [b][768][KCAP]
// MODE 5: cross KV (N=1536): cols 0-767->C0(K), 768-1535->C2 = V^T [b][768][1024]
template<int MODE, typename TA>
__device__ __forceinline__ void gemm_body(char* ldsp, const TA* __restrict__ A, const u16* __restrict__ Bt,
                                          void* __restrict__ C0, void* __restrict__ C1, void* __restrict__ C2,
                                          int wgid, int N, int K){
  constexpr int BM = 64, MI = 2, LPS = 3;
  constexpr int NBUF = (sizeof(TA)==4) ? 2 : 3;
  u16* As = (u16*)ldsp;                           // [NBUF][64*32]
  u16* Bs = (u16*)(ldsp + NBUF*(BM*32)*2);        // [NBUF][128*32]
  int nbx = N >> 7;
  int bx = wgid % nbx, by = wgid / nbx;
  int tid = threadIdx.x;
  int w = tid>>6, l = tid&63, g = l>>4, c = l&15;
  int wr = w&1, wc = w>>1;
  f32x4 acc[MI][4] = {};
  float4 rg0, rg1;
  const int NK = K/32;

  auto STAGEB = [&](int buf, int kt){
    #pragma unroll
    for (int p=0;p<2;++p){
      int row = w*32 + p*16 + (l>>2);
      int su  = (l&3) ^ ((row>>1)&3);
      gld16((const void*)(Bt + (size_t)(bx*128+row)*K + kt + su*8), (void*)&Bs[buf*128*32 + (w*32+p*16)*32]);
    }
  };
  auto STAGEA16 = [&](int buf, int kt){
    int row = w*16 + (l>>2);
    int su  = (l&3) ^ ((row>>1)&3);
    gld16((const void*)((const u16*)A + (size_t)(by*BM+row)*K + kt + su*8), (void*)&As[buf*BM*32 + (w*16)*32]);
  };
  auto LOADREG = [&](int kt){
    const float* ap = (const float*)A + (size_t)(by*BM + (tid>>2))*K + kt + (tid&3)*8;
    rg0 = *(const float4*)ap; rg1 = *(const float4*)(ap+4);
  };
  auto WRITEA = [&](int buf){
    int row = tid>>2, unit = tid&3;
    uint4 wv;
    wv.x=pk2(rg0.x,rg0.y); wv.y=pk2(rg0.z,rg0.w); wv.z=pk2(rg1.x,rg1.y); wv.w=pk2(rg1.z,rg1.w);
    int sw = (row>>1)&3;
    *(uint4*)&As[buf*BM*32 + row*32 + (unit^sw)*8] = wv;
  };
  auto COMPUTE = [&](int buf){
    short8 af[MI], bfr[4];
    #pragma unroll
    for (int mi=0;mi<MI;++mi){ int row = wr*32 + mi*16 + c; af[mi]  = *(const short8*)&As[buf*BM*32 + row*32 + (g^((row>>1)&3))*8]; }
    #pragma unroll
    for (int ni=0;ni<4;++ni){ int row = wc*64 + ni*16 + c;  bfr[ni] = *(const short8*)&Bs[buf*128*32 + row*32 + (g^((row>>1)&3))*8]; }
    #pragma unroll
    for (int mi=0;mi<MI;++mi)
      #pragma unroll
      for (int ni=0;ni<4;++ni) acc[mi][ni] = MFMA(af[mi], bfr[ni], acc[mi][ni]);
  };

  if constexpr (sizeof(TA)==4){
    // f32-A path: 2-buffer, __syncthreads
    LOADREG(0); STAGEB(0,0); WRITEA(0);
    __syncthreads();
    int buf = 0;
    for (int t=0;t<NK;++t){
      int ktn = (t+1)*32;
      if (t+1<NK){ LOADREG(ktn); STAGEB(buf^1, ktn); }
      COMPUTE(buf);
      if (t+1<NK) WRITEA(buf^1);
      __syncthreads();
      buf ^= 1;
    }
  } else {
    // bf16-A path: 3-buffer distance-2 counted-vmcnt pipeline
    STAGEA16(0,0);  STAGEB(0,0);
    STAGEA16(1,32); STAGEB(1,32);
    vwait<LPS>();
    wgbar();
    int buf = 0;
    for (int t=0;t<NK;++t){
      if (t+2 < NK){
        int nb = buf+2; if (nb>=3) nb-=3;
        STAGEA16(nb,(t+2)*32); STAGEB(nb,(t+2)*32);
      }
      COMPUTE(buf);
      if (t < NK-2) vwait<LPS>(); else vwait<0>();
      wgbar();
      ++buf; if (buf==3) buf=0;
    }
  }

  int row0 = by*BM + wr*32, col0 = bx*128 + wc*64;
  #pragma unroll
  for (int mi=0;mi<MI;++mi)
    #pragma unroll
    for (int ni=0;ni<4;++ni)
      #pragma unroll
      for (int r=0;r<4;++r){
        int row = row0 + mi*16 + g*4 + r;
        int col = col0 + ni*16 + c;
        float v = acc[mi][ni][r];
        if (MODE==0){
          ((u16*)C0)[(size_t)row*N + col] = ftou16(v);
        } else if (MODE==1){
          ((float*)C0)[(size_t)row*N + col] += v;
        } else if (MODE==2){
          float z2 = 1.5957691216057308f*(v + 0.044715f*v*v*v);
          float e  = __expf(z2);
          float th = 1.f - 2.f/(e + 1.f);
          ((u16*)C0)[(size_t)row*N + col] = ftou16(0.5f*v*(1.f+th));
        } else if (MODE==6){
          size_t idx = (size_t)row*N + col;
          float fin = ((float*)C0)[idx] + v;
          ((float*)C0)[idx] = fin;
          ((float*)C1)[idx] = fin;
        } else if (MODE==4){
          if (col < 768)       ((u16*)C0)[(size_t)row*768 + col]       = ftou16(v);
          else if (col < 1536) ((u16*)C1)[(size_t)row*768 + col - 768] = ftou16(v);
          else {
            int vv = col - 1536; int bb = row / KCAP; int key = row - bb*KCAP;
            ((u16*)C2)[((size_t)(bb*768 + vv))*KCAP + key] = ftou16(v);
          }
        } else { // MODE 5
          if (col < 768) ((u16*)C0)[(size_t)row*768 + col] = ftou16(v);
          else {
            int vv = col - 768; int bb = row >> 10; int key = row & 1023;
            ((u16*)C2)[((size_t)(bb*768 + vv))*1024 + key] = ftou16(v);
          }
        }
      }
}

template<int MODE, typename TA>
__global__ __launch_bounds__(256) void gemm_k(const TA* __restrict__ A, const u16* __restrict__ Bt,
                                              void* __restrict__ C0, void* __restrict__ C1, void* __restrict__ C2,
                                              int N, int K){
  constexpr int LDSZ = ((sizeof(TA)==4)?2:3) * (64+128)*32*2;
  __shared__ __align__(16) char pool[LDSZ];
  gemm_body<MODE,TA>(pool, A, Bt, C0, C1, C2, xcd_swz(), N, K);
}

// q_c (480 blocks) + cross imgKV (1536 blocks) fused dual dispatch
__global__ __launch_bounds__(256) void gemm_dual_k(const u16* __restrict__ T0, const u16* __restrict__ wq_ct,
                                                   u16* __restrict__ Qb,
                                                   const float* __restrict__ img, const u16* __restrict__ wkv_ct,
                                                   u16* __restrict__ Kb, u16* __restrict__ Vt){
  __shared__ __align__(16) char pool[3*(64+128)*32*2];
  int wgid = xcd_swz();   // grid = 2016
  if (wgid < 480) gemm_body<0,u16>  (pool, T0,  wq_ct,  Qb, nullptr, nullptr, wgid,      768,  768);
  else            gemm_body<5,float>(pool, img, wkv_ct, Kb, nullptr, Vt,      wgid-480, 1536,  768);
}

// ---------------- MFMA flash attention: 3-buffer distance-2 counted-vmcnt K/V pipeline ----------------
template<int MASKED>
__global__ __launch_bounds__(256) void attn_k(const u16* __restrict__ Q, const u16* __restrict__ Kb,
                                              const u16* __restrict__ Vt, u16* __restrict__ O,
                                              const int* __restrict__ counts, int Lk){
  __shared__ __align__(16) u16 Ks[3][64*64];
  __shared__ __align__(16) u16 Vs[3][64*64];
  __shared__ __align__(16) u16 P[4][16][72];
  int tid = threadIdx.x;
  int w = tid>>6, l = tid&63, g = l>>4, c = l&15;
  int wgid = xcd_swz();
  int qc = wgid % 5;
  int bh = wgid / 5;
  int h = bh % H_, b = bh / H_;
  int q0 = qc*128 + w*32;
  int cnt = MASKED ? counts[b] : Lk;
  int nt = (cnt + 63) >> 6;

  short8 qf[2][2];
  #pragma unroll
  for (int mi=0;mi<2;++mi){
    const u16* Qrow = Q + ((size_t)(b*KCAP + q0 + mi*16 + c))*D_ + h*DH_;
    qf[mi][0] = *(const short8*)(Qrow + g*8);
    qf[mi][1] = *(const short8*)(Qrow + 32 + g*8);
  }

  int srow8 = (l>>3);
  int sunit = l&7;
  auto STAGE = [&](int buf, int kb){    // 4 gld16 per wave
    #pragma unroll
    for (int p=0;p<2;++p){
      int r0 = w*16 + p*8;
      int rowK = r0 + srow8;
      int su = sunit ^ (rowK&7);
      gld16((const void*)(Kb + ((size_t)(b*Lk + kb + rowK))*D_ + h*DH_ + su*8), (void*)&Ks[buf][r0*64]);
      gld16((const void*)(Vt + ((size_t)(b*D_ + h*DH_ + rowK))*Lk + kb + su*8), (void*)&Vs[buf][r0*64]);
    }
  };

  f32x4 o[2][4] = {};
  float m_[2][4], l_[2][4] = {};
  #pragma unroll
  for (int mi=0;mi<2;++mi)
    #pragma unroll
    for (int r=0;r<4;++r) m_[mi][r] = -1e30f;

  STAGE(0, 0);
  if (nt > 1){ STAGE(1, 64); vwait<4>(); } else { vwait<0>(); }
  wgbar();
  int buf = 0;
  for (int t=0; t<nt; ++t){
    int kb = t*64;
    if (t+2 < nt){
      int nb = buf+2; if (nb>=3) nb-=3;
      STAGE(nb, kb+128);
    }
    short8 fr[4][2];
    #pragma unroll
    for (int nb=0;nb<4;++nb)
      #pragma unroll
      for (int kh=0;kh<2;++kh)
        fr[nb][kh] = *(const short8*)&Ks[buf][(nb*16+c)*64 + (((kh<<2)|g) ^ (c&7))*8];
    f32x4 z[2][4];
    #pragma unroll
    for (int mi=0;mi<2;++mi)
      #pragma unroll
      for (int nb=0;nb<4;++nb){
        f32x4 zz = {0.f,0.f,0.f,0.f};
        zz = MFMA(qf[mi][0], fr[nb][0], zz);
        zz = MFMA(qf[mi][1], fr[nb][1], zz);
        z[mi][nb] = zz;
      }
    float pv[2][4][4];
    #pragma unroll
    for (int nb=0;nb<4;++nb){
      bool msk = MASKED && (kb + nb*16 + c >= cnt);
      #pragma unroll
      for (int mi=0;mi<2;++mi)
        #pragma unroll
        for (int r=0;r<4;++r) pv[mi][nb][r] = msk ? -1e30f : z[mi][nb][r]*0.125f;
    }
    float scl[2][4];
    #pragma unroll
    for (int mi=0;mi<2;++mi){
      #pragma unroll
      for (int r=0;r<4;++r){
        float v = fmaxf(fmaxf(pv[mi][0][r],pv[mi][1][r]), fmaxf(pv[mi][2][r],pv[mi][3][r]));
        v = fmaxf(v, __shfl_xor(v,1)); v = fmaxf(v, __shfl_xor(v,2));
        v = fmaxf(v, __shfl_xor(v,4)); v = fmaxf(v, __shfl_xor(v,8));
        float nm = fmaxf(m_[mi][r], v);
        scl[mi][r] = __expf(m_[mi][r] - nm);
        m_[mi][r] = nm;
      }
      #pragma unroll
      for (int r=0;r<4;++r){
        float acc2 = 0.f;
        #pragma unroll
        for (int nb=0;nb<4;++nb){
          float e = __expf(pv[mi][nb][r] - m_[mi][r]);
          pv[mi][nb][r] = e; acc2 += e;
        }
        acc2 += __shfl_xor(acc2,1); acc2 += __shfl_xor(acc2,2);
        acc2 += __shfl_xor(acc2,4); acc2 += __shfl_xor(acc2,8);
        l_[mi][r] = l_[mi][r]*scl[mi][r] + acc2;
      }
      #pragma unroll
      for (int nbd=0;nbd<4;++nbd)
        #pragma unroll
        for (int r=0;r<4;++r) o[mi][nbd][r] *= scl[mi][r];
    }
    #pragma unroll
    for (int nbd=0;nbd<4;++nbd)
      #pragma unroll
      for (int kh=0;kh<2;++kh)
        fr[nbd][kh] = *(const short8*)&Vs[buf][(nbd*16+c)*64 + (((kh<<2)|g) ^ (c&7))*8];
    #pragma unroll
    for (int mi=0;mi<2;++mi){
      #pragma unroll
      for (int nb=0;nb<4;++nb)
        #pragma unroll
        for (int r=0;r<4;++r) P[w][g*4+r][nb*16+c] = ftou16(pv[mi][nb][r]);
      short8 pa0 = *(const short8*)&P[w][c][g*8];
      short8 pa1 = *(const short8*)&P[w][c][32 + g*8];
      #pragma unroll
      for (int nbd=0;nbd<4;++nbd){
        o[mi][nbd] = MFMA(pa0, fr[nbd][0], o[mi][nbd]);
        o[mi][nbd] = MFMA(pa1, fr[nbd][1], o[mi][nbd]);
      }
    }
    if (t < nt-2) vwait<4>(); else vwait<0>();
    wgbar();
    ++buf; if (buf==3) buf=0;
  }
  #pragma unroll
  for (int mi=0;mi<2;++mi)
    #pragma unroll
    for (int nbd=0;nbd<4;++nbd)
      #pragma unroll
      for (int r=0;r<4;++r)
        O[((size_t)(b*KCAP + q0 + mi*16 + g*4 + r))*D_ + h*DH_ + nbd*16 + c] = ftou16(o[mi][nbd][r] / l_[mi][r]);
}

// ---------------- scatter back ----------------
__global__ __launch_bounds__(256) void scatter_k(const int* __restrict__ pos, const float* __restrict__ X,
                                                 const float* __restrict__ hid, float* __restrict__ out0){
  int bs = blockIdx.x; int tid = threadIdx.x;
  int b = bs >> 12;
  int p = pos[bs];
  float* orow = out0 + (size_t)bs*D_;
  if (p >= 0){
    int pc = p < KCAP ? p : (KCAP-1);
    const float* xr = X + ((size_t)(b*KCAP + pc))*D_;
    orow[tid]     = xr[tid];
    orow[tid+256] = xr[tid+256];
    orow[tid+512] = xr[tid+512];
  } else {
    const float* hr = hid + (size_t)bs*D_;
    orow[tid]     = hr[tid];
    orow[tid+256] = hr[tid+256];
    orow[tid+512] = hr[tid+512];
  }
}

extern "C" void kernel_launch(void* const* d_in, const int* in_sizes, int n_in,
                              void* d_out, int out_size, void* d_ws, size_t ws_size,
                              hipStream_t stream){
  const float* img  = (const float*)d_in[0];
  const float* hid  = (const float*)d_in[1];
  const int*   seq  = (const int*)  d_in[2];
  const float* W[10] = { (const float*)d_in[3], (const float*)d_in[4], (const float*)d_in[5], (const float*)d_in[6],
                         (const float*)d_in[7], (const float*)d_in[8], (const float*)d_in[9], (const float*)d_in[10],
                         (const float*)d_in[11], (const float*)d_in[12] };
  const float* ln1s = (const float*)d_in[13];
  const float* ln1b = (const float*)d_in[14];
  const float* ln2s = (const float*)d_in[15];
  const float* ln2b = (const float*)d_in[16];
  const float* ln3s = (const float*)d_in[17];
  const float* ln3b = (const float*)d_in[18];

  char* ws = (char*)d_ws;
  int*   pos    = (int*)  (ws + 0);          //   131072
  int*   src    = (int*)  (ws + 131072);     //    20480
  int*   counts = (int*)  (ws + 151552);     //      256
  float* X      = (float*)(ws + 151808);     // 15728640
  u16*   T0     = (u16*)  (ws + 15880448);   //  7864320
  u16*   Qb     = (u16*)  (ws + 23744768);   //  7864320
  u16*   Kb     = (u16*)  (ws + 31609088);   // 12582912
  u16*   Vt     = (u16*)  (ws + 44192000);   // 12582912
  u16*   AO     = (u16*)  (ws + 56774912);   //  7864320
  u16*   Wt     = (u16*)  (ws + 64639232);   // 18874368 -> total 83513600
  u16*   MID    = Qb;                        // 31457280, aliases Qb..Vt (dead during FFN)

  u16* wqkv_st = Wt + 0ull*589824;           // rows 0-767 Q, 768-1535 K, 1536-2303 V
  u16* wo_st   = Wt + 3ull*589824;
  u16* wq_ct   = Wt + 4ull*589824;
  u16* wkv_ct  = Wt + 5ull*589824;           // rows 0-767 K, 768-1535 V
  u16* wo_ct   = Wt + 7ull*589824;
  u16* wff1t   = Wt + 8ull*589824;           // [3072][768]
  u16* wff2t   = wff1t + 2359296;            // [768][3072]

  float* out0 = (float*)d_out;
  float* out1 = out0 + (size_t)B_*S_*D_;

  TransArgs ta;
  for (int i=0;i<10;++i) ta.w[i] = W[i];
  for (int i=0;i<8;++i)  ta.o[i] = Wt + (size_t)i*589824;
  ta.o[8] = wff1t; ta.o[9] = wff2t;

  // transpose (9216) + scan (8) in one launch
  transpose_scan_k<<<9224, 256, 0, stream>>>(ta, seq, pos, src, counts);
  // gather + LN1 fused
  gather_ln_k<<<B_*KCAP, 256, 0, stream>>>(hid, src, counts, ln1s, ln1b, X, T0);

  const int G_QKV  = (5120/64)*(2304/128);   // 1440
  const int G_N768 = (5120/64)*(768/128);    // 480
  const int G_FF1  = (5120/64)*(3072/128);   // 1920
  const int G_DUAL = 480 + (8192/64)*(1536/128); // 480 + 1536 = 2016
  const int G_ATT  = B_*H_*5;                // 480

  // ---- self-attention block ----
  gemm_k<4,u16><<<G_QKV, 256, 0, stream>>>(T0, wqkv_st, Qb, Kb, Vt, 2304, 768);
  attn_k<1><<<G_ATT, 256, 0, stream>>>(Qb, Kb, Vt, AO, counts, KCAP);
  gemm_k<1,u16><<<G_N768, 256, 0, stream>>>(AO, wo_st, X, nullptr, nullptr, 768, 768);

  // ---- cross-attention block (q_c + img KV fused in one dispatch) ----
  ln_k<<<5120, 256, 0, stream>>>(X, T0, ln2s, ln2b);
  gemm_dual_k<<<G_DUAL, 256, 0, stream>>>(T0, wq_ct, Qb, img, wkv_ct, Kb, Vt);
  attn_k<0><<<G_ATT, 256, 0, stream>>>(Qb, Kb, Vt, AO, counts, N_);
  gemm_k<1,u16><<<G_N768, 256, 0, stream>>>(AO, wo_ct, X, nullptr, nullptr, 768, 768);

  // ---- FFN block (FF2 epilogue also emits out1) ----
  ln_k<<<5120, 256, 0, stream>>>(X, T0, ln3s, ln3b);
  gemm_k<2,u16><<<G_FF1, 256, 0, stream>>>(T0, wff1t, MID, nullptr, nullptr, 3072, 768);
  gemm_k<6,u16><<<G_N768, 256, 0, stream>>>(MID, wff2t, X, out1, nullptr, 768, 3072);

  // ---- output 0 ----
  scatter_k<<<B_*S_, 256, 0, stream>>>(pos, X, hid, out0);
}

// Round 9
// 469.606 us; speedup vs baseline: 5.5613x; 1.0103x over previous
//
#include <hip/hip_runtime.h>
#include <hip/hip_bf16.h>

// Fetcher: SOC extraction -> [self-attn + cross-attn(img) + GELU-FFN] -> scatter-back.
// Round 8 (fixed): mega1 = self-QKV + img-KV one dispatch, BOTH at BM=128 (16:8 MFMA:ds_read).
// Cross K/V get dedicated buffers (KbC/VtC) distinct from self K/V. FF1 at BM=128.

#define B_    8
#define S_    4096
#define D_    768
#define N_    1024
#define FF_   3072
#define H_    12
#define DH_   64
#define KCAP  640
#define SOC_TOK 3
#define EOS_TOK 2

typedef __hip_bfloat16 bf16;
typedef unsigned short u16;
typedef __attribute__((ext_vector_type(8))) short short8;
typedef __attribute__((ext_vector_type(4))) float f32x4;

__device__ __forceinline__ u16 ftou16(float x){ union{bf16 b; u16 s;} c; c.b = __float2bfloat16(x); return c.s; }
__device__ __forceinline__ unsigned pk2(float lo, float hi){ return (unsigned)ftou16(lo) | ((unsigned)ftou16(hi)<<16); }

__device__ __forceinline__ f32x4 MFMA(short8 a, short8 b, f32x4 c){
  return __builtin_amdgcn_mfma_f32_16x16x32_bf16(a, b, c, 0, 0, 0);
}

__device__ __forceinline__ void gld16(const void* gp, void* lp){
  __builtin_amdgcn_global_load_lds(
    reinterpret_cast<const __attribute__((address_space(1))) unsigned int*>((size_t)gp),
    reinterpret_cast<__attribute__((address_space(3))) unsigned int*>((size_t)lp),
    16, 0, 0);
}

template<int N> __device__ __forceinline__ void vwait(){
  asm volatile("s_waitcnt vmcnt(%0)" :: "i"(N) : "memory");
}
__device__ __forceinline__ void wgbar(){ asm volatile("s_barrier" ::: "memory"); }

__device__ __forceinline__ int xcd_swz(){
  int id = blockIdx.x;
  return (id & 7) * ((int)gridDim.x >> 3) + (id >> 3);
}

// ---------------- scan body ----------------
__device__ void scan_body(const int* __restrict__ seq, int* __restrict__ pos,
                          int* __restrict__ src, int* __restrict__ counts, int b){
  int tid = threadIdx.x;
  __shared__ int sd[256];
  __shared__ int carryE, carryS;
  if (tid==0){ carryE=0; carryS=0; }
  __syncthreads();
  for (int c=0; c<S_; c+=256){
    int s   = c + tid;
    int tok = seq[b*S_ + s];
    int isE = (tok==EOS_TOK) ? 1 : 0;
    int isS = (tok==SOC_TOK) ? 1 : 0;
    sd[tid]=isE; __syncthreads();
    for (int off=1; off<256; off<<=1){ int t_=(tid>=off)?sd[tid-off]:0; __syncthreads(); sd[tid]+=t_; __syncthreads(); }
    int eIncl = sd[tid];
    int eTot  = sd[255];
    int valid = (isS && (carryE + eIncl)==0) ? 1 : 0;
    __syncthreads();
    sd[tid]=valid; __syncthreads();
    for (int off=1; off<256; off<<=1){ int t_=(tid>=off)?sd[tid-off]:0; __syncthreads(); sd[tid]+=t_; __syncthreads(); }
    int vIncl = sd[tid];
    int vTot  = sd[255];
    if (valid){
      int slot = carryS + vIncl - 1;
      pos[b*S_ + s] = slot;
      if (slot < KCAP) src[b*KCAP + slot] = s;
    } else {
      pos[b*S_ + s] = -1;
    }
    __syncthreads();
    if (tid==0){ carryE += eTot; carryS += vTot; }
    __syncthreads();
  }
  if (tid==0) counts[b] = (carryS < KCAP) ? carryS : KCAP;
}

// ---------------- transpose + scan, one launch ----------------
struct TransArgs { const float* w[10]; u16* o[10]; };
__global__ __launch_bounds__(256) void transpose_scan_k(TransArgs a, const int* __restrict__ seq,
                                                        int* __restrict__ pos, int* __restrict__ src,
                                                        int* __restrict__ counts){
  int id = blockIdx.x;
  if (id >= 9216){ scan_body(seq, pos, src, counts, id - 9216); return; }
  __shared__ float tile[32][33];
  int wi, t, K, N;
  if (id < 4608){ wi = id/576; t = id%576; K = 768; N = 768; }
  else if (id < 6912){ wi = 8; t = id-4608; K = 768; N = 3072; }
  else { wi = 9; t = id-6912; K = 3072; N = 768; }
  const float* in = a.w[wi]; u16* out = a.o[wi];
  int nbx = N >> 5;
  int bx = t % nbx, by = t / nbx;
  int tx = threadIdx.x & 31, ty = threadIdx.x >> 5;
  #pragma unroll
  for (int i=0;i<4;++i)
    tile[ty + i*8][tx] = in[(size_t)(by*32 + ty + i*8)*N + bx*32 + tx];
  __syncthreads();
  #pragma unroll
  for (int i=0;i<4;++i)
    out[(size_t)(bx*32 + ty + i*8)*K + by*32 + tx] = ftou16(tile[tx][ty + i*8]);
}

// ---------------- gather + LN1 fused ----------------
__global__ __launch_bounds__(256) void gather_ln_k(const float* __restrict__ hid,
                                                   const int* __restrict__ src,
                                                   const int* __restrict__ counts,
                                                   const float* __restrict__ g, const float* __restrict__ bt,
                                                   float* __restrict__ X, u16* __restrict__ T0){
  int bk = blockIdx.x; int b = bk / KCAP; int k = bk % KCAP;
  int tid = threadIdx.x;
  float v0, v1, v2;
  if (k < counts[b]){
    const float* hr = hid + ((size_t)b*S_ + src[b*KCAP + k])*D_;
    v0 = hr[tid]; v1 = hr[tid+256]; v2 = hr[tid+512];
  } else { v0 = v1 = v2 = 0.f; }
  float* xr = X + (size_t)bk*D_;
  xr[tid] = v0; xr[tid+256] = v1; xr[tid+512] = v2;
  float s1=v0+v1+v2, s2=v0*v0+v1*v1+v2*v2;
  for (int off=32; off; off>>=1){ s1+=__shfl_xor(s1,off); s2+=__shfl_xor(s2,off); }
  __shared__ float red[8];
  __shared__ float mu_s, rs_s;
  int w=tid>>6, ln=tid&63;
  if (ln==0){ red[w]=s1; red[4+w]=s2; }
  __syncthreads();
  if (tid==0){
    float S1=red[0]+red[1]+red[2]+red[3];
    float S2=red[4]+red[5]+red[6]+red[7];
    float mu = S1*(1.f/D_);
    float var= S2*(1.f/D_) - mu*mu;
    mu_s=mu; rs_s=rsqrtf(var + 1e-5f);
  }
  __syncthreads();
  float mu=mu_s, rs=rs_s;
  u16* yr = T0 + (size_t)bk*D_;
  yr[tid]     = ftou16((v0-mu)*rs*g[tid]     + bt[tid]);
  yr[tid+256] = ftou16((v1-mu)*rs*g[tid+256] + bt[tid+256]);
  yr[tid+512] = ftou16((v2-mu)*rs*g[tid+512] + bt[tid+512]);
}

// ---------------- layernorm ----------------
__global__ __launch_bounds__(256) void ln_k(const float* __restrict__ X, u16* __restrict__ Y,
                                            const float* __restrict__ g, const float* __restrict__ bt){
  int r = blockIdx.x; int tid = threadIdx.x;
  const float* xr = X + (size_t)r*D_;
  float v0=xr[tid], v1=xr[tid+256], v2=xr[tid+512];
  float s1=v0+v1+v2, s2=v0*v0+v1*v1+v2*v2;
  for (int off=32; off; off>>=1){ s1+=__shfl_xor(s1,off); s2+=__shfl_xor(s2,off); }
  __shared__ float red[8];
  __shared__ float mu_s, rs_s;
  int w=tid>>6, ln=tid&63;
  if (ln==0){ red[w]=s1; red[4+w]=s2; }
  __syncthreads();
  if (tid==0){
    float S1=red[0]+red[1]+red[2]+red[3];
    float S2=red[4]+red[5]+red[6]+red[7];
    float mu = S1*(1.f/D_);
    float var= S2*(1.f/D_) - mu*mu;
    mu_s=mu; rs_s=rsqrtf(var + 1e-5f);
  }
  __syncthreads();
  float mu=mu_s, rs=rs_s;
  u16* yr = Y + (size_t)r*D_;
  yr[tid]     = ftou16((v0-mu)*rs*g[tid]     + bt[tid]);
  yr[tid+256] = ftou16((v1-mu)*rs*g[tid+256] + bt[tid+256]);
  yr[tid+512] = ftou16((v2-mu)*rs*g[tid+512] + bt[tid+512]);
}

// ---------------- MFMA GEMM body ----------------
template<int MODE, int BM, typename TA>
__device__ __forceinline__ void gemm_body(char* ldsp, const TA* __restrict__ A, const u16* __restrict__ Bt,
                                          void* __restrict__ C0, void* __restrict__ C1, void* __restrict__ C2,
                                          int wgid, int N, int K){
  constexpr int MI   = BM/32;
  constexpr int NBUF = (BM==128) ? 2 : ((sizeof(TA)==4) ? 2 : 3);
  u16* As = (u16*)ldsp;
  u16* Bs = (u16*)(ldsp + NBUF*(BM*32)*2);
  int nbx = N >> 7;
  int bx = wgid % nbx, by = wgid / nbx;
  int tid = threadIdx.x;
  int w = tid>>6, l = tid&63, g = l>>4, c = l&15;
  int wr = w&1, wc = w>>1;
  f32x4 acc[MI][4] = {};
  float4 rg[4];
  const int NK = K/32;

  auto STAGEB = [&](int buf, int kt){
    #pragma unroll
    for (int p=0;p<2;++p){
      int row = w*32 + p*16 + (l>>2);
      int su  = (l&3) ^ ((row>>1)&3);
      gld16((const void*)(Bt + (size_t)(bx*128+row)*K + kt + su*8), (void*)&Bs[buf*128*32 + (w*32+p*16)*32]);
    }
  };
  auto STAGEA16 = [&](int buf, int kt){
    if constexpr (BM==128){
      #pragma unroll
      for (int p=0;p<2;++p){
        int row = w*32 + p*16 + (l>>2);
        int su  = (l&3) ^ ((row>>1)&3);
        gld16((const void*)((const u16*)A + (size_t)(by*BM+row)*K + kt + su*8), (void*)&As[buf*BM*32 + (w*32+p*16)*32]);
      }
    } else {
      int row = w*16 + (l>>2);
      int su  = (l&3) ^ ((row>>1)&3);
      gld16((const void*)((const u16*)A + (size_t)(by*BM+row)*K + kt + su*8), (void*)&As[buf*BM*32 + (w*16)*32]);
    }
  };
  auto LOADREG = [&](int kt){
    if constexpr (BM==128){
      const float* ap = (const float*)A + (size_t)(by*BM + (tid>>1))*K + kt + (tid&1)*16;
      rg[0]=*(const float4*)ap;     rg[1]=*(const float4*)(ap+4);
      rg[2]=*(const float4*)(ap+8); rg[3]=*(const float4*)(ap+12);
    } else {
      const float* ap = (const float*)A + (size_t)(by*BM + (tid>>2))*K + kt + (tid&3)*8;
      rg[0] = *(const float4*)ap; rg[1] = *(const float4*)(ap+4);
    }
  };
  auto WRITEA = [&](int buf){
    if constexpr (BM==128){
      int row = tid>>1, half = tid&1;
      uint4 w0,w1;
      w0.x=pk2(rg[0].x,rg[0].y); w0.y=pk2(rg[0].z,rg[0].w); w0.z=pk2(rg[1].x,rg[1].y); w0.w=pk2(rg[1].z,rg[1].w);
      w1.x=pk2(rg[2].x,rg[2].y); w1.y=pk2(rg[2].z,rg[2].w); w1.z=pk2(rg[3].x,rg[3].y); w1.w=pk2(rg[3].z,rg[3].w);
      int sw = (row>>1)&3;
      *(uint4*)&As[buf*BM*32 + row*32 + ((half*2  )^sw)*8] = w0;
      *(uint4*)&As[buf*BM*32 + row*32 + ((half*2+1)^sw)*8] = w1;
    } else {
      int row = tid>>2, unit = tid&3;
      uint4 wv;
      wv.x=pk2(rg[0].x,rg[0].y); wv.y=pk2(rg[0].z,rg[0].w); wv.z=pk2(rg[1].x,rg[1].y); wv.w=pk2(rg[1].z,rg[1].w);
      int sw = (row>>1)&3;
      *(uint4*)&As[buf*BM*32 + row*32 + (unit^sw)*8] = wv;
    }
  };
  auto COMPUTE = [&](int buf){
    short8 af[MI], bfr[4];
    #pragma unroll
    for (int mi=0;mi<MI;++mi){ int row = wr*(MI*16) + mi*16 + c; af[mi]  = *(const short8*)&As[buf*BM*32 + row*32 + (g^((row>>1)&3))*8]; }
    #pragma unroll
    for (int ni=0;ni<4;++ni){ int row = wc*64 + ni*16 + c;       bfr[ni] = *(const short8*)&Bs[buf*128*32 + row*32 + (g^((row>>1)&3))*8]; }
    #pragma unroll
    for (int mi=0;mi<MI;++mi)
      #pragma unroll
      for (int ni=0;ni<4;++ni) acc[mi][ni] = MFMA(af[mi], bfr[ni], acc[mi][ni]);
  };

  if constexpr (BM==128 || sizeof(TA)==4){
    if constexpr (sizeof(TA)==4){ LOADREG(0); STAGEB(0,0); WRITEA(0); }
    else { STAGEA16(0,0); STAGEB(0,0); }
    __syncthreads();
    int buf = 0;
    for (int t=0;t<NK;++t){
      int ktn = (t+1)*32;
      if constexpr (sizeof(TA)==4){
        if (t+1<NK){ LOADREG(ktn); STAGEB(buf^1, ktn); }
        COMPUTE(buf);
        if (t+1<NK) WRITEA(buf^1);
      } else {
        if (t+1<NK){ STAGEA16(buf^1, ktn); STAGEB(buf^1, ktn); }
        COMPUTE(buf);
      }
      __syncthreads();
      buf ^= 1;
    }
  } else {
    constexpr int LPS = 3;
    STAGEA16(0,0);  STAGEB(0,0);
    STAGEA16(1,32); STAGEB(1,32);
    vwait<LPS>();
    wgbar();
    int buf = 0;
    for (int t=0;t<NK;++t){
      if (t+2 < NK){
        int nb = buf+2; if (nb>=3) nb-=3;
        STAGEA16(nb,(t+2)*32); STAGEB(nb,(t+2)*32);
      }
      COMPUTE(buf);
      if (t < NK-2) vwait<LPS>(); else vwait<0>();
      wgbar();
      ++buf; if (buf==3) buf=0;
    }
  }

  int row0 = by*BM + wr*(MI*16), col0 = bx*128 + wc*64;
  #pragma unroll
  for (int mi=0;mi<MI;++mi)
    #pragma unroll
    for (int ni=0;ni<4;++ni)
      #pragma unroll
      for (int r=0;r<4;++r){
        int row = row0 + mi*16 + g*4 + r;
        int col = col0 + ni*16 + c;
        float v = acc[mi][ni][r];
        if (MODE==0){
          ((u16*)C0)[(size_t)row*N + col] = ftou16(v);
        } else if (MODE==1){
          ((float*)C0)[(size_t)row*N + col] += v;
        } else if (MODE==2){
          float z2 = 1.5957691216057308f*(v + 0.044715f*v*v*v);
          float e  = __expf(z2);
          float th = 1.f - 2.f/(e + 1.f);
          ((u16*)C0)[(size_t)row*N + col] = ftou16(0.5f*v*(1.f+th));
        } else if (MODE==6){
          size_t idx = (size_t)row*N + col;
          float fin = ((float*)C0)[idx] + v;
          ((float*)C0)[idx] = fin;
          ((float*)C1)[idx] = fin;
        } else if (MODE==4){
          if (col < 768)       ((u16*)C0)[(size_t)row*768 + col]       = ftou16(v);
          else if (col < 1536) ((u16*)C1)[(size_t)row*768 + col - 768] = ftou16(v);
          else {
            int vv = col - 1536; int bb = row / KCAP; int key = row - bb*KCAP;
            ((u16*)C2)[((size_t)(bb*768 + vv))*KCAP + key] = ftou16(v);
          }
        } else { // MODE 5
          if (col < 768) ((u16*)C0)[(size_t)row*768 + col] = ftou16(v);
          else {
            int vv = col - 768; int bb = row >> 10; int key = row & 1023;
            ((u16*)C2)[((size_t)(bb*768 + vv))*1024 + key] = ftou16(v);
          }
        }
      }
}

template<int MODE, int BM, typename TA>
__global__ __launch_bounds__(256) void gemm_k(const TA* __restrict__ A, const u16* __restrict__ Bt,
                                              void* __restrict__ C0, void* __restrict__ C1, void* __restrict__ C2,
                                              int N, int K){
  constexpr int NBUF = (BM==128) ? 2 : ((sizeof(TA)==4) ? 2 : 3);
  __shared__ __align__(16) char pool[NBUF*(BM+128)*32*2];
  gemm_body<MODE,BM,TA>(pool, A, Bt, C0, C1, C2, xcd_swz(), N, K);
}

// mega1: self QKV (720 blocks) + cross img KV (768 blocks), both BM=128, one dispatch
__global__ __launch_bounds__(256) void mega1_k(const u16* __restrict__ T0, const u16* __restrict__ wqkv_st,
                                               u16* __restrict__ Qb, u16* __restrict__ Kb, u16* __restrict__ VtS,
                                               const float* __restrict__ img, const u16* __restrict__ wkv_ct,
                                               u16* __restrict__ KbC, u16* __restrict__ VtC){
  __shared__ __align__(16) char pool[2*(128+128)*32*2];
  int wgid = xcd_swz();   // grid = 1488
  if (wgid < 720) gemm_body<4,128,u16>  (pool, T0,  wqkv_st, Qb,  Kb,      VtS, wgid,     2304, 768);
  else            gemm_body<5,128,float>(pool, img, wkv_ct,  KbC, nullptr, VtC, wgid-720, 1536, 768);
}

// ---------------- MFMA flash attention ----------------
template<int MASKED>
__global__ __launch_bounds__(256) void attn_k(const u16* __restrict__ Q, const u16* __restrict__ Kb,
                                              const u16* __restrict__ Vt, u16* __restrict__ O,
                                              const int* __restrict__ counts, int Lk){
  __shared__ __align__(16) u16 Ks[3][64*64];
  __shared__ __align__(16) u16 Vs[3][64*64];
  __shared__ __align__(16) u16 P[4][16][72];
  int tid = threadIdx.x;
  int w = tid>>6, l = tid&63, g = l>>4, c = l&15;
  int wgid = xcd_swz();
  int qc = wgid % 5;
  int bh = wgid / 5;
  int h = bh % H_, b = bh / H_;
  int q0 = qc*128 + w*32;
  int cnt = MASKED ? counts[b] : Lk;
  int nt = (cnt + 63) >> 6;

  short8 qf[2][2];
  #pragma unroll
  for (int mi=0;mi<2;++mi){
    const u16* Qrow = Q + ((size_t)(b*KCAP + q0 + mi*16 + c))*D_ + h*DH_;
    qf[mi][0] = *(const short8*)(Qrow + g*8);
    qf[mi][1] = *(const short8*)(Qrow + 32 + g*8);
  }

  int srow8 = (l>>3);
  int sunit = l&7;
  auto STAGE = [&](int buf, int kb){
    #pragma unroll
    for (int p=0;p<2;++p){
      int r0 = w*16 + p*8;
      int rowK = r0 + srow8;
      int su = sunit ^ (rowK&7);
      gld16((const void*)(Kb + ((size_t)(b*Lk + kb + rowK))*D_ + h*DH_ + su*8), (void*)&Ks[buf][r0*64]);
      gld16((const void*)(Vt + ((size_t)(b*D_ + h*DH_ + rowK))*Lk + kb + su*8), (void*)&Vs[buf][r0*64]);
    }
  };

  f32x4 o[2][4] = {};
  float m_[2][4], l_[2][4] = {};
  #pragma unroll
  for (int mi=0;mi<2;++mi)
    #pragma unroll
    for (int r=0;r<4;++r) m_[mi][r] = -1e30f;

  STAGE(0, 0);
  if (nt > 1){ STAGE(1, 64); vwait<4>(); } else { vwait<0>(); }
  wgbar();
  int buf = 0;
  for (int t=0; t<nt; ++t){
    int kb = t*64;
    if (t+2 < nt){
      int nb = buf+2; if (nb>=3) nb-=3;
      STAGE(nb, kb+128);
    }
    short8 fr[4][2];
    #pragma unroll
    for (int nb=0;nb<4;++nb)
      #pragma unroll
      for (int kh=0;kh<2;++kh)
        fr[nb][kh] = *(const short8*)&Ks[buf][(nb*16+c)*64 + (((kh<<2)|g) ^ (c&7))*8];
    f32x4 z[2][4];
    #pragma unroll
    for (int mi=0;mi<2;++mi)
      #pragma unroll
      for (int nb=0;nb<4;++nb){
        f32x4 zz = {0.f,0.f,0.f,0.f};
        zz = MFMA(qf[mi][0], fr[nb][0], zz);
        zz = MFMA(qf[mi][1], fr[nb][1], zz);
        z[mi][nb] = zz;
      }
    float pv[2][4][4];
    #pragma unroll
    for (int nb=0;nb<4;++nb){
      bool msk = MASKED && (kb + nb*16 + c >= cnt);
      #pragma unroll
      for (int mi=0;mi<2;++mi)
        #pragma unroll
        for (int r=0;r<4;++r) pv[mi][nb][r] = msk ? -1e30f : z[mi][nb][r]*0.125f;
    }
    float scl[2][4];
    #pragma unroll
    for (int mi=0;mi<2;++mi){
      #pragma unroll
      for (int r=0;r<4;++r){
        float v = fmaxf(fmaxf(pv[mi][0][r],pv[mi][1][r]), fmaxf(pv[mi][2][r],pv[mi][3][r]));
        v = fmaxf(v, __shfl_xor(v,1)); v = fmaxf(v, __shfl_xor(v,2));
        v = fmaxf(v, __shfl_xor(v,4)); v = fmaxf(v, __shfl_xor(v,8));
        float nm = fmaxf(m_[mi][r], v);
        scl[mi][r] = __expf(m_[mi][r] - nm);
        m_[mi][r] = nm;
      }
      #pragma unroll
      for (int r=0;r<4;++r){
        float acc2 = 0.f;
        #pragma unroll
        for (int nb=0;nb<4;++nb){
          float e = __expf(pv[mi][nb][r] - m_[mi][r]);
          pv[mi][nb][r] = e; acc2 += e;
        }
        acc2 += __shfl_xor(acc2,1); acc2 += __shfl_xor(acc2,2);
        acc2 += __shfl_xor(acc2,4); acc2 += __shfl_xor(acc2,8);
        l_[mi][r] = l_[mi][r]*scl[mi][r] + acc2;
      }
      #pragma unroll
      for (int nbd=0;nbd<4;++nbd)
        #pragma unroll
        for (int r=0;r<4;++r) o[mi][nbd][r] *= scl[mi][r];
    }
    #pragma unroll
    for (int nbd=0;nbd<4;++nbd)
      #pragma unroll
      for (int kh=0;kh<2;++kh)
        fr[nbd][kh] = *(const short8*)&Vs[buf][(nbd*16+c)*64 + (((kh<<2)|g) ^ (c&7))*8];
    #pragma unroll
    for (int mi=0;mi<2;++mi){
      #pragma unroll
      for (int nb=0;nb<4;++nb)
        #pragma unroll
        for (int r=0;r<4;++r) P[w][g*4+r][nb*16+c] = ftou16(pv[mi][nb][r]);
      short8 pa0 = *(const short8*)&P[w][c][g*8];
      short8 pa1 = *(const short8*)&P[w][c][32 + g*8];
      #pragma unroll
      for (int nbd=0;nbd<4;++nbd){
        o[mi][nbd] = MFMA(pa0, fr[nbd][0], o[mi][nbd]);
        o[mi][nbd] = MFMA(pa1, fr[nbd][1], o[mi][nbd]);
      }
    }
    if (t < nt-2) vwait<4>(); else vwait<0>();
    wgbar();
    ++buf; if (buf==3) buf=0;
  }
  #pragma unroll
  for (int mi=0;mi<2;++mi)
    #pragma unroll
    for (int nbd=0;nbd<4;++nbd)
      #pragma unroll
      for (int r=0;r<4;++r)
        O[((size_t)(b*KCAP + q0 + mi*16 + g*4 + r))*D_ + h*DH_ + nbd*16 + c] = ftou16(o[mi][nbd][r] / l_[mi][r]);
}

// ---------------- scatter back ----------------
__global__ __launch_bounds__(256) void scatter_k(const int* __restrict__ pos, const float* __restrict__ X,
                                                 const float* __restrict__ hid, float* __restrict__ out0){
  int bs = blockIdx.x; int tid = threadIdx.x;
  int b = bs >> 12;
  int p = pos[bs];
  float* orow = out0 + (size_t)bs*D_;
  if (p >= 0){
    int pc = p < KCAP ? p : (KCAP-1);
    const float* xr = X + ((size_t)(b*KCAP + pc))*D_;
    orow[tid]     = xr[tid];
    orow[tid+256] = xr[tid+256];
    orow[tid+512] = xr[tid+512];
  } else {
    const float* hr = hid + (size_t)bs*D_;
    orow[tid]     = hr[tid];
    orow[tid+256] = hr[tid+256];
    orow[tid+512] = hr[tid+512];
  }
}

extern "C" void kernel_launch(void* const* d_in, const int* in_sizes, int n_in,
                              void* d_out, int out_size, void* d_ws, size_t ws_size,
                              hipStream_t stream){
  const float* img  = (const float*)d_in[0];
  const float* hid  = (const float*)d_in[1];
  const int*   seq  = (const int*)  d_in[2];
  const float* W[10] = { (const float*)d_in[3], (const float*)d_in[4], (const float*)d_in[5], (const float*)d_in[6],
                         (const float*)d_in[7], (const float*)d_in[8], (const float*)d_in[9], (const float*)d_in[10],
                         (const float*)d_in[11], (const float*)d_in[12] };
  const float* ln1s = (const float*)d_in[13];
  const float* ln1b = (const float*)d_in[14];
  const float* ln2s = (const float*)d_in[15];
  const float* ln2b = (const float*)d_in[16];
  const float* ln3s = (const float*)d_in[17];
  const float* ln3b = (const float*)d_in[18];

  char* ws = (char*)d_ws;
  int*   pos    = (int*)  (ws + 0);          //   131072
  int*   src    = (int*)  (ws + 131072);     //    20480
  int*   counts = (int*)  (ws + 151552);     //      256
  float* X      = (float*)(ws + 151808);     // 15728640
  u16*   T0     = (u16*)  (ws + 15880448);   //  7864320
  u16*   Qb     = (u16*)  (ws + 23744768);   //  7864320
  u16*   Kb     = (u16*)  (ws + 31609088);   //  7864320 (self K, [B*KCAP][768])
  u16*   VtS    = (u16*)  (ws + 39473408);   //  7864320 (self V^T, [B][768][KCAP])
  u16*   KbC    = (u16*)  (ws + 47337728);   // 12582912 (cross K, [B*N][768])
  u16*   VtC    = (u16*)  (ws + 59920640);   // 12582912 (cross V^T, [B][768][N])
  u16*   AO     = (u16*)  (ws + 72503552);   //  7864320
  u16*   Wt     = (u16*)  (ws + 80367872);   // 18874368 -> total 99242240
  u16*   MID    = Qb;                        // 31457280 alias over Qb..KbC (dead during FFN)

  u16* wqkv_st = Wt + 0ull*589824;
  u16* wo_st   = Wt + 3ull*589824;
  u16* wq_ct   = Wt + 4ull*589824;
  u16* wkv_ct  = Wt + 5ull*589824;
  u16* wo_ct   = Wt + 7ull*589824;
  u16* wff1t   = Wt + 8ull*589824;
  u16* wff2t   = wff1t + 2359296;

  float* out0 = (float*)d_out;
  float* out1 = out0 + (size_t)B_*S_*D_;

  TransArgs ta;
  for (int i=0;i<10;++i) ta.w[i] = W[i];
  for (int i=0;i<8;++i)  ta.o[i] = Wt + (size_t)i*589824;
  ta.o[8] = wff1t; ta.o[9] = wff2t;

  transpose_scan_k<<<9224, 256, 0, stream>>>(ta, seq, pos, src, counts);
  gather_ln_k<<<B_*KCAP, 256, 0, stream>>>(hid, src, counts, ln1s, ln1b, X, T0);

  const int G_MEGA1 = 720 + 768;             // 1488
  const int G_N768  = (5120/64)*(768/128);   // 480
  const int G_FF1   = (5120/128)*(3072/128); // 960
  const int G_ATT   = B_*H_*5;               // 480

  // ---- self-attention block (+ independent img KV projection fused) ----
  mega1_k<<<G_MEGA1, 256, 0, stream>>>(T0, wqkv_st, Qb, Kb, VtS, img, wkv_ct, KbC, VtC);
  attn_k<1><<<G_ATT, 256, 0, stream>>>(Qb, Kb, VtS, AO, counts, KCAP);
  gemm_k<1,64,u16><<<G_N768, 256, 0, stream>>>(AO, wo_st, X, nullptr, nullptr, 768, 768);

  // ---- cross-attention block ----
  ln_k<<<5120, 256, 0, stream>>>(X, T0, ln2s, ln2b);
  gemm_k<0,64,u16><<<G_N768, 256, 0, stream>>>(T0, wq_ct, Qb, nullptr, nullptr, 768, 768);
  attn_k<0><<<G_ATT, 256, 0, stream>>>(Qb, KbC, VtC, AO, counts, N_);
  gemm_k<1,64,u16><<<G_N768, 256, 0, stream>>>(AO, wo_ct, X, nullptr, nullptr, 768, 768);

  // ---- FFN block (FF2 epilogue also emits out1) ----
  ln_k<<<5120, 256, 0, stream>>>(X, T0, ln3s, ln3b);
  gemm_k<2,128,u16><<<G_FF1, 256, 0, stream>>>(T0, wff1t, MID, nullptr, nullptr, 3072, 768);
  gemm_k<6,64,u16><<<G_N768, 256, 0, stream>>>(MID, wff2t, X, out1, nullptr, 768, 3072);

  // ---- output 0 ----
  scatter_k<<<B_*S_, 256, 0, stream>>>(pos, X, hid, out0);
}

// Round 10
// 446.871 us; speedup vs baseline: 5.8442x; 1.0509x over previous
//
#include <hip/hip_runtime.h>
#include <hip/hip_bf16.h>

// Fetcher: SOC extraction -> [self-attn + cross-attn(img) + GELU-FFN] -> scatter-back.
// Round 9: V^T epilogue stores packed ushort4 (4 consecutive keys/lane) — was 64-lane
//          2B-scattered stores; the r-dimension of the D-fragment is contiguous in V^T.

#define B_    8
#define S_    4096
#define D_    768
#define N_    1024
#define FF_   3072
#define H_    12
#define DH_   64
#define KCAP  640
#define SOC_TOK 3
#define EOS_TOK 2

typedef __hip_bfloat16 bf16;
typedef unsigned short u16;
typedef __attribute__((ext_vector_type(8))) short short8;
typedef __attribute__((ext_vector_type(4))) float f32x4;

__device__ __forceinline__ u16 ftou16(float x){ union{bf16 b; u16 s;} c; c.b = __float2bfloat16(x); return c.s; }
__device__ __forceinline__ unsigned pk2(float lo, float hi){ return (unsigned)ftou16(lo) | ((unsigned)ftou16(hi)<<16); }

__device__ __forceinline__ f32x4 MFMA(short8 a, short8 b, f32x4 c){
  return __builtin_amdgcn_mfma_f32_16x16x32_bf16(a, b, c, 0, 0, 0);
}

__device__ __forceinline__ void gld16(const void* gp, void* lp){
  __builtin_amdgcn_global_load_lds(
    reinterpret_cast<const __attribute__((address_space(1))) unsigned int*>((size_t)gp),
    reinterpret_cast<__attribute__((address_space(3))) unsigned int*>((size_t)lp),
    16, 0, 0);
}

template<int N> __device__ __forceinline__ void vwait(){
  asm volatile("s_waitcnt vmcnt(%0)" :: "i"(N) : "memory");
}
__device__ __forceinline__ void wgbar(){ asm volatile("s_barrier" ::: "memory"); }

__device__ __forceinline__ int xcd_swz(){
  int id = blockIdx.x;
  return (id & 7) * ((int)gridDim.x >> 3) + (id >> 3);
}

// ---------------- scan body ----------------
__device__ void scan_body(const int* __restrict__ seq, int* __restrict__ pos,
                          int* __restrict__ src, int* __restrict__ counts, int b){
  int tid = threadIdx.x;
  __shared__ int sd[256];
  __shared__ int carryE, carryS;
  if (tid==0){ carryE=0; carryS=0; }
  __syncthreads();
  for (int c=0; c<S_; c+=256){
    int s   = c + tid;
    int tok = seq[b*S_ + s];
    int isE = (tok==EOS_TOK) ? 1 : 0;
    int isS = (tok==SOC_TOK) ? 1 : 0;
    sd[tid]=isE; __syncthreads();
    for (int off=1; off<256; off<<=1){ int t_=(tid>=off)?sd[tid-off]:0; __syncthreads(); sd[tid]+=t_; __syncthreads(); }
    int eIncl = sd[tid];
    int eTot  = sd[255];
    int valid = (isS && (carryE + eIncl)==0) ? 1 : 0;
    __syncthreads();
    sd[tid]=valid; __syncthreads();
    for (int off=1; off<256; off<<=1){ int t_=(tid>=off)?sd[tid-off]:0; __syncthreads(); sd[tid]+=t_; __syncthreads(); }
    int vIncl = sd[tid];
    int vTot  = sd[255];
    if (valid){
      int slot = carryS + vIncl - 1;
      pos[b*S_ + s] = slot;
      if (slot < KCAP) src[b*KCAP + slot] = s;
    } else {
      pos[b*S_ + s] = -1;
    }
    __syncthreads();
    if (tid==0){ carryE += eTot; carryS += vTot; }
    __syncthreads();
  }
  if (tid==0) counts[b] = (carryS < KCAP) ? carryS : KCAP;
}

// ---------------- transpose + scan, one launch ----------------
struct TransArgs { const float* w[10]; u16* o[10]; };
__global__ __launch_bounds__(256) void transpose_scan_k(TransArgs a, const int* __restrict__ seq,
                                                        int* __restrict__ pos, int* __restrict__ src,
                                                        int* __restrict__ counts){
  int id = blockIdx.x;
  if (id >= 9216){ scan_body(seq, pos, src, counts, id - 9216); return; }
  __shared__ float tile[32][33];
  int wi, t, K, N;
  if (id < 4608){ wi = id/576; t = id%576; K = 768; N = 768; }
  else if (id < 6912){ wi = 8; t = id-4608; K = 768; N = 3072; }
  else { wi = 9; t = id-6912; K = 3072; N = 768; }
  const float* in = a.w[wi]; u16* out = a.o[wi];
  int nbx = N >> 5;
  int bx = t % nbx, by = t / nbx;
  int tx = threadIdx.x & 31, ty = threadIdx.x >> 5;
  #pragma unroll
  for (int i=0;i<4;++i)
    tile[ty + i*8][tx] = in[(size_t)(by*32 + ty + i*8)*N + bx*32 + tx];
  __syncthreads();
  #pragma unroll
  for (int i=0;i<4;++i)
    out[(size_t)(bx*32 + ty + i*8)*K + by*32 + tx] = ftou16(tile[tx][ty + i*8]);
}

// ---------------- gather + LN1 fused ----------------
__global__ __launch_bounds__(256) void gather_ln_k(const float* __restrict__ hid,
                                                   const int* __restrict__ src,
                                                   const int* __restrict__ counts,
                                                   const float* __restrict__ g, const float* __restrict__ bt,
                                                   float* __restrict__ X, u16* __restrict__ T0){
  int bk = blockIdx.x; int b = bk / KCAP; int k = bk % KCAP;
  int tid = threadIdx.x;
  float v0, v1, v2;
  if (k < counts[b]){
    const float* hr = hid + ((size_t)b*S_ + src[b*KCAP + k])*D_;
    v0 = hr[tid]; v1 = hr[tid+256]; v2 = hr[tid+512];
  } else { v0 = v1 = v2 = 0.f; }
  float* xr = X + (size_t)bk*D_;
  xr[tid] = v0; xr[tid+256] = v1; xr[tid+512] = v2;
  float s1=v0+v1+v2, s2=v0*v0+v1*v1+v2*v2;
  for (int off=32; off; off>>=1){ s1+=__shfl_xor(s1,off); s2+=__shfl_xor(s2,off); }
  __shared__ float red[8];
  __shared__ float mu_s, rs_s;
  int w=tid>>6, ln=tid&63;
  if (ln==0){ red[w]=s1; red[4+w]=s2; }
  __syncthreads();
  if (tid==0){
    float S1=red[0]+red[1]+red[2]+red[3];
    float S2=red[4]+red[5]+red[6]+red[7];
    float mu = S1*(1.f/D_);
    float var= S2*(1.f/D_) - mu*mu;
    mu_s=mu; rs_s=rsqrtf(var + 1e-5f);
  }
  __syncthreads();
  float mu=mu_s, rs=rs_s;
  u16* yr = T0 + (size_t)bk*D_;
  yr[tid]     = ftou16((v0-mu)*rs*g[tid]     + bt[tid]);
  yr[tid+256] = ftou16((v1-mu)*rs*g[tid+256] + bt[tid+256]);
  yr[tid+512] = ftou16((v2-mu)*rs*g[tid+512] + bt[tid+512]);
}

// ---------------- layernorm ----------------
__global__ __launch_bounds__(256) void ln_k(const float* __restrict__ X, u16* __restrict__ Y,
                                            const float* __restrict__ g, const float* __restrict__ bt){
  int r = blockIdx.x; int tid = threadIdx.x;
  const float* xr = X + (size_t)r*D_;
  float v0=xr[tid], v1=xr[tid+256], v2=xr[tid+512];
  float s1=v0+v1+v2, s2=v0*v0+v1*v1+v2*v2;
  for (int off=32; off; off>>=1){ s1+=__shfl_xor(s1,off); s2+=__shfl_xor(s2,off); }
  __shared__ float red[8];
  __shared__ float mu_s, rs_s;
  int w=tid>>6, ln=tid&63;
  if (ln==0){ red[w]=s1; red[4+w]=s2; }
  __syncthreads();
  if (tid==0){
    float S1=red[0]+red[1]+red[2]+red[3];
    float S2=red[4]+red[5]+red[6]+red[7];
    float mu = S1*(1.f/D_);
    float var= S2*(1.f/D_) - mu*mu;
    mu_s=mu; rs_s=rsqrtf(var + 1e-5f);
  }
  __syncthreads();
  float mu=mu_s, rs=rs_s;
  u16* yr = Y + (size_t)r*D_;
  yr[tid]     = ftou16((v0-mu)*rs*g[tid]     + bt[tid]);
  yr[tid+256] = ftou16((v1-mu)*rs*g[tid+256] + bt[tid+256]);
  yr[tid+512] = ftou16((v2-mu)*rs*g[tid+512] + bt[tid+512]);
}

// ---------------- MFMA GEMM body ----------------
// MODE 0: C0_bf16 ; 1: C0_f32 += ; 2: C0_bf16 = gelu ; 6: C0_f32 +=, C1_f32 = result
// MODE 4: self QKV (N=2304): Q->C0, K->C1, V^T->C2 [b][768][KCAP]  (V writes ushort4-packed)
// MODE 5: cross KV (N=1536): K->C0, V^T->C2 [b][768][1024]         (V writes ushort4-packed)
template<int MODE, int BM, typename TA>
__device__ __forceinline__ void gemm_body(char* ldsp, const TA* __restrict__ A, const u16* __restrict__ Bt,
                                          void* __restrict__ C0, void* __restrict__ C1, void* __restrict__ C2,
                                          int wgid, int N, int K){
  constexpr int MI   = BM/32;
  constexpr int NBUF = (BM==128) ? 2 : ((sizeof(TA)==4) ? 2 : 3);
  u16* As = (u16*)ldsp;
  u16* Bs = (u16*)(ldsp + NBUF*(BM*32)*2);
  int nbx = N >> 7;
  int bx = wgid % nbx, by = wgid / nbx;
  int tid = threadIdx.x;
  int w = tid>>6, l = tid&63, g = l>>4, c = l&15;
  int wr = w&1, wc = w>>1;
  f32x4 acc[MI][4] = {};
  float4 rg[4];
  const int NK = K/32;

  auto STAGEB = [&](int buf, int kt){
    #pragma unroll
    for (int p=0;p<2;++p){
      int row = w*32 + p*16 + (l>>2);
      int su  = (l&3) ^ ((row>>1)&3);
      gld16((const void*)(Bt + (size_t)(bx*128+row)*K + kt + su*8), (void*)&Bs[buf*128*32 + (w*32+p*16)*32]);
    }
  };
  auto STAGEA16 = [&](int buf, int kt){
    if constexpr (BM==128){
      #pragma unroll
      for (int p=0;p<2;++p){
        int row = w*32 + p*16 + (l>>2);
        int su  = (l&3) ^ ((row>>1)&3);
        gld16((const void*)((const u16*)A + (size_t)(by*BM+row)*K + kt + su*8), (void*)&As[buf*BM*32 + (w*32+p*16)*32]);
      }
    } else {
      int row = w*16 + (l>>2);
      int su  = (l&3) ^ ((row>>1)&3);
      gld16((const void*)((const u16*)A + (size_t)(by*BM+row)*K + kt + su*8), (void*)&As[buf*BM*32 + (w*16)*32]);
    }
  };
  auto LOADREG = [&](int kt){
    if constexpr (BM==128){
      const float* ap = (const float*)A + (size_t)(by*BM + (tid>>1))*K + kt + (tid&1)*16;
      rg[0]=*(const float4*)ap;     rg[1]=*(const float4*)(ap+4);
      rg[2]=*(const float4*)(ap+8); rg[3]=*(const float4*)(ap+12);
    } else {
      const float* ap = (const float*)A + (size_t)(by*BM + (tid>>2))*K + kt + (tid&3)*8;
      rg[0] = *(const float4*)ap; rg[1] = *(const float4*)(ap+4);
    }
  };
  auto WRITEA = [&](int buf){
    if constexpr (BM==128){
      int row = tid>>1, half = tid&1;
      uint4 w0,w1;
      w0.x=pk2(rg[0].x,rg[0].y); w0.y=pk2(rg[0].z,rg[0].w); w0.z=pk2(rg[1].x,rg[1].y); w0.w=pk2(rg[1].z,rg[1].w);
      w1.x=pk2(rg[2].x,rg[2].y); w1.y=pk2(rg[2].z,rg[2].w); w1.z=pk2(rg[3].x,rg[3].y); w1.w=pk2(rg[3].z,rg[3].w);
      int sw = (row>>1)&3;
      *(uint4*)&As[buf*BM*32 + row*32 + ((half*2  )^sw)*8] = w0;
      *(uint4*)&As[buf*BM*32 + row*32 + ((half*2+1)^sw)*8] = w1;
    } else {
      int row = tid>>2, unit = tid&3;
      uint4 wv;
      wv.x=pk2(rg[0].x,rg[0].y); wv.y=pk2(rg[0].z,rg[0].w); wv.z=pk2(rg[1].x,rg[1].y); wv.w=pk2(rg[1].z,rg[1].w);
      int sw = (row>>1)&3;
      *(uint4*)&As[buf*BM*32 + row*32 + (unit^sw)*8] = wv;
    }
  };
  auto COMPUTE = [&](int buf){
    short8 af[MI], bfr[4];
    #pragma unroll
    for (int mi=0;mi<MI;++mi){ int row = wr*(MI*16) + mi*16 + c; af[mi]  = *(const short8*)&As[buf*BM*32 + row*32 + (g^((row>>1)&3))*8]; }
    #pragma unroll
    for (int ni=0;ni<4;++ni){ int row = wc*64 + ni*16 + c;       bfr[ni] = *(const short8*)&Bs[buf*128*32 + row*32 + (g^((row>>1)&3))*8]; }
    #pragma unroll
    for (int mi=0;mi<MI;++mi)
      #pragma unroll
      for (int ni=0;ni<4;++ni) acc[mi][ni] = MFMA(af[mi], bfr[ni], acc[mi][ni]);
  };

  if constexpr (BM==128 || sizeof(TA)==4){
    if constexpr (sizeof(TA)==4){ LOADREG(0); STAGEB(0,0); WRITEA(0); }
    else { STAGEA16(0,0); STAGEB(0,0); }
    __syncthreads();
    int buf = 0;
    for (int t=0;t<NK;++t){
      int ktn = (t+1)*32;
      if constexpr (sizeof(TA)==4){
        if (t+1<NK){ LOADREG(ktn); STAGEB(buf^1, ktn); }
        COMPUTE(buf);
        if (t+1<NK) WRITEA(buf^1);
      } else {
        if (t+1<NK){ STAGEA16(buf^1, ktn); STAGEB(buf^1, ktn); }
        COMPUTE(buf);
      }
      __syncthreads();
      buf ^= 1;
    }
  } else {
    constexpr int LPS = 3;
    STAGEA16(0,0);  STAGEB(0,0);
    STAGEA16(1,32); STAGEB(1,32);
    vwait<LPS>();
    wgbar();
    int buf = 0;
    for (int t=0;t<NK;++t){
      if (t+2 < NK){
        int nb = buf+2; if (nb>=3) nb-=3;
        STAGEA16(nb,(t+2)*32); STAGEB(nb,(t+2)*32);
      }
      COMPUTE(buf);
      if (t < NK-2) vwait<LPS>(); else vwait<0>();
      wgbar();
      ++buf; if (buf==3) buf=0;
    }
  }

  int row0 = by*BM + wr*(MI*16), col0 = bx*128 + wc*64;
  #pragma unroll
  for (int mi=0;mi<MI;++mi)
    #pragma unroll
    for (int ni=0;ni<4;++ni){
      int rowb = row0 + mi*16 + g*4;          // base of 4 consecutive rows (keys)
      int col  = col0 + ni*16 + c;
      if (MODE==4 && col >= 1536){
        // V^T packed write: 4 consecutive keys (r=0..3) at same vv -> one 8B store
        int vv = col - 1536; int bb = rowb / KCAP; int key = rowb - bb*KCAP;
        ushort4 pk;
        pk.x = ftou16(acc[mi][ni][0]); pk.y = ftou16(acc[mi][ni][1]);
        pk.z = ftou16(acc[mi][ni][2]); pk.w = ftou16(acc[mi][ni][3]);
        *(ushort4*)&((u16*)C2)[((size_t)(bb*768 + vv))*KCAP + key] = pk;
      } else if (MODE==5 && col >= 768){
        int vv = col - 768; int bb = rowb >> 10; int key = rowb & 1023;
        ushort4 pk;
        pk.x = ftou16(acc[mi][ni][0]); pk.y = ftou16(acc[mi][ni][1]);
        pk.z = ftou16(acc[mi][ni][2]); pk.w = ftou16(acc[mi][ni][3]);
        *(ushort4*)&((u16*)C2)[((size_t)(bb*768 + vv))*1024 + key] = pk;
      } else {
        #pragma unroll
        for (int r=0;r<4;++r){
          int row = rowb + r;
          float v = acc[mi][ni][r];
          if (MODE==0){
            ((u16*)C0)[(size_t)row*N + col] = ftou16(v);
          } else if (MODE==1){
            ((float*)C0)[(size_t)row*N + col] += v;
          } else if (MODE==2){
            float z2 = 1.5957691216057308f*(v + 0.044715f*v*v*v);
            float e  = __expf(z2);
            float th = 1.f - 2.f/(e + 1.f);
            ((u16*)C0)[(size_t)row*N + col] = ftou16(0.5f*v*(1.f+th));
          } else if (MODE==6){
            size_t idx = (size_t)row*N + col;
            float fin = ((float*)C0)[idx] + v;
            ((float*)C0)[idx] = fin;
            ((float*)C1)[idx] = fin;
          } else if (MODE==4){
            if (col < 768)  ((u16*)C0)[(size_t)row*768 + col]       = ftou16(v);
            else            ((u16*)C1)[(size_t)row*768 + col - 768] = ftou16(v);
          } else { // MODE 5, col < 768
            ((u16*)C0)[(size_t)row*768 + col] = ftou16(v);
          }
        }
      }
    }
}

template<int MODE, int BM, typename TA>
__global__ __launch_bounds__(256) void gemm_k(const TA* __restrict__ A, const u16* __restrict__ Bt,
                                              void* __restrict__ C0, void* __restrict__ C1, void* __restrict__ C2,
                                              int N, int K){
  constexpr int NBUF = (BM==128) ? 2 : ((sizeof(TA)==4) ? 2 : 3);
  __shared__ __align__(16) char pool[NBUF*(BM+128)*32*2];
  gemm_body<MODE,BM,TA>(pool, A, Bt, C0, C1, C2, xcd_swz(), N, K);
}

// mega1: self QKV (720 blocks) + cross img KV (768 blocks), both BM=128, one dispatch
__global__ __launch_bounds__(256) void mega1_k(const u16* __restrict__ T0, const u16* __restrict__ wqkv_st,
                                               u16* __restrict__ Qb, u16* __restrict__ Kb, u16* __restrict__ VtS,
                                               const float* __restrict__ img, const u16* __restrict__ wkv_ct,
                                               u16* __restrict__ KbC, u16* __restrict__ VtC){
  __shared__ __align__(16) char pool[2*(128+128)*32*2];
  int wgid = xcd_swz();   // grid = 1488
  if (wgid < 720) gemm_body<4,128,u16>  (pool, T0,  wqkv_st, Qb,  Kb,      VtS, wgid,     2304, 768);
  else            gemm_body<5,128,float>(pool, img, wkv_ct,  KbC, nullptr, VtC, wgid-720, 1536, 768);
}

// ---------------- MFMA flash attention ----------------
template<int MASKED>
__global__ __launch_bounds__(256) void attn_k(const u16* __restrict__ Q, const u16* __restrict__ Kb,
                                              const u16* __restrict__ Vt, u16* __restrict__ O,
                                              const int* __restrict__ counts, int Lk){
  __shared__ __align__(16) u16 Ks[3][64*64];
  __shared__ __align__(16) u16 Vs[3][64*64];
  __shared__ __align__(16) u16 P[4][16][72];
  int tid = threadIdx.x;
  int w = tid>>6, l = tid&63, g = l>>4, c = l&15;
  int wgid = xcd_swz();
  int qc = wgid % 5;
  int bh = wgid / 5;
  int h = bh % H_, b = bh / H_;
  int q0 = qc*128 + w*32;
  int cnt = MASKED ? counts[b] : Lk;
  int nt = (cnt + 63) >> 6;

  short8 qf[2][2];
  #pragma unroll
  for (int mi=0;mi<2;++mi){
    const u16* Qrow = Q + ((size_t)(b*KCAP + q0 + mi*16 + c))*D_ + h*DH_;
    qf[mi][0] = *(const short8*)(Qrow + g*8);
    qf[mi][1] = *(const short8*)(Qrow + 32 + g*8);
  }

  int srow8 = (l>>3);
  int sunit = l&7;
  auto STAGE = [&](int buf, int kb){
    #pragma unroll
    for (int p=0;p<2;++p){
      int r0 = w*16 + p*8;
      int rowK = r0 + srow8;
      int su = sunit ^ (rowK&7);
      gld16((const void*)(Kb + ((size_t)(b*Lk + kb + rowK))*D_ + h*DH_ + su*8), (void*)&Ks[buf][r0*64]);
      gld16((const void*)(Vt + ((size_t)(b*D_ + h*DH_ + rowK))*Lk + kb + su*8), (void*)&Vs[buf][r0*64]);
    }
  };

  f32x4 o[2][4] = {};
  float m_[2][4], l_[2][4] = {};
  #pragma unroll
  for (int mi=0;mi<2;++mi)
    #pragma unroll
    for (int r=0;r<4;++r) m_[mi][r] = -1e30f;

  STAGE(0, 0);
  if (nt > 1){ STAGE(1, 64); vwait<4>(); } else { vwait<0>(); }
  wgbar();
  int buf = 0;
  for (int t=0; t<nt; ++t){
    int kb = t*64;
    if (t+2 < nt){
      int nb = buf+2; if (nb>=3) nb-=3;
      STAGE(nb, kb+128);
    }
    short8 fr[4][2];
    #pragma unroll
    for (int nb=0;nb<4;++nb)
      #pragma unroll
      for (int kh=0;kh<2;++kh)
        fr[nb][kh] = *(const short8*)&Ks[buf][(nb*16+c)*64 + (((kh<<2)|g) ^ (c&7))*8];
    f32x4 z[2][4];
    #pragma unroll
    for (int mi=0;mi<2;++mi)
      #pragma unroll
      for (int nb=0;nb<4;++nb){
        f32x4 zz = {0.f,0.f,0.f,0.f};
        zz = MFMA(qf[mi][0], fr[nb][0], zz);
        zz = MFMA(qf[mi][1], fr[nb][1], zz);
        z[mi][nb] = zz;
      }
    float pv[2][4][4];
    #pragma unroll
    for (int nb=0;nb<4;++nb){
      bool msk = MASKED && (kb + nb*16 + c >= cnt);
      #pragma unroll
      for (int mi=0;mi<2;++mi)
        #pragma unroll
        for (int r=0;r<4;++r) pv[mi][nb][r] = msk ? -1e30f : z[mi][nb][r]*0.125f;
    }
    float scl[2][4];
    #pragma unroll
    for (int mi=0;mi<2;++mi){
      #pragma unroll
      for (int r=0;r<4;++r){
        float v = fmaxf(fmaxf(pv[mi][0][r],pv[mi][1][r]), fmaxf(pv[mi][2][r],pv[mi][3][r]));
        v = fmaxf(v, __shfl_xor(v,1)); v = fmaxf(v, __shfl_xor(v,2));
        v = fmaxf(v, __shfl_xor(v,4)); v = fmaxf(v, __shfl_xor(v,8));
        float nm = fmaxf(m_[mi][r], v);
        scl[mi][r] = __expf(m_[mi][r] - nm);
        m_[mi][r] = nm;
      }
      #pragma unroll
      for (int r=0;r<4;++r){
        float acc2 = 0.f;
        #pragma unroll
        for (int nb=0;nb<4;++nb){
          float e = __expf(pv[mi][nb][r] - m_[mi][r]);
          pv[mi][nb][r] = e; acc2 += e;
        }
        acc2 += __shfl_xor(acc2,1); acc2 += __shfl_xor(acc2,2);
        acc2 += __shfl_xor(acc2,4); acc2 += __shfl_xor(acc2,8);
        l_[mi][r] = l_[mi][r]*scl[mi][r] + acc2;
      }
      #pragma unroll
      for (int nbd=0;nbd<4;++nbd)
        #pragma unroll
        for (int r=0;r<4;++r) o[mi][nbd][r] *= scl[mi][r];
    }
    #pragma unroll
    for (int nbd=0;nbd<4;++nbd)
      #pragma unroll
      for (int kh=0;kh<2;++kh)
        fr[nbd][kh] = *(const short8*)&Vs[buf][(nbd*16+c)*64 + (((kh<<2)|g) ^ (c&7))*8];
    #pragma unroll
    for (int mi=0;mi<2;++mi){
      #pragma unroll
      for (int nb=0;nb<4;++nb)
        #pragma unroll
        for (int r=0;r<4;++r) P[w][g*4+r][nb*16+c] = ftou16(pv[mi][nb][r]);
      short8 pa0 = *(const short8*)&P[w][c][g*8];
      short8 pa1 = *(const short8*)&P[w][c][32 + g*8];
      #pragma unroll
      for (int nbd=0;nbd<4;++nbd){
        o[mi][nbd] = MFMA(pa0, fr[nbd][0], o[mi][nbd]);
        o[mi][nbd] = MFMA(pa1, fr[nbd][1], o[mi][nbd]);
      }
    }
    if (t < nt-2) vwait<4>(); else vwait<0>();
    wgbar();
    ++buf; if (buf==3) buf=0;
  }
  #pragma unroll
  for (int mi=0;mi<2;++mi)
    #pragma unroll
    for (int nbd=0;nbd<4;++nbd)
      #pragma unroll
      for (int r=0;r<4;++r)
        O[((size_t)(b*KCAP + q0 + mi*16 + g*4 + r))*D_ + h*DH_ + nbd*16 + c] = ftou16(o[mi][nbd][r] / l_[mi][r]);
}

// ---------------- scatter back ----------------
__global__ __launch_bounds__(256) void scatter_k(const int* __restrict__ pos, const float* __restrict__ X,
                                                 const float* __restrict__ hid, float* __restrict__ out0){
  int bs = blockIdx.x; int tid = threadIdx.x;
  int b = bs >> 12;
  int p = pos[bs];
  float* orow = out0 + (size_t)bs*D_;
  if (p >= 0){
    int pc = p < KCAP ? p : (KCAP-1);
    const float* xr = X + ((size_t)(b*KCAP + pc))*D_;
    orow[tid]     = xr[tid];
    orow[tid+256] = xr[tid+256];
    orow[tid+512] = xr[tid+512];
  } else {
    const float* hr = hid + (size_t)bs*D_;
    orow[tid]     = hr[tid];
    orow[tid+256] = hr[tid+256];
    orow[tid+512] = hr[tid+512];
  }
}

extern "C" void kernel_launch(void* const* d_in, const int* in_sizes, int n_in,
                              void* d_out, int out_size, void* d_ws, size_t ws_size,
                              hipStream_t stream){
  const float* img  = (const float*)d_in[0];
  const float* hid  = (const float*)d_in[1];
  const int*   seq  = (const int*)  d_in[2];
  const float* W[10] = { (const float*)d_in[3], (const float*)d_in[4], (const float*)d_in[5], (const float*)d_in[6],
                         (const float*)d_in[7], (const float*)d_in[8], (const float*)d_in[9], (const float*)d_in[10],
                         (const float*)d_in[11], (const float*)d_in[12] };
  const float* ln1s = (const float*)d_in[13];
  const float* ln1b = (const float*)d_in[14];
  const float* ln2s = (const float*)d_in[15];
  const float* ln2b = (const float*)d_in[16];
  const float* ln3s = (const float*)d_in[17];
  const float* ln3b = (const float*)d_in[18];

  char* ws = (char*)d_ws;
  int*   pos    = (int*)  (ws + 0);
  int*   src    = (int*)  (ws + 131072);
  int*   counts = (int*)  (ws + 151552);
  float* X      = (float*)(ws + 151808);
  u16*   T0     = (u16*)  (ws + 15880448);
  u16*   Qb     = (u16*)  (ws + 23744768);
  u16*   Kb     = (u16*)  (ws + 31609088);
  u16*   VtS    = (u16*)  (ws + 39473408);
  u16*   KbC    = (u16*)  (ws + 47337728);
  u16*   VtC    = (u16*)  (ws + 59920640);
  u16*   AO     = (u16*)  (ws + 72503552);
  u16*   Wt     = (u16*)  (ws + 80367872);
  u16*   MID    = Qb;

  u16* wqkv_st = Wt + 0ull*589824;
  u16* wo_st   = Wt + 3ull*589824;
  u16* wq_ct   = Wt + 4ull*589824;
  u16* wkv_ct  = Wt + 5ull*589824;
  u16* wo_ct   = Wt + 7ull*589824;
  u16* wff1t   = Wt + 8ull*589824;
  u16* wff2t   = wff1t + 2359296;

  float* out0 = (float*)d_out;
  float* out1 = out0 + (size_t)B_*S_*D_;

  TransArgs ta;
  for (int i=0;i<10;++i) ta.w[i] = W[i];
  for (int i=0;i<8;++i)  ta.o[i] = Wt + (size_t)i*589824;
  ta.o[8] = wff1t; ta.o[9] = wff2t;

  transpose_scan_k<<<9224, 256, 0, stream>>>(ta, seq, pos, src, counts);
  gather_ln_k<<<B_*KCAP, 256, 0, stream>>>(hid, src, counts, ln1s, ln1b, X, T0);

  const int G_MEGA1 = 720 + 768;             // 1488
  const int G_N768  = (5120/64)*(768/128);   // 480
  const int G_FF1   = (5120/128)*(3072/128); // 960
  const int G_ATT   = B_*H_*5;               // 480

  // ---- self-attention block (+ independent img KV projection fused) ----
  mega1_k<<<G_MEGA1, 256, 0, stream>>>(T0, wqkv_st, Qb, Kb, VtS, img, wkv_ct, KbC, VtC);
  attn_k<1><<<G_ATT, 256, 0, stream>>>(Qb, Kb, VtS, AO, counts, KCAP);
  gemm_k<1,64,u16><<<G_N768, 256, 0, stream>>>(AO, wo_st, X, nullptr, nullptr, 768, 768);

  // ---- cross-attention block ----
  ln_k<<<5120, 256, 0, stream>>>(X, T0, ln2s, ln2b);
  gemm_k<0,64,u16><<<G_N768, 256, 0, stream>>>(T0, wq_ct, Qb, nullptr, nullptr, 768, 768);
  attn_k<0><<<G_ATT, 256, 0, stream>>>(Qb, KbC, VtC, AO, counts, N_);
  gemm_k<1,64,u16><<<G_N768, 256, 0, stream>>>(AO, wo_ct, X, nullptr, nullptr, 768, 768);

  // ---- FFN block (FF2 epilogue also emits out1) ----
  ln_k<<<5120, 256, 0, stream>>>(X, T0, ln3s, ln3b);
  gemm_k<2,128,u16><<<G_FF1, 256, 0, stream>>>(T0, wff1t, MID, nullptr, nullptr, 3072, 768);
  gemm_k<6,64,u16><<<G_N768, 256, 0, stream>>>(MID, wff2t, X, out1, nullptr, 768, 3072);

  // ---- output 0 ----
  scatter_k<<<B_*S_, 256, 0, stream>>>(pos, X, hid, out0);
}

// Round 11
// 427.429 us; speedup vs baseline: 6.1101x; 1.0455x over previous
//
#include <hip/hip_runtime.h>
#include <hip/hip_bf16.h>

// Fetcher: SOC extraction -> [self-attn + cross-attn(img) + GELU-FFN] -> scatter-back.
// Round 10: img pre-converted to bf16 (scratch = out1 region of d_out, rewritten by FF2),
//           so mega1's img-KV half uses the same global_load_lds bf16 path as QKV.

#define B_    8
#define S_    4096
#define D_    768
#define N_    1024
#define FF_   3072
#define H_    12
#define DH_   64
#define KCAP  640
#define SOC_TOK 3
#define EOS_TOK 2

typedef __hip_bfloat16 bf16;
typedef unsigned short u16;
typedef __attribute__((ext_vector_type(8))) short short8;
typedef __attribute__((ext_vector_type(4))) float f32x4;

__device__ __forceinline__ u16 ftou16(float x){ union{bf16 b; u16 s;} c; c.b = __float2bfloat16(x); return c.s; }
__device__ __forceinline__ unsigned pk2(float lo, float hi){ return (unsigned)ftou16(lo) | ((unsigned)ftou16(hi)<<16); }

__device__ __forceinline__ f32x4 MFMA(short8 a, short8 b, f32x4 c){
  return __builtin_amdgcn_mfma_f32_16x16x32_bf16(a, b, c, 0, 0, 0);
}

__device__ __forceinline__ void gld16(const void* gp, void* lp){
  __builtin_amdgcn_global_load_lds(
    reinterpret_cast<const __attribute__((address_space(1))) unsigned int*>((size_t)gp),
    reinterpret_cast<__attribute__((address_space(3))) unsigned int*>((size_t)lp),
    16, 0, 0);
}

template<int N> __device__ __forceinline__ void vwait(){
  asm volatile("s_waitcnt vmcnt(%0)" :: "i"(N) : "memory");
}
__device__ __forceinline__ void wgbar(){ asm volatile("s_barrier" ::: "memory"); }

__device__ __forceinline__ int xcd_swz(){
  int id = blockIdx.x;
  return (id & 7) * ((int)gridDim.x >> 3) + (id >> 3);
}

// ---------------- scan body ----------------
__device__ void scan_body(const int* __restrict__ seq, int* __restrict__ pos,
                          int* __restrict__ src, int* __restrict__ counts, int b){
  int tid = threadIdx.x;
  __shared__ int sd[256];
  __shared__ int carryE, carryS;
  if (tid==0){ carryE=0; carryS=0; }
  __syncthreads();
  for (int c=0; c<S_; c+=256){
    int s   = c + tid;
    int tok = seq[b*S_ + s];
    int isE = (tok==EOS_TOK) ? 1 : 0;
    int isS = (tok==SOC_TOK) ? 1 : 0;
    sd[tid]=isE; __syncthreads();
    for (int off=1; off<256; off<<=1){ int t_=(tid>=off)?sd[tid-off]:0; __syncthreads(); sd[tid]+=t_; __syncthreads(); }
    int eIncl = sd[tid];
    int eTot  = sd[255];
    int valid = (isS && (carryE + eIncl)==0) ? 1 : 0;
    __syncthreads();
    sd[tid]=valid; __syncthreads();
    for (int off=1; off<256; off<<=1){ int t_=(tid>=off)?sd[tid-off]:0; __syncthreads(); sd[tid]+=t_; __syncthreads(); }
    int vIncl = sd[tid];
    int vTot  = sd[255];
    if (valid){
      int slot = carryS + vIncl - 1;
      pos[b*S_ + s] = slot;
      if (slot < KCAP) src[b*KCAP + slot] = s;
    } else {
      pos[b*S_ + s] = -1;
    }
    __syncthreads();
    if (tid==0){ carryE += eTot; carryS += vTot; }
    __syncthreads();
  }
  if (tid==0) counts[b] = (carryS < KCAP) ? carryS : KCAP;
}

// ---------------- transpose + scan + img->bf16 convert, one launch ----------------
struct TransArgs { const float* w[10]; u16* o[10]; };
__global__ __launch_bounds__(256) void transpose_scan_k(TransArgs a, const int* __restrict__ seq,
                                                        int* __restrict__ pos, int* __restrict__ src,
                                                        int* __restrict__ counts,
                                                        const float* __restrict__ img, u16* __restrict__ imgB){
  int id = blockIdx.x;
  if (id >= 9224){
    // img f32 -> bf16 convert: 3072 blocks x 2048 elems
    int base = (id - 9224)*2048 + threadIdx.x*8;
    float4 a0 = *(const float4*)(img + base);
    float4 a1 = *(const float4*)(img + base + 4);
    uint4 wv;
    wv.x = pk2(a0.x,a0.y); wv.y = pk2(a0.z,a0.w); wv.z = pk2(a1.x,a1.y); wv.w = pk2(a1.z,a1.w);
    *(uint4*)(imgB + base) = wv;
    return;
  }
  if (id >= 9216){ scan_body(seq, pos, src, counts, id - 9216); return; }
  __shared__ float tile[32][33];
  int wi, t, K, N;
  if (id < 4608){ wi = id/576; t = id%576; K = 768; N = 768; }
  else if (id < 6912){ wi = 8; t = id-4608; K = 768; N = 3072; }
  else { wi = 9; t = id-6912; K = 3072; N = 768; }
  const float* in = a.w[wi]; u16* out = a.o[wi];
  int nbx = N >> 5;
  int bx = t % nbx, by = t / nbx;
  int tx = threadIdx.x & 31, ty = threadIdx.x >> 5;
  #pragma unroll
  for (int i=0;i<4;++i)
    tile[ty + i*8][tx] = in[(size_t)(by*32 + ty + i*8)*N + bx*32 + tx];
  __syncthreads();
  #pragma unroll
  for (int i=0;i<4;++i)
    out[(size_t)(bx*32 + ty + i*8)*K + by*32 + tx] = ftou16(tile[tx][ty + i*8]);
}

// ---------------- gather + LN1 fused ----------------
__global__ __launch_bounds__(256) void gather_ln_k(const float* __restrict__ hid,
                                                   const int* __restrict__ src,
                                                   const int* __restrict__ counts,
                                                   const float* __restrict__ g, const float* __restrict__ bt,
                                                   float* __restrict__ X, u16* __restrict__ T0){
  int bk = blockIdx.x; int b = bk / KCAP; int k = bk % KCAP;
  int tid = threadIdx.x;
  float v0, v1, v2;
  if (k < counts[b]){
    const float* hr = hid + ((size_t)b*S_ + src[b*KCAP + k])*D_;
    v0 = hr[tid]; v1 = hr[tid+256]; v2 = hr[tid+512];
  } else { v0 = v1 = v2 = 0.f; }
  float* xr = X + (size_t)bk*D_;
  xr[tid] = v0; xr[tid+256] = v1; xr[tid+512] = v2;
  float s1=v0+v1+v2, s2=v0*v0+v1*v1+v2*v2;
  for (int off=32; off; off>>=1){ s1+=__shfl_xor(s1,off); s2+=__shfl_xor(s2,off); }
  __shared__ float red[8];
  __shared__ float mu_s, rs_s;
  int w=tid>>6, ln=tid&63;
  if (ln==0){ red[w]=s1; red[4+w]=s2; }
  __syncthreads();
  if (tid==0){
    float S1=red[0]+red[1]+red[2]+red[3];
    float S2=red[4]+red[5]+red[6]+red[7];
    float mu = S1*(1.f/D_);
    float var= S2*(1.f/D_) - mu*mu;
    mu_s=mu; rs_s=rsqrtf(var + 1e-5f);
  }
  __syncthreads();
  float mu=mu_s, rs=rs_s;
  u16* yr = T0 + (size_t)bk*D_;
  yr[tid]     = ftou16((v0-mu)*rs*g[tid]     + bt[tid]);
  yr[tid+256] = ftou16((v1-mu)*rs*g[tid+256] + bt[tid+256]);
  yr[tid+512] = ftou16((v2-mu)*rs*g[tid+512] + bt[tid+512]);
}

// ---------------- layernorm ----------------
__global__ __launch_bounds__(256) void ln_k(const float* __restrict__ X, u16* __restrict__ Y,
                                            const float* __restrict__ g, const float* __restrict__ bt){
  int r = blockIdx.x; int tid = threadIdx.x;
  const float* xr = X + (size_t)r*D_;
  float v0=xr[tid], v1=xr[tid+256], v2=xr[tid+512];
  float s1=v0+v1+v2, s2=v0*v0+v1*v1+v2*v2;
  for (int off=32; off; off>>=1){ s1+=__shfl_xor(s1,off); s2+=__shfl_xor(s2,off); }
  __shared__ float red[8];
  __shared__ float mu_s, rs_s;
  int w=tid>>6, ln=tid&63;
  if (ln==0){ red[w]=s1; red[4+w]=s2; }
  __syncthreads();
  if (tid==0){
    float S1=red[0]+red[1]+red[2]+red[3];
    float S2=red[4]+red[5]+red[6]+red[7];
    float mu = S1*(1.f/D_);
    float var= S2*(1.f/D_) - mu*mu;
    mu_s=mu; rs_s=rsqrtf(var + 1e-5f);
  }
  __syncthreads();
  float mu=mu_s, rs=rs_s;
  u16* yr = Y + (size_t)r*D_;
  yr[tid]     = ftou16((v0-mu)*rs*g[tid]     + bt[tid]);
  yr[tid+256] = ftou16((v1-mu)*rs*g[tid+256] + bt[tid+256]);
  yr[tid+512] = ftou16((v2-mu)*rs*g[tid+512] + bt[tid+512]);
}

// ---------------- MFMA GEMM body ----------------
// MODE 0: C0_bf16 ; 1: C0_f32 += ; 2: C0_bf16 = gelu ; 6: C0_f32 +=, C1_f32 = result
// MODE 4: self QKV (N=2304): Q->C0, K->C1, V^T->C2 [b][768][KCAP]  (V writes ushort4-packed)
// MODE 5: cross KV (N=1536): K->C0, V^T->C2 [b][768][1024]         (V writes ushort4-packed)
template<int MODE, int BM, typename TA>
__device__ __forceinline__ void gemm_body(char* ldsp, const TA* __restrict__ A, const u16* __restrict__ Bt,
                                          void* __restrict__ C0, void* __restrict__ C1, void* __restrict__ C2,
                                          int wgid, int N, int K){
  constexpr int MI   = BM/32;
  constexpr int NBUF = (BM==128) ? 2 : ((sizeof(TA)==4) ? 2 : 3);
  u16* As = (u16*)ldsp;
  u16* Bs = (u16*)(ldsp + NBUF*(BM*32)*2);
  int nbx = N >> 7;
  int bx = wgid % nbx, by = wgid / nbx;
  int tid = threadIdx.x;
  int w = tid>>6, l = tid&63, g = l>>4, c = l&15;
  int wr = w&1, wc = w>>1;
  f32x4 acc[MI][4] = {};
  float4 rg[4];
  const int NK = K/32;

  auto STAGEB = [&](int buf, int kt){
    #pragma unroll
    for (int p=0;p<2;++p){
      int row = w*32 + p*16 + (l>>2);
      int su  = (l&3) ^ ((row>>1)&3);
      gld16((const void*)(Bt + (size_t)(bx*128+row)*K + kt + su*8), (void*)&Bs[buf*128*32 + (w*32+p*16)*32]);
    }
  };
  auto STAGEA16 = [&](int buf, int kt){
    if constexpr (BM==128){
      #pragma unroll
      for (int p=0;p<2;++p){
        int row = w*32 + p*16 + (l>>2);
        int su  = (l&3) ^ ((row>>1)&3);
        gld16((const void*)((const u16*)A + (size_t)(by*BM+row)*K + kt + su*8), (void*)&As[buf*BM*32 + (w*32+p*16)*32]);
      }
    } else {
      int row = w*16 + (l>>2);
      int su  = (l&3) ^ ((row>>1)&3);
      gld16((const void*)((const u16*)A + (size_t)(by*BM+row)*K + kt + su*8), (void*)&As[buf*BM*32 + (w*16)*32]);
    }
  };
  auto LOADREG = [&](int kt){
    if constexpr (BM==128){
      const float* ap = (const float*)A + (size_t)(by*BM + (tid>>1))*K + kt + (tid&1)*16;
      rg[0]=*(const float4*)ap;     rg[1]=*(const float4*)(ap+4);
      rg[2]=*(const float4*)(ap+8); rg[3]=*(const float4*)(ap+12);
    } else {
      const float* ap = (const float*)A + (size_t)(by*BM + (tid>>2))*K + kt + (tid&3)*8;
      rg[0] = *(const float4*)ap; rg[1] = *(const float4*)(ap+4);
    }
  };
  auto WRITEA = [&](int buf){
    if constexpr (BM==128){
      int row = tid>>1, half = tid&1;
      uint4 w0,w1;
      w0.x=pk2(rg[0].x,rg[0].y); w0.y=pk2(rg[0].z,rg[0].w); w0.z=pk2(rg[1].x,rg[1].y); w0.w=pk2(rg[1].z,rg[1].w);
      w1.x=pk2(rg[2].x,rg[2].y); w1.y=pk2(rg[2].z,rg[2].w); w1.z=pk2(rg[3].x,rg[3].y); w1.w=pk2(rg[3].z,rg[3].w);
      int sw = (row>>1)&3;
      *(uint4*)&As[buf*BM*32 + row*32 + ((half*2  )^sw)*8] = w0;
      *(uint4*)&As[buf*BM*32 + row*32 + ((half*2+1)^sw)*8] = w1;
    } else {
      int row = tid>>2, unit = tid&3;
      uint4 wv;
      wv.x=pk2(rg[0].x,rg[0].y); wv.y=pk2(rg[0].z,rg[0].w); wv.z=pk2(rg[1].x,rg[1].y); wv.w=pk2(rg[1].z,rg[1].w);
      int sw = (row>>1)&3;
      *(uint4*)&As[buf*BM*32 + row*32 + (unit^sw)*8] = wv;
    }
  };
  auto COMPUTE = [&](int buf){
    short8 af[MI], bfr[4];
    #pragma unroll
    for (int mi=0;mi<MI;++mi){ int row = wr*(MI*16) + mi*16 + c; af[mi]  = *(const short8*)&As[buf*BM*32 + row*32 + (g^((row>>1)&3))*8]; }
    #pragma unroll
    for (int ni=0;ni<4;++ni){ int row = wc*64 + ni*16 + c;       bfr[ni] = *(const short8*)&Bs[buf*128*32 + row*32 + (g^((row>>1)&3))*8]; }
    #pragma unroll
    for (int mi=0;mi<MI;++mi)
      #pragma unroll
      for (int ni=0;ni<4;++ni) acc[mi][ni] = MFMA(af[mi], bfr[ni], acc[mi][ni]);
  };

  if constexpr (BM==128 || sizeof(TA)==4){
    if constexpr (sizeof(TA)==4){ LOADREG(0); STAGEB(0,0); WRITEA(0); }
    else { STAGEA16(0,0); STAGEB(0,0); }
    __syncthreads();
    int buf = 0;
    for (int t=0;t<NK;++t){
      int ktn = (t+1)*32;
      if constexpr (sizeof(TA)==4){
        if (t+1<NK){ LOADREG(ktn); STAGEB(buf^1, ktn); }
        COMPUTE(buf);
        if (t+1<NK) WRITEA(buf^1);
      } else {
        if (t+1<NK){ STAGEA16(buf^1, ktn); STAGEB(buf^1, ktn); }
        COMPUTE(buf);
      }
      __syncthreads();
      buf ^= 1;
    }
  } else {
    constexpr int LPS = 3;
    STAGEA16(0,0);  STAGEB(0,0);
    STAGEA16(1,32); STAGEB(1,32);
    vwait<LPS>();
    wgbar();
    int buf = 0;
    for (int t=0;t<NK;++t){
      if (t+2 < NK){
        int nb = buf+2; if (nb>=3) nb-=3;
        STAGEA16(nb,(t+2)*32); STAGEB(nb,(t+2)*32);
      }
      COMPUTE(buf);
      if (t < NK-2) vwait<LPS>(); else vwait<0>();
      wgbar();
      ++buf; if (buf==3) buf=0;
    }
  }

  int row0 = by*BM + wr*(MI*16), col0 = bx*128 + wc*64;
  #pragma unroll
  for (int mi=0;mi<MI;++mi)
    #pragma unroll
    for (int ni=0;ni<4;++ni){
      int rowb = row0 + mi*16 + g*4;          // base of 4 consecutive rows (keys)
      int col  = col0 + ni*16 + c;
      if (MODE==4 && col >= 1536){
        int vv = col - 1536; int bb = rowb / KCAP; int key = rowb - bb*KCAP;
        ushort4 pk;
        pk.x = ftou16(acc[mi][ni][0]); pk.y = ftou16(acc[mi][ni][1]);
        pk.z = ftou16(acc[mi][ni][2]); pk.w = ftou16(acc[mi][ni][3]);
        *(ushort4*)&((u16*)C2)[((size_t)(bb*768 + vv))*KCAP + key] = pk;
      } else if (MODE==5 && col >= 768){
        int vv = col - 768; int bb = rowb >> 10; int key = rowb & 1023;
        ushort4 pk;
        pk.x = ftou16(acc[mi][ni][0]); pk.y = ftou16(acc[mi][ni][1]);
        pk.z = ftou16(acc[mi][ni][2]); pk.w = ftou16(acc[mi][ni][3]);
        *(ushort4*)&((u16*)C2)[((size_t)(bb*768 + vv))*1024 + key] = pk;
      } else {
        #pragma unroll
        for (int r=0;r<4;++r){
          int row = rowb + r;
          float v = acc[mi][ni][r];
          if (MODE==0){
            ((u16*)C0)[(size_t)row*N + col] = ftou16(v);
          } else if (MODE==1){
            ((float*)C0)[(size_t)row*N + col] += v;
          } else if (MODE==2){
            float z2 = 1.5957691216057308f*(v + 0.044715f*v*v*v);
            float e  = __expf(z2);
            float th = 1.f - 2.f/(e + 1.f);
            ((u16*)C0)[(size_t)row*N + col] = ftou16(0.5f*v*(1.f+th));
          } else if (MODE==6){
            size_t idx = (size_t)row*N + col;
            float fin = ((float*)C0)[idx] + v;
            ((float*)C0)[idx] = fin;
            ((float*)C1)[idx] = fin;
          } else if (MODE==4){
            if (col < 768)  ((u16*)C0)[(size_t)row*768 + col]       = ftou16(v);
            else            ((u16*)C1)[(size_t)row*768 + col - 768] = ftou16(v);
          } else { // MODE 5, col < 768
            ((u16*)C0)[(size_t)row*768 + col] = ftou16(v);
          }
        }
      }
    }
}

template<int MODE, int BM, typename TA>
__global__ __launch_bounds__(256) void gemm_k(const TA* __restrict__ A, const u16* __restrict__ Bt,
                                              void* __restrict__ C0, void* __restrict__ C1, void* __restrict__ C2,
                                              int N, int K){
  constexpr int NBUF = (BM==128) ? 2 : ((sizeof(TA)==4) ? 2 : 3);
  __shared__ __align__(16) char pool[NBUF*(BM+128)*32*2];
  gemm_body<MODE,BM,TA>(pool, A, Bt, C0, C1, C2, xcd_swz(), N, K);
}

// mega1: self QKV (720 blocks) + cross img KV (768 blocks), both BM=128 bf16-A, one dispatch
__global__ __launch_bounds__(256) void mega1_k(const u16* __restrict__ T0, const u16* __restrict__ wqkv_st,
                                               u16* __restrict__ Qb, u16* __restrict__ Kb, u16* __restrict__ VtS,
                                               const u16* __restrict__ imgB, const u16* __restrict__ wkv_ct,
                                               u16* __restrict__ KbC, u16* __restrict__ VtC){
  __shared__ __align__(16) char pool[2*(128+128)*32*2];
  int wgid = xcd_swz();   // grid = 1488
  if (wgid < 720) gemm_body<4,128,u16>(pool, T0,   wqkv_st, Qb,  Kb,      VtS, wgid,     2304, 768);
  else            gemm_body<5,128,u16>(pool, imgB, wkv_ct,  KbC, nullptr, VtC, wgid-720, 1536, 768);
}

// ---------------- MFMA flash attention ----------------
template<int MASKED>
__global__ __launch_bounds__(256) void attn_k(const u16* __restrict__ Q, const u16* __restrict__ Kb,
                                              const u16* __restrict__ Vt, u16* __restrict__ O,
                                              const int* __restrict__ counts, int Lk){
  __shared__ __align__(16) u16 Ks[3][64*64];
  __shared__ __align__(16) u16 Vs[3][64*64];
  __shared__ __align__(16) u16 P[4][16][72];
  int tid = threadIdx.x;
  int w = tid>>6, l = tid&63, g = l>>4, c = l&15;
  int wgid = xcd_swz();
  int qc = wgid % 5;
  int bh = wgid / 5;
  int h = bh % H_, b = bh / H_;
  int q0 = qc*128 + w*32;
  int cnt = MASKED ? counts[b] : Lk;
  int nt = (cnt + 63) >> 6;

  short8 qf[2][2];
  #pragma unroll
  for (int mi=0;mi<2;++mi){
    const u16* Qrow = Q + ((size_t)(b*KCAP + q0 + mi*16 + c))*D_ + h*DH_;
    qf[mi][0] = *(const short8*)(Qrow + g*8);
    qf[mi][1] = *(const short8*)(Qrow + 32 + g*8);
  }

  int srow8 = (l>>3);
  int sunit = l&7;
  auto STAGE = [&](int buf, int kb){
    #pragma unroll
    for (int p=0;p<2;++p){
      int r0 = w*16 + p*8;
      int rowK = r0 + srow8;
      int su = sunit ^ (rowK&7);
      gld16((const void*)(Kb + ((size_t)(b*Lk + kb + rowK))*D_ + h*DH_ + su*8), (void*)&Ks[buf][r0*64]);
      gld16((const void*)(Vt + ((size_t)(b*D_ + h*DH_ + rowK))*Lk + kb + su*8), (void*)&Vs[buf][r0*64]);
    }
  };

  f32x4 o[2][4] = {};
  float m_[2][4], l_[2][4] = {};
  #pragma unroll
  for (int mi=0;mi<2;++mi)
    #pragma unroll
    for (int r=0;r<4;++r) m_[mi][r] = -1e30f;

  STAGE(0, 0);
  if (nt > 1){ STAGE(1, 64); vwait<4>(); } else { vwait<0>(); }
  wgbar();
  int buf = 0;
  for (int t=0; t<nt; ++t){
    int kb = t*64;
    if (t+2 < nt){
      int nb = buf+2; if (nb>=3) nb-=3;
      STAGE(nb, kb+128);
    }
    short8 fr[4][2];
    #pragma unroll
    for (int nb=0;nb<4;++nb)
      #pragma unroll
      for (int kh=0;kh<2;++kh)
        fr[nb][kh] = *(const short8*)&Ks[buf][(nb*16+c)*64 + (((kh<<2)|g) ^ (c&7))*8];
    f32x4 z[2][4];
    #pragma unroll
    for (int mi=0;mi<2;++mi)
      #pragma unroll
      for (int nb=0;nb<4;++nb){
        f32x4 zz = {0.f,0.f,0.f,0.f};
        zz = MFMA(qf[mi][0], fr[nb][0], zz);
        zz = MFMA(qf[mi][1], fr[nb][1], zz);
        z[mi][nb] = zz;
      }
    float pv[2][4][4];
    #pragma unroll
    for (int nb=0;nb<4;++nb){
      bool msk = MASKED && (kb + nb*16 + c >= cnt);
      #pragma unroll
      for (int mi=0;mi<2;++mi)
        #pragma unroll
        for (int r=0;r<4;++r) pv[mi][nb][r] = msk ? -1e30f : z[mi][nb][r]*0.125f;
    }
    float scl[2][4];
    #pragma unroll
    for (int mi=0;mi<2;++mi){
      #pragma unroll
      for (int r=0;r<4;++r){
        float v = fmaxf(fmaxf(pv[mi][0][r],pv[mi][1][r]), fmaxf(pv[mi][2][r],pv[mi][3][r]));
        v = fmaxf(v, __shfl_xor(v,1)); v = fmaxf(v, __shfl_xor(v,2));
        v = fmaxf(v, __shfl_xor(v,4)); v = fmaxf(v, __shfl_xor(v,8));
        float nm = fmaxf(m_[mi][r], v);
        scl[mi][r] = __expf(m_[mi][r] - nm);
        m_[mi][r] = nm;
      }
      #pragma unroll
      for (int r=0;r<4;++r){
        float acc2 = 0.f;
        #pragma unroll
        for (int nb=0;nb<4;++nb){
          float e = __expf(pv[mi][nb][r] - m_[mi][r]);
          pv[mi][nb][r] = e; acc2 += e;
        }
        acc2 += __shfl_xor(acc2,1); acc2 += __shfl_xor(acc2,2);
        acc2 += __shfl_xor(acc2,4); acc2 += __shfl_xor(acc2,8);
        l_[mi][r] = l_[mi][r]*scl[mi][r] + acc2;
      }
      #pragma unroll
      for (int nbd=0;nbd<4;++nbd)
        #pragma unroll
        for (int r=0;r<4;++r) o[mi][nbd][r] *= scl[mi][r];
    }
    #pragma unroll
    for (int nbd=0;nbd<4;++nbd)
      #pragma unroll
      for (int kh=0;kh<2;++kh)
        fr[nbd][kh] = *(const short8*)&Vs[buf][(nbd*16+c)*64 + (((kh<<2)|g) ^ (c&7))*8];
    #pragma unroll
    for (int mi=0;mi<2;++mi){
      #pragma unroll
      for (int nb=0;nb<4;++nb)
        #pragma unroll
        for (int r=0;r<4;++r) P[w][g*4+r][nb*16+c] = ftou16(pv[mi][nb][r]);
      short8 pa0 = *(const short8*)&P[w][c][g*8];
      short8 pa1 = *(const short8*)&P[w][c][32 + g*8];
      #pragma unroll
      for (int nbd=0;nbd<4;++nbd){
        o[mi][nbd] = MFMA(pa0, fr[nbd][0], o[mi][nbd]);
        o[mi][nbd] = MFMA(pa1, fr[nbd][1], o[mi][nbd]);
      }
    }
    if (t < nt-2) vwait<4>(); else vwait<0>();
    wgbar();
    ++buf; if (buf==3) buf=0;
  }
  #pragma unroll
  for (int mi=0;mi<2;++mi)
    #pragma unroll
    for (int nbd=0;nbd<4;++nbd)
      #pragma unroll
      for (int r=0;r<4;++r)
        O[((size_t)(b*KCAP + q0 + mi*16 + g*4 + r))*D_ + h*DH_ + nbd*16 + c] = ftou16(o[mi][nbd][r] / l_[mi][r]);
}

// ---------------- scatter back ----------------
__global__ __launch_bounds__(256) void scatter_k(const int* __restrict__ pos, const float* __restrict__ X,
                                                 const float* __restrict__ hid, float* __restrict__ out0){
  int bs = blockIdx.x; int tid = threadIdx.x;
  int b = bs >> 12;
  int p = pos[bs];
  float* orow = out0 + (size_t)bs*D_;
  if (p >= 0){
    int pc = p < KCAP ? p : (KCAP-1);
    const float* xr = X + ((size_t)(b*KCAP + pc))*D_;
    orow[tid]     = xr[tid];
    orow[tid+256] = xr[tid+256];
    orow[tid+512] = xr[tid+512];
  } else {
    const float* hr = hid + (size_t)bs*D_;
    orow[tid]     = hr[tid];
    orow[tid+256] = hr[tid+256];
    orow[tid+512] = hr[tid+512];
  }
}

extern "C" void kernel_launch(void* const* d_in, const int* in_sizes, int n_in,
                              void* d_out, int out_size, void* d_ws, size_t ws_size,
                              hipStream_t stream){
  const float* img  = (const float*)d_in[0];
  const float* hid  = (const float*)d_in[1];
  const int*   seq  = (const int*)  d_in[2];
  const float* W[10] = { (const float*)d_in[3], (const float*)d_in[4], (const float*)d_in[5], (const float*)d_in[6],
                         (const float*)d_in[7], (const float*)d_in[8], (const float*)d_in[9], (const float*)d_in[10],
                         (const float*)d_in[11], (const float*)d_in[12] };
  const float* ln1s = (const float*)d_in[13];
  const float* ln1b = (const float*)d_in[14];
  const float* ln2s = (const float*)d_in[15];
  const float* ln2b = (const float*)d_in[16];
  const float* ln3s = (const float*)d_in[17];
  const float* ln3b = (const float*)d_in[18];

  char* ws = (char*)d_ws;
  int*   pos    = (int*)  (ws + 0);
  int*   src    = (int*)  (ws + 131072);
  int*   counts = (int*)  (ws + 151552);
  float* X      = (float*)(ws + 151808);
  u16*   T0     = (u16*)  (ws + 15880448);
  u16*   Qb     = (u16*)  (ws + 23744768);
  u16*   Kb     = (u16*)  (ws + 31609088);
  u16*   VtS    = (u16*)  (ws + 39473408);
  u16*   KbC    = (u16*)  (ws + 47337728);
  u16*   VtC    = (u16*)  (ws + 59920640);
  u16*   AO     = (u16*)  (ws + 72503552);
  u16*   Wt     = (u16*)  (ws + 80367872);
  u16*   MID    = Qb;

  u16* wqkv_st = Wt + 0ull*589824;
  u16* wo_st   = Wt + 3ull*589824;
  u16* wq_ct   = Wt + 4ull*589824;
  u16* wkv_ct  = Wt + 5ull*589824;
  u16* wo_ct   = Wt + 7ull*589824;
  u16* wff1t   = Wt + 8ull*589824;
  u16* wff2t   = wff1t + 2359296;

  float* out0 = (float*)d_out;
  float* out1 = out0 + (size_t)B_*S_*D_;
  // img bf16 scratch lives in the out1 region (12.6MB <= 15.7MB); FF2 rewrites out1 fully.
  u16* imgB = (u16*)out1;

  TransArgs ta;
  for (int i=0;i<10;++i) ta.w[i] = W[i];
  for (int i=0;i<8;++i)  ta.o[i] = Wt + (size_t)i*589824;
  ta.o[8] = wff1t; ta.o[9] = wff2t;

  // transpose (9216) + scan (8) + img convert (3072) in one launch
  transpose_scan_k<<<12296, 256, 0, stream>>>(ta, seq, pos, src, counts, img, imgB);
  gather_ln_k<<<B_*KCAP, 256, 0, stream>>>(hid, src, counts, ln1s, ln1b, X, T0);

  const int G_MEGA1 = 720 + 768;             // 1488
  const int G_N768  = (5120/64)*(768/128);   // 480
  const int G_FF1   = (5120/128)*(3072/128); // 960
  const int G_ATT   = B_*H_*5;               // 480

  // ---- self-attention block (+ independent img KV projection fused) ----
  mega1_k<<<G_MEGA1, 256, 0, stream>>>(T0, wqkv_st, Qb, Kb, VtS, imgB, wkv_ct, KbC, VtC);
  attn_k<1><<<G_ATT, 256, 0, stream>>>(Qb, Kb, VtS, AO, counts, KCAP);
  gemm_k<1,64,u16><<<G_N768, 256, 0, stream>>>(AO, wo_st, X, nullptr, nullptr, 768, 768);

  // ---- cross-attention block ----
  ln_k<<<5120, 256, 0, stream>>>(X, T0, ln2s, ln2b);
  gemm_k<0,64,u16><<<G_N768, 256, 0, stream>>>(T0, wq_ct, Qb, nullptr, nullptr, 768, 768);
  attn_k<0><<<G_ATT, 256, 0, stream>>>(Qb, KbC, VtC, AO, counts, N_);
  gemm_k<1,64,u16><<<G_N768, 256, 0, stream>>>(AO, wo_ct, X, nullptr, nullptr, 768, 768);

  // ---- FFN block (FF2 epilogue also emits out1; overwrites imgB scratch) ----
  ln_k<<<5120, 256, 0, stream>>>(X, T0, ln3s, ln3b);
  gemm_k<2,128,u16><<<G_FF1, 256, 0, stream>>>(T0, wff1t, MID, nullptr, nullptr, 3072, 768);
  gemm_k<6,64,u16><<<G_N768, 256, 0, stream>>>(MID, wff2t, X, out1, nullptr, 768, 3072);

  // ---- output 0 ----
  scatter_k<<<B_*S_, 256, 0, stream>>>(pos, X, hid, out0);
}

// Round 12
// 421.432 us; speedup vs baseline: 6.1970x; 1.0142x over previous
//
#include <hip/hip_runtime.h>
#include <hip/hip_bf16.h>

// Fetcher: SOC extraction -> [self-attn + cross-attn(img) + GELU-FFN] -> scatter-back.
// Round 11: attn 64q-blocks (grid 960, was 480 = grid-starved); FF2 writes out1 only
//           (scatter reads out1); hid-copy rows fused into gather_ln dispatch.

#define B_    8
#define S_    4096
#define D_    768
#define N_    1024
#define FF_   3072
#define H_    12
#define DH_   64
#define KCAP  640
#define SOC_TOK 3
#define EOS_TOK 2

typedef __hip_bfloat16 bf16;
typedef unsigned short u16;
typedef __attribute__((ext_vector_type(8))) short short8;
typedef __attribute__((ext_vector_type(4))) float f32x4;

__device__ __forceinline__ u16 ftou16(float x){ union{bf16 b; u16 s;} c; c.b = __float2bfloat16(x); return c.s; }
__device__ __forceinline__ unsigned pk2(float lo, float hi){ return (unsigned)ftou16(lo) | ((unsigned)ftou16(hi)<<16); }

__device__ __forceinline__ f32x4 MFMA(short8 a, short8 b, f32x4 c){
  return __builtin_amdgcn_mfma_f32_16x16x32_bf16(a, b, c, 0, 0, 0);
}

__device__ __forceinline__ void gld16(const void* gp, void* lp){
  __builtin_amdgcn_global_load_lds(
    reinterpret_cast<const __attribute__((address_space(1))) unsigned int*>((size_t)gp),
    reinterpret_cast<__attribute__((address_space(3))) unsigned int*>((size_t)lp),
    16, 0, 0);
}

template<int N> __device__ __forceinline__ void vwait(){
  asm volatile("s_waitcnt vmcnt(%0)" :: "i"(N) : "memory");
}
__device__ __forceinline__ void wgbar(){ asm volatile("s_barrier" ::: "memory"); }

__device__ __forceinline__ int xcd_swz(){
  int id = blockIdx.x;
  return (id & 7) * ((int)gridDim.x >> 3) + (id >> 3);
}

// ---------------- scan body ----------------
__device__ void scan_body(const int* __restrict__ seq, int* __restrict__ pos,
                          int* __restrict__ src, int* __restrict__ counts, int b){
  int tid = threadIdx.x;
  __shared__ int sd[256];
  __shared__ int carryE, carryS;
  if (tid==0){ carryE=0; carryS=0; }
  __syncthreads();
  for (int c=0; c<S_; c+=256){
    int s   = c + tid;
    int tok = seq[b*S_ + s];
    int isE = (tok==EOS_TOK) ? 1 : 0;
    int isS = (tok==SOC_TOK) ? 1 : 0;
    sd[tid]=isE; __syncthreads();
    for (int off=1; off<256; off<<=1){ int t_=(tid>=off)?sd[tid-off]:0; __syncthreads(); sd[tid]+=t_; __syncthreads(); }
    int eIncl = sd[tid];
    int eTot  = sd[255];
    int valid = (isS && (carryE + eIncl)==0) ? 1 : 0;
    __syncthreads();
    sd[tid]=valid; __syncthreads();
    for (int off=1; off<256; off<<=1){ int t_=(tid>=off)?sd[tid-off]:0; __syncthreads(); sd[tid]+=t_; __syncthreads(); }
    int vIncl = sd[tid];
    int vTot  = sd[255];
    if (valid){
      int slot = carryS + vIncl - 1;
      pos[b*S_ + s] = slot;
      if (slot < KCAP) src[b*KCAP + slot] = s;
    } else {
      pos[b*S_ + s] = -1;
    }
    __syncthreads();
    if (tid==0){ carryE += eTot; carryS += vTot; }
    __syncthreads();
  }
  if (tid==0) counts[b] = (carryS < KCAP) ? carryS : KCAP;
}

// ---------------- transpose + scan + img->bf16 convert, one launch ----------------
struct TransArgs { const float* w[10]; u16* o[10]; };
__global__ __launch_bounds__(256) void transpose_scan_k(TransArgs a, const int* __restrict__ seq,
                                                        int* __restrict__ pos, int* __restrict__ src,
                                                        int* __restrict__ counts,
                                                        const float* __restrict__ img, u16* __restrict__ imgB){
  int id = blockIdx.x;
  if (id >= 9224){
    int base = (id - 9224)*2048 + threadIdx.x*8;
    float4 a0 = *(const float4*)(img + base);
    float4 a1 = *(const float4*)(img + base + 4);
    uint4 wv;
    wv.x = pk2(a0.x,a0.y); wv.y = pk2(a0.z,a0.w); wv.z = pk2(a1.x,a1.y); wv.w = pk2(a1.z,a1.w);
    *(uint4*)(imgB + base) = wv;
    return;
  }
  if (id >= 9216){ scan_body(seq, pos, src, counts, id - 9216); return; }
  __shared__ float tile[32][33];
  int wi, t, K, N;
  if (id < 4608){ wi = id/576; t = id%576; K = 768; N = 768; }
  else if (id < 6912){ wi = 8; t = id-4608; K = 768; N = 3072; }
  else { wi = 9; t = id-6912; K = 3072; N = 768; }
  const float* in = a.w[wi]; u16* out = a.o[wi];
  int nbx = N >> 5;
  int bx = t % nbx, by = t / nbx;
  int tx = threadIdx.x & 31, ty = threadIdx.x >> 5;
  #pragma unroll
  for (int i=0;i<4;++i)
    tile[ty + i*8][tx] = in[(size_t)(by*32 + ty + i*8)*N + bx*32 + tx];
  __syncthreads();
  #pragma unroll
  for (int i=0;i<4;++i)
    out[(size_t)(bx*32 + ty + i*8)*K + by*32 + tx] = ftou16(tile[tx][ty + i*8]);
}

// ---------------- prep: gather+LN1 (blocks 0..5119) + hid-copy of non-SOC rows ----------------
__global__ __launch_bounds__(256) void prep_k(const float* __restrict__ hid,
                                              const int* __restrict__ src,
                                              const int* __restrict__ counts,
                                              const int* __restrict__ pos,
                                              const float* __restrict__ g, const float* __restrict__ bt,
                                              float* __restrict__ X, u16* __restrict__ T0,
                                              float* __restrict__ out0){
  int id = blockIdx.x; int tid = threadIdx.x;
  if (id >= 5120){
    // hid-copy: rows where pos<0 (non-SOC). 4 rows per block.
    int base = (id - 5120)*4;
    #pragma unroll
    for (int r2=0;r2<4;++r2){
      int bs = base + r2;
      if (pos[bs] >= 0) continue;
      const float* hr = hid + (size_t)bs*D_;
      float* orow = out0 + (size_t)bs*D_;
      orow[tid]     = hr[tid];
      orow[tid+256] = hr[tid+256];
      orow[tid+512] = hr[tid+512];
    }
    return;
  }
  int bk = id; int b = bk / KCAP; int k = bk % KCAP;
  float v0, v1, v2;
  if (k < counts[b]){
    const float* hr = hid + ((size_t)b*S_ + src[b*KCAP + k])*D_;
    v0 = hr[tid]; v1 = hr[tid+256]; v2 = hr[tid+512];
  } else { v0 = v1 = v2 = 0.f; }
  float* xr = X + (size_t)bk*D_;
  xr[tid] = v0; xr[tid+256] = v1; xr[tid+512] = v2;
  float s1=v0+v1+v2, s2=v0*v0+v1*v1+v2*v2;
  for (int off=32; off; off>>=1){ s1+=__shfl_xor(s1,off); s2+=__shfl_xor(s2,off); }
  __shared__ float red[8];
  __shared__ float mu_s, rs_s;
  int w=tid>>6, ln=tid&63;
  if (ln==0){ red[w]=s1; red[4+w]=s2; }
  __syncthreads();
  if (tid==0){
    float S1=red[0]+red[1]+red[2]+red[3];
    float S2=red[4]+red[5]+red[6]+red[7];
    float mu = S1*(1.f/D_);
    float var= S2*(1.f/D_) - mu*mu;
    mu_s=mu; rs_s=rsqrtf(var + 1e-5f);
  }
  __syncthreads();
  float mu=mu_s, rs=rs_s;
  u16* yr = T0 + (size_t)bk*D_;
  yr[tid]     = ftou16((v0-mu)*rs*g[tid]     + bt[tid]);
  yr[tid+256] = ftou16((v1-mu)*rs*g[tid+256] + bt[tid+256]);
  yr[tid+512] = ftou16((v2-mu)*rs*g[tid+512] + bt[tid+512]);
}

// ---------------- layernorm ----------------
__global__ __launch_bounds__(256) void ln_k(const float* __restrict__ X, u16* __restrict__ Y,
                                            const float* __restrict__ g, const float* __restrict__ bt){
  int r = blockIdx.x; int tid = threadIdx.x;
  const float* xr = X + (size_t)r*D_;
  float v0=xr[tid], v1=xr[tid+256], v2=xr[tid+512];
  float s1=v0+v1+v2, s2=v0*v0+v1*v1+v2*v2;
  for (int off=32; off; off>>=1){ s1+=__shfl_xor(s1,off); s2+=__shfl_xor(s2,off); }
  __shared__ float red[8];
  __shared__ float mu_s, rs_s;
  int w=tid>>6, ln=tid&63;
  if (ln==0){ red[w]=s1; red[4+w]=s2; }
  __syncthreads();
  if (tid==0){
    float S1=red[0]+red[1]+red[2]+red[3];
    float S2=red[4]+red[5]+red[6]+red[7];
    float mu = S1*(1.f/D_);
    float var= S2*(1.f/D_) - mu*mu;
    mu_s=mu; rs_s=rsqrtf(var + 1e-5f);
  }
  __syncthreads();
  float mu=mu_s, rs=rs_s;
  u16* yr = Y + (size_t)r*D_;
  yr[tid]     = ftou16((v0-mu)*rs*g[tid]     + bt[tid]);
  yr[tid+256] = ftou16((v1-mu)*rs*g[tid+256] + bt[tid+256]);
  yr[tid+512] = ftou16((v2-mu)*rs*g[tid+512] + bt[tid+512]);
}

// ---------------- MFMA GEMM body ----------------
// MODE 0: C0_bf16 ; 1: C0_f32 += ; 2: C0_bf16 = gelu ; 6: C1_f32 = C0_f32 + result (C0 read-only)
// MODE 4: self QKV (N=2304): Q->C0, K->C1, V^T->C2 [b][768][KCAP]  (V writes ushort4-packed)
// MODE 5: cross KV (N=1536): K->C0, V^T->C2 [b][768][1024]         (V writes ushort4-packed)
template<int MODE, int BM, typename TA>
__device__ __forceinline__ void gemm_body(char* ldsp, const TA* __restrict__ A, const u16* __restrict__ Bt,
                                          void* __restrict__ C0, void* __restrict__ C1, void* __restrict__ C2,
                                          int wgid, int N, int K){
  constexpr int MI   = BM/32;
  constexpr int NBUF = (BM==128) ? 2 : ((sizeof(TA)==4) ? 2 : 3);
  u16* As = (u16*)ldsp;
  u16* Bs = (u16*)(ldsp + NBUF*(BM*32)*2);
  int nbx = N >> 7;
  int bx = wgid % nbx, by = wgid / nbx;
  int tid = threadIdx.x;
  int w = tid>>6, l = tid&63, g = l>>4, c = l&15;
  int wr = w&1, wc = w>>1;
  f32x4 acc[MI][4] = {};
  float4 rg[4];
  const int NK = K/32;

  auto STAGEB = [&](int buf, int kt){
    #pragma unroll
    for (int p=0;p<2;++p){
      int row = w*32 + p*16 + (l>>2);
      int su  = (l&3) ^ ((row>>1)&3);
      gld16((const void*)(Bt + (size_t)(bx*128+row)*K + kt + su*8), (void*)&Bs[buf*128*32 + (w*32+p*16)*32]);
    }
  };
  auto STAGEA16 = [&](int buf, int kt){
    if constexpr (BM==128){
      #pragma unroll
      for (int p=0;p<2;++p){
        int row = w*32 + p*16 + (l>>2);
        int su  = (l&3) ^ ((row>>1)&3);
        gld16((const void*)((const u16*)A + (size_t)(by*BM+row)*K + kt + su*8), (void*)&As[buf*BM*32 + (w*32+p*16)*32]);
      }
    } else {
      int row = w*16 + (l>>2);
      int su  = (l&3) ^ ((row>>1)&3);
      gld16((const void*)((const u16*)A + (size_t)(by*BM+row)*K + kt + su*8), (void*)&As[buf*BM*32 + (w*16)*32]);
    }
  };
  auto LOADREG = [&](int kt){
    if constexpr (BM==128){
      const float* ap = (const float*)A + (size_t)(by*BM + (tid>>1))*K + kt + (tid&1)*16;
      rg[0]=*(const float4*)ap;     rg[1]=*(const float4*)(ap+4);
      rg[2]=*(const float4*)(ap+8); rg[3]=*(const float4*)(ap+12);
    } else {
      const float* ap = (const float*)A + (size_t)(by*BM + (tid>>2))*K + kt + (tid&3)*8;
      rg[0] = *(const float4*)ap; rg[1] = *(const float4*)(ap+4);
    }
  };
  auto WRITEA = [&](int buf){
    if constexpr (BM==128){
      int row = tid>>1, half = tid&1;
      uint4 w0,w1;
      w0.x=pk2(rg[0].x,rg[0].y); w0.y=pk2(rg[0].z,rg[0].w); w0.z=pk2(rg[1].x,rg[1].y); w0.w=pk2(rg[1].z,rg[1].w);
      w1.x=pk2(rg[2].x,rg[2].y); w1.y=pk2(rg[2].z,rg[2].w); w1.z=pk2(rg[3].x,rg[3].y); w1.w=pk2(rg[3].z,rg[3].w);
      int sw = (row>>1)&3;
      *(uint4*)&As[buf*BM*32 + row*32 + ((half*2  )^sw)*8] = w0;
      *(uint4*)&As[buf*BM*32 + row*32 + ((half*2+1)^sw)*8] = w1;
    } else {
      int row = tid>>2, unit = tid&3;
      uint4 wv;
      wv.x=pk2(rg[0].x,rg[0].y); wv.y=pk2(rg[0].z,rg[0].w); wv.z=pk2(rg[1].x,rg[1].y); wv.w=pk2(rg[1].z,rg[1].w);
      int sw = (row>>1)&3;
      *(uint4*)&As[buf*BM*32 + row*32 + (unit^sw)*8] = wv;
    }
  };
  auto COMPUTE = [&](int buf){
    short8 af[MI], bfr[4];
    #pragma unroll
    for (int mi=0;mi<MI;++mi){ int row = wr*(MI*16) + mi*16 + c; af[mi]  = *(const short8*)&As[buf*BM*32 + row*32 + (g^((row>>1)&3))*8]; }
    #pragma unroll
    for (int ni=0;ni<4;++ni){ int row = wc*64 + ni*16 + c;       bfr[ni] = *(const short8*)&Bs[buf*128*32 + row*32 + (g^((row>>1)&3))*8]; }
    #pragma unroll
    for (int mi=0;mi<MI;++mi)
      #pragma unroll
      for (int ni=0;ni<4;++ni) acc[mi][ni] = MFMA(af[mi], bfr[ni], acc[mi][ni]);
  };

  if constexpr (BM==128 || sizeof(TA)==4){
    if constexpr (sizeof(TA)==4){ LOADREG(0); STAGEB(0,0); WRITEA(0); }
    else { STAGEA16(0,0); STAGEB(0,0); }
    __syncthreads();
    int buf = 0;
    for (int t=0;t<NK;++t){
      int ktn = (t+1)*32;
      if constexpr (sizeof(TA)==4){
        if (t+1<NK){ LOADREG(ktn); STAGEB(buf^1, ktn); }
        COMPUTE(buf);
        if (t+1<NK) WRITEA(buf^1);
      } else {
        if (t+1<NK){ STAGEA16(buf^1, ktn); STAGEB(buf^1, ktn); }
        COMPUTE(buf);
      }
      __syncthreads();
      buf ^= 1;
    }
  } else {
    constexpr int LPS = 3;
    STAGEA16(0,0);  STAGEB(0,0);
    STAGEA16(1,32); STAGEB(1,32);
    vwait<LPS>();
    wgbar();
    int buf = 0;
    for (int t=0;t<NK;++t){
      if (t+2 < NK){
        int nb = buf+2; if (nb>=3) nb-=3;
        STAGEA16(nb,(t+2)*32); STAGEB(nb,(t+2)*32);
      }
      COMPUTE(buf);
      if (t < NK-2) vwait<LPS>(); else vwait<0>();
      wgbar();
      ++buf; if (buf==3) buf=0;
    }
  }

  int row0 = by*BM + wr*(MI*16), col0 = bx*128 + wc*64;
  #pragma unroll
  for (int mi=0;mi<MI;++mi)
    #pragma unroll
    for (int ni=0;ni<4;++ni){
      int rowb = row0 + mi*16 + g*4;
      int col  = col0 + ni*16 + c;
      if (MODE==4 && col >= 1536){
        int vv = col - 1536; int bb = rowb / KCAP; int key = rowb - bb*KCAP;
        ushort4 pk;
        pk.x = ftou16(acc[mi][ni][0]); pk.y = ftou16(acc[mi][ni][1]);
        pk.z = ftou16(acc[mi][ni][2]); pk.w = ftou16(acc[mi][ni][3]);
        *(ushort4*)&((u16*)C2)[((size_t)(bb*768 + vv))*KCAP + key] = pk;
      } else if (MODE==5 && col >= 768){
        int vv = col - 768; int bb = rowb >> 10; int key = rowb & 1023;
        ushort4 pk;
        pk.x = ftou16(acc[mi][ni][0]); pk.y = ftou16(acc[mi][ni][1]);
        pk.z = ftou16(acc[mi][ni][2]); pk.w = ftou16(acc[mi][ni][3]);
        *(ushort4*)&((u16*)C2)[((size_t)(bb*768 + vv))*1024 + key] = pk;
      } else {
        #pragma unroll
        for (int r=0;r<4;++r){
          int row = rowb + r;
          float v = acc[mi][ni][r];
          if (MODE==0){
            ((u16*)C0)[(size_t)row*N + col] = ftou16(v);
          } else if (MODE==1){
            ((float*)C0)[(size_t)row*N + col] += v;
          } else if (MODE==2){
            float z2 = 1.5957691216057308f*(v + 0.044715f*v*v*v);
            float e  = __expf(z2);
            float th = 1.f - 2.f/(e + 1.f);
            ((u16*)C0)[(size_t)row*N + col] = ftou16(0.5f*v*(1.f+th));
          } else if (MODE==6){
            size_t idx = (size_t)row*N + col;
            ((float*)C1)[idx] = ((const float*)C0)[idx] + v;
          } else if (MODE==4){
            if (col < 768)  ((u16*)C0)[(size_t)row*768 + col]       = ftou16(v);
            else            ((u16*)C1)[(size_t)row*768 + col - 768] = ftou16(v);
          } else { // MODE 5, col < 768
            ((u16*)C0)[(size_t)row*768 + col] = ftou16(v);
          }
        }
      }
    }
}

template<int MODE, int BM, typename TA>
__global__ __launch_bounds__(256) void gemm_k(const TA* __restrict__ A, const u16* __restrict__ Bt,
                                              void* __restrict__ C0, void* __restrict__ C1, void* __restrict__ C2,
                                              int N, int K){
  constexpr int NBUF = (BM==128) ? 2 : ((sizeof(TA)==4) ? 2 : 3);
  __shared__ __align__(16) char pool[NBUF*(BM+128)*32*2];
  gemm_body<MODE,BM,TA>(pool, A, Bt, C0, C1, C2, xcd_swz(), N, K);
}

// mega1: self QKV (720 blocks) + cross img KV (768 blocks), both BM=128 bf16-A, one dispatch
__global__ __launch_bounds__(256) void mega1_k(const u16* __restrict__ T0, const u16* __restrict__ wqkv_st,
                                               u16* __restrict__ Qb, u16* __restrict__ Kb, u16* __restrict__ VtS,
                                               const u16* __restrict__ imgB, const u16* __restrict__ wkv_ct,
                                               u16* __restrict__ KbC, u16* __restrict__ VtC){
  __shared__ __align__(16) char pool[2*(128+128)*32*2];
  int wgid = xcd_swz();   // grid = 1488
  if (wgid < 720) gemm_body<4,128,u16>(pool, T0,   wqkv_st, Qb,  Kb,      VtS, wgid,     2304, 768);
  else            gemm_body<5,128,u16>(pool, imgB, wkv_ct,  KbC, nullptr, VtC, wgid-720, 1536, 768);
}

// ---------------- MFMA flash attention: 64 q / block (4 waves x 16 q), 3-buf counted-vmcnt ----------------
template<int MASKED>
__global__ __launch_bounds__(256) void attn_k(const u16* __restrict__ Q, const u16* __restrict__ Kb,
                                              const u16* __restrict__ Vt, u16* __restrict__ O,
                                              const int* __restrict__ counts, int Lk){
  __shared__ __align__(16) u16 Ks[3][64*64];
  __shared__ __align__(16) u16 Vs[3][64*64];
  __shared__ __align__(16) u16 P[4][16][72];
  int tid = threadIdx.x;
  int w = tid>>6, l = tid&63, g = l>>4, c = l&15;
  int wgid = xcd_swz();
  int qc = wgid % 10;           // KCAP/64 chunks
  int bh = wgid / 10;
  int h = bh % H_, b = bh / H_;
  int q0 = qc*64 + w*16;
  int cnt = MASKED ? counts[b] : Lk;
  int nt = (cnt + 63) >> 6;

  const u16* Qrow = Q + ((size_t)(b*KCAP + q0 + c))*D_ + h*DH_;
  short8 qf0 = *(const short8*)(Qrow + g*8);
  short8 qf1 = *(const short8*)(Qrow + 32 + g*8);

  int srow8 = (l>>3);
  int sunit = l&7;
  auto STAGE = [&](int buf, int kb){
    #pragma unroll
    for (int p=0;p<2;++p){
      int r0 = w*16 + p*8;
      int rowK = r0 + srow8;
      int su = sunit ^ (rowK&7);
      gld16((const void*)(Kb + ((size_t)(b*Lk + kb + rowK))*D_ + h*DH_ + su*8), (void*)&Ks[buf][r0*64]);
      gld16((const void*)(Vt + ((size_t)(b*D_ + h*DH_ + rowK))*Lk + kb + su*8), (void*)&Vs[buf][r0*64]);
    }
  };

  f32x4 o[4] = {};
  float m_[4], l_[4] = {};
  #pragma unroll
  for (int r=0;r<4;++r) m_[r] = -1e30f;

  STAGE(0, 0);
  if (nt > 1){ STAGE(1, 64); vwait<4>(); } else { vwait<0>(); }
  wgbar();
  int buf = 0;
  for (int t=0; t<nt; ++t){
    int kb = t*64;
    if (t+2 < nt){
      int nb = buf+2; if (nb>=3) nb-=3;
      STAGE(nb, kb+128);
    }
    short8 fr[4][2];
    #pragma unroll
    for (int nb=0;nb<4;++nb)
      #pragma unroll
      for (int kh=0;kh<2;++kh)
        fr[nb][kh] = *(const short8*)&Ks[buf][(nb*16+c)*64 + (((kh<<2)|g) ^ (c&7))*8];
    float pv[4][4];
    #pragma unroll
    for (int nb=0;nb<4;++nb){
      f32x4 zz = {0.f,0.f,0.f,0.f};
      zz = MFMA(qf0, fr[nb][0], zz);
      zz = MFMA(qf1, fr[nb][1], zz);
      bool msk = MASKED && (kb + nb*16 + c >= cnt);
      #pragma unroll
      for (int r=0;r<4;++r) pv[nb][r] = msk ? -1e30f : zz[r]*0.125f;
    }
    float scl[4];
    #pragma unroll
    for (int r=0;r<4;++r){
      float v = fmaxf(fmaxf(pv[0][r],pv[1][r]), fmaxf(pv[2][r],pv[3][r]));
      v = fmaxf(v, __shfl_xor(v,1)); v = fmaxf(v, __shfl_xor(v,2));
      v = fmaxf(v, __shfl_xor(v,4)); v = fmaxf(v, __shfl_xor(v,8));
      float nm = fmaxf(m_[r], v);
      scl[r] = __expf(m_[r] - nm);
      m_[r] = nm;
    }
    #pragma unroll
    for (int r=0;r<4;++r){
      float acc2 = 0.f;
      #pragma unroll
      for (int nb=0;nb<4;++nb){
        float e = __expf(pv[nb][r] - m_[r]);
        pv[nb][r] = e; acc2 += e;
      }
      acc2 += __shfl_xor(acc2,1); acc2 += __shfl_xor(acc2,2);
      acc2 += __shfl_xor(acc2,4); acc2 += __shfl_xor(acc2,8);
      l_[r] = l_[r]*scl[r] + acc2;
    }
    #pragma unroll
    for (int nbd=0;nbd<4;++nbd)
      #pragma unroll
      for (int r=0;r<4;++r) o[nbd][r] *= scl[r];
    // V fragments
    short8 fv[4][2];
    #pragma unroll
    for (int nbd=0;nbd<4;++nbd)
      #pragma unroll
      for (int kh=0;kh<2;++kh)
        fv[nbd][kh] = *(const short8*)&Vs[buf][(nbd*16+c)*64 + (((kh<<2)|g) ^ (c&7))*8];
    // P repack
    #pragma unroll
    for (int nb=0;nb<4;++nb)
      #pragma unroll
      for (int r=0;r<4;++r) P[w][g*4+r][nb*16+c] = ftou16(pv[nb][r]);
    short8 pa0 = *(const short8*)&P[w][c][g*8];
    short8 pa1 = *(const short8*)&P[w][c][32 + g*8];
    #pragma unroll
    for (int nbd=0;nbd<4;++nbd){
      o[nbd] = MFMA(pa0, fv[nbd][0], o[nbd]);
      o[nbd] = MFMA(pa1, fv[nbd][1], o[nbd]);
    }
    if (t < nt-2) vwait<4>(); else vwait<0>();
    wgbar();
    ++buf; if (buf==3) buf=0;
  }
  #pragma unroll
  for (int nbd=0;nbd<4;++nbd)
    #pragma unroll
    for (int r=0;r<4;++r)
      O[((size_t)(b*KCAP + q0 + g*4 + r))*D_ + h*DH_ + nbd*16 + c] = ftou16(o[nbd][r] / l_[r]);
}

// ---------------- final scatter: SOC rows only, from out1 (= x final, f32) ----------------
__global__ __launch_bounds__(256) void scatter_soc_k(const int* __restrict__ pos,
                                                     const float* __restrict__ out1,
                                                     float* __restrict__ out0){
  int base = blockIdx.x*4; int tid = threadIdx.x;
  #pragma unroll
  for (int r2=0;r2<4;++r2){
    int bs = base + r2;
    int p = pos[bs];
    if (p < 0) continue;
    int pc = p < KCAP ? p : (KCAP-1);
    int b = bs >> 12;
    const float* xr = out1 + ((size_t)(b*KCAP + pc))*D_;
    float* orow = out0 + (size_t)bs*D_;
    orow[tid]     = xr[tid];
    orow[tid+256] = xr[tid+256];
    orow[tid+512] = xr[tid+512];
  }
}

extern "C" void kernel_launch(void* const* d_in, const int* in_sizes, int n_in,
                              void* d_out, int out_size, void* d_ws, size_t ws_size,
                              hipStream_t stream){
  const float* img  = (const float*)d_in[0];
  const float* hid  = (const float*)d_in[1];
  const int*   seq  = (const int*)  d_in[2];
  const float* W[10] = { (const float*)d_in[3], (const float*)d_in[4], (const float*)d_in[5], (const float*)d_in[6],
                         (const float*)d_in[7], (const float*)d_in[8], (const float*)d_in[9], (const float*)d_in[10],
                         (const float*)d_in[11], (const float*)d_in[12] };
  const float* ln1s = (const float*)d_in[13];
  const float* ln1b = (const float*)d_in[14];
  const float* ln2s = (const float*)d_in[15];
  const float* ln2b = (const float*)d_in[16];
  const float* ln3s = (const float*)d_in[17];
  const float* ln3b = (const float*)d_in[18];

  char* ws = (char*)d_ws;
  int*   pos    = (int*)  (ws + 0);
  int*   src    = (int*)  (ws + 131072);
  int*   counts = (int*)  (ws + 151552);
  float* X      = (float*)(ws + 151808);
  u16*   T0     = (u16*)  (ws + 15880448);
  u16*   Qb     = (u16*)  (ws + 23744768);
  u16*   Kb     = (u16*)  (ws + 31609088);
  u16*   VtS    = (u16*)  (ws + 39473408);
  u16*   KbC    = (u16*)  (ws + 47337728);
  u16*   VtC    = (u16*)  (ws + 59920640);
  u16*   AO     = (u16*)  (ws + 72503552);
  u16*   Wt     = (u16*)  (ws + 80367872);
  u16*   MID    = Qb;

  u16* wqkv_st = Wt + 0ull*589824;
  u16* wo_st   = Wt + 3ull*589824;
  u16* wq_ct   = Wt + 4ull*589824;
  u16* wkv_ct  = Wt + 5ull*589824;
  u16* wo_ct   = Wt + 7ull*589824;
  u16* wff1t   = Wt + 8ull*589824;
  u16* wff2t   = wff1t + 2359296;

  float* out0 = (float*)d_out;
  float* out1 = out0 + (size_t)B_*S_*D_;
  // img bf16 scratch lives in the out1 region (12.6MB <= 15.7MB); FF2 rewrites out1 fully.
  u16* imgB = (u16*)out1;

  TransArgs ta;
  for (int i=0;i<10;++i) ta.w[i] = W[i];
  for (int i=0;i<8;++i)  ta.o[i] = Wt + (size_t)i*589824;
  ta.o[8] = wff1t; ta.o[9] = wff2t;

  // transpose (9216) + scan (8) + img convert (3072)
  transpose_scan_k<<<12296, 256, 0, stream>>>(ta, seq, pos, src, counts, img, imgB);
  // gather+LN1 (5120) + hid-copy of non-SOC rows (8192)
  prep_k<<<13312, 256, 0, stream>>>(hid, src, counts, pos, ln1s, ln1b, X, T0, out0);

  const int G_MEGA1 = 720 + 768;             // 1488
  const int G_N768  = (5120/64)*(768/128);   // 480
  const int G_FF1   = (5120/128)*(3072/128); // 960
  const int G_ATT   = B_*H_*10;              // 960

  // ---- self-attention block (+ independent img KV projection fused) ----
  mega1_k<<<G_MEGA1, 256, 0, stream>>>(T0, wqkv_st, Qb, Kb, VtS, imgB, wkv_ct, KbC, VtC);
  attn_k<1><<<G_ATT, 256, 0, stream>>>(Qb, Kb, VtS, AO, counts, KCAP);
  gemm_k<1,64,u16><<<G_N768, 256, 0, stream>>>(AO, wo_st, X, nullptr, nullptr, 768, 768);

  // ---- cross-attention block ----
  ln_k<<<5120, 256, 0, stream>>>(X, T0, ln2s, ln2b);
  gemm_k<0,64,u16><<<G_N768, 256, 0, stream>>>(T0, wq_ct, Qb, nullptr, nullptr, 768, 768);
  attn_k<0><<<G_ATT, 256, 0, stream>>>(Qb, KbC, VtC, AO, counts, N_);
  gemm_k<1,64,u16><<<G_N768, 256, 0, stream>>>(AO, wo_ct, X, nullptr, nullptr, 768, 768);

  // ---- FFN block (FF2 writes out1 = X + ff2; X itself stays pre-FF2) ----
  ln_k<<<5120, 256, 0, stream>>>(X, T0, ln3s, ln3b);
  gemm_k<2,128,u16><<<G_FF1, 256, 0, stream>>>(T0, wff1t, MID, nullptr, nullptr, 3072, 768);
  gemm_k<6,64,u16><<<G_N768, 256, 0, stream>>>(MID, wff2t, X, out1, nullptr, 768, 3072);

  // ---- final: SOC rows of out0 from out1 ----
  scatter_soc_k<<<8192, 256, 0, stream>>>(pos, out1, out0);
}

// Round 13
// 413.327 us; speedup vs baseline: 6.3185x; 1.0196x over previous
//
#include <hip/hip_runtime.h>
#include <hip/hip_bf16.h>

// Fetcher: SOC extraction -> [self-attn + cross-attn(img) + GELU-FFN] -> scatter-back.
// Round 13: revert attn to 128q/block (2 m-tiles/wave, grid 480) — the 64q split halved
//           MFMA-per-staged-byte and regressed (72.7us vs ~48us). Keep all round-12 wins.

#define B_    8
#define S_    4096
#define D_    768
#define N_    1024
#define FF_   3072
#define H_    12
#define DH_   64
#define KCAP  640
#define SOC_TOK 3
#define EOS_TOK 2

typedef __hip_bfloat16 bf16;
typedef unsigned short u16;
typedef __attribute__((ext_vector_type(8))) short short8;
typedef __attribute__((ext_vector_type(4))) float f32x4;

__device__ __forceinline__ u16 ftou16(float x){ union{bf16 b; u16 s;} c; c.b = __float2bfloat16(x); return c.s; }
__device__ __forceinline__ unsigned pk2(float lo, float hi){ return (unsigned)ftou16(lo) | ((unsigned)ftou16(hi)<<16); }

__device__ __forceinline__ f32x4 MFMA(short8 a, short8 b, f32x4 c){
  return __builtin_amdgcn_mfma_f32_16x16x32_bf16(a, b, c, 0, 0, 0);
}

__device__ __forceinline__ void gld16(const void* gp, void* lp){
  __builtin_amdgcn_global_load_lds(
    reinterpret_cast<const __attribute__((address_space(1))) unsigned int*>((size_t)gp),
    reinterpret_cast<__attribute__((address_space(3))) unsigned int*>((size_t)lp),
    16, 0, 0);
}

template<int N> __device__ __forceinline__ void vwait(){
  asm volatile("s_waitcnt vmcnt(%0)" :: "i"(N) : "memory");
}
__device__ __forceinline__ void wgbar(){ asm volatile("s_barrier" ::: "memory"); }

__device__ __forceinline__ int xcd_swz(){
  int id = blockIdx.x;
  return (id & 7) * ((int)gridDim.x >> 3) + (id >> 3);
}

// ---------------- scan body ----------------
__device__ void scan_body(const int* __restrict__ seq, int* __restrict__ pos,
                          int* __restrict__ src, int* __restrict__ counts, int b){
  int tid = threadIdx.x;
  __shared__ int sd[256];
  __shared__ int carryE, carryS;
  if (tid==0){ carryE=0; carryS=0; }
  __syncthreads();
  for (int c=0; c<S_; c+=256){
    int s   = c + tid;
    int tok = seq[b*S_ + s];
    int isE = (tok==EOS_TOK) ? 1 : 0;
    int isS = (tok==SOC_TOK) ? 1 : 0;
    sd[tid]=isE; __syncthreads();
    for (int off=1; off<256; off<<=1){ int t_=(tid>=off)?sd[tid-off]:0; __syncthreads(); sd[tid]+=t_; __syncthreads(); }
    int eIncl = sd[tid];
    int eTot  = sd[255];
    int valid = (isS && (carryE + eIncl)==0) ? 1 : 0;
    __syncthreads();
    sd[tid]=valid; __syncthreads();
    for (int off=1; off<256; off<<=1){ int t_=(tid>=off)?sd[tid-off]:0; __syncthreads(); sd[tid]+=t_; __syncthreads(); }
    int vIncl = sd[tid];
    int vTot  = sd[255];
    if (valid){
      int slot = carryS + vIncl - 1;
      pos[b*S_ + s] = slot;
      if (slot < KCAP) src[b*KCAP + slot] = s;
    } else {
      pos[b*S_ + s] = -1;
    }
    __syncthreads();
    if (tid==0){ carryE += eTot; carryS += vTot; }
    __syncthreads();
  }
  if (tid==0) counts[b] = (carryS < KCAP) ? carryS : KCAP;
}

// ---------------- transpose + scan + img->bf16 convert, one launch ----------------
struct TransArgs { const float* w[10]; u16* o[10]; };
__global__ __launch_bounds__(256) void transpose_scan_k(TransArgs a, const int* __restrict__ seq,
                                                        int* __restrict__ pos, int* __restrict__ src,
                                                        int* __restrict__ counts,
                                                        const float* __restrict__ img, u16* __restrict__ imgB){
  int id = blockIdx.x;
  if (id >= 9224){
    int base = (id - 9224)*2048 + threadIdx.x*8;
    float4 a0 = *(const float4*)(img + base);
    float4 a1 = *(const float4*)(img + base + 4);
    uint4 wv;
    wv.x = pk2(a0.x,a0.y); wv.y = pk2(a0.z,a0.w); wv.z = pk2(a1.x,a1.y); wv.w = pk2(a1.z,a1.w);
    *(uint4*)(imgB + base) = wv;
    return;
  }
  if (id >= 9216){ scan_body(seq, pos, src, counts, id - 9216); return; }
  __shared__ float tile[32][33];
  int wi, t, K, N;
  if (id < 4608){ wi = id/576; t = id%576; K = 768; N = 768; }
  else if (id < 6912){ wi = 8; t = id-4608; K = 768; N = 3072; }
  else { wi = 9; t = id-6912; K = 3072; N = 768; }
  const float* in = a.w[wi]; u16* out = a.o[wi];
  int nbx = N >> 5;
  int bx = t % nbx, by = t / nbx;
  int tx = threadIdx.x & 31, ty = threadIdx.x >> 5;
  #pragma unroll
  for (int i=0;i<4;++i)
    tile[ty + i*8][tx] = in[(size_t)(by*32 + ty + i*8)*N + bx*32 + tx];
  __syncthreads();
  #pragma unroll
  for (int i=0;i<4;++i)
    out[(size_t)(bx*32 + ty + i*8)*K + by*32 + tx] = ftou16(tile[tx][ty + i*8]);
}

// ---------------- prep: gather+LN1 (blocks 0..5119) + hid-copy of non-SOC rows ----------------
__global__ __launch_bounds__(256) void prep_k(const float* __restrict__ hid,
                                              const int* __restrict__ src,
                                              const int* __restrict__ counts,
                                              const int* __restrict__ pos,
                                              const float* __restrict__ g, const float* __restrict__ bt,
                                              float* __restrict__ X, u16* __restrict__ T0,
                                              float* __restrict__ out0){
  int id = blockIdx.x; int tid = threadIdx.x;
  if (id >= 5120){
    int base = (id - 5120)*4;
    #pragma unroll
    for (int r2=0;r2<4;++r2){
      int bs = base + r2;
      if (pos[bs] >= 0) continue;
      const float* hr = hid + (size_t)bs*D_;
      float* orow = out0 + (size_t)bs*D_;
      orow[tid]     = hr[tid];
      orow[tid+256] = hr[tid+256];
      orow[tid+512] = hr[tid+512];
    }
    return;
  }
  int bk = id; int b = bk / KCAP; int k = bk % KCAP;
  float v0, v1, v2;
  if (k < counts[b]){
    const float* hr = hid + ((size_t)b*S_ + src[b*KCAP + k])*D_;
    v0 = hr[tid]; v1 = hr[tid+256]; v2 = hr[tid+512];
  } else { v0 = v1 = v2 = 0.f; }
  float* xr = X + (size_t)bk*D_;
  xr[tid] = v0; xr[tid+256] = v1; xr[tid+512] = v2;
  float s1=v0+v1+v2, s2=v0*v0+v1*v1+v2*v2;
  for (int off=32; off; off>>=1){ s1+=__shfl_xor(s1,off); s2+=__shfl_xor(s2,off); }
  __shared__ float red[8];
  __shared__ float mu_s, rs_s;
  int w=tid>>6, ln=tid&63;
  if (ln==0){ red[w]=s1; red[4+w]=s2; }
  __syncthreads();
  if (tid==0){
    float S1=red[0]+red[1]+red[2]+red[3];
    float S2=red[4]+red[5]+red[6]+red[7];
    float mu = S1*(1.f/D_);
    float var= S2*(1.f/D_) - mu*mu;
    mu_s=mu; rs_s=rsqrtf(var + 1e-5f);
  }
  __syncthreads();
  float mu=mu_s, rs=rs_s;
  u16* yr = T0 + (size_t)bk*D_;
  yr[tid]     = ftou16((v0-mu)*rs*g[tid]     + bt[tid]);
  yr[tid+256] = ftou16((v1-mu)*rs*g[tid+256] + bt[tid+256]);
  yr[tid+512] = ftou16((v2-mu)*rs*g[tid+512] + bt[tid+512]);
}

// ---------------- layernorm ----------------
__global__ __launch_bounds__(256) void ln_k(const float* __restrict__ X, u16* __restrict__ Y,
                                            const float* __restrict__ g, const float* __restrict__ bt){
  int r = blockIdx.x; int tid = threadIdx.x;
  const float* xr = X + (size_t)r*D_;
  float v0=xr[tid], v1=xr[tid+256], v2=xr[tid+512];
  float s1=v0+v1+v2, s2=v0*v0+v1*v1+v2*v2;
  for (int off=32; off; off>>=1){ s1+=__shfl_xor(s1,off); s2+=__shfl_xor(s2,off); }
  __shared__ float red[8];
  __shared__ float mu_s, rs_s;
  int w=tid>>6, ln=tid&63;
  if (ln==0){ red[w]=s1; red[4+w]=s2; }
  __syncthreads();
  if (tid==0){
    float S1=red[0]+red[1]+red[2]+red[3];
    float S2=red[4]+red[5]+red[6]+red[7];
    float mu = S1*(1.f/D_);
    float var= S2*(1.f/D_) - mu*mu;
    mu_s=mu; rs_s=rsqrtf(var + 1e-5f);
  }
  __syncthreads();
  float mu=mu_s, rs=rs_s;
  u16* yr = Y + (size_t)r*D_;
  yr[tid]     = ftou16((v0-mu)*rs*g[tid]     + bt[tid]);
  yr[tid+256] = ftou16((v1-mu)*rs*g[tid+256] + bt[tid+256]);
  yr[tid+512] = ftou16((v2-mu)*rs*g[tid+512] + bt[tid+512]);
}

// ---------------- MFMA GEMM body ----------------
// MODE 0: C0_bf16 ; 1: C0_f32 += ; 2: C0_bf16 = gelu ; 6: C1_f32 = C0_f32 + result (C0 read-only)
// MODE 4: self QKV (N=2304): Q->C0, K->C1, V^T->C2 [b][768][KCAP]  (V writes ushort4-packed)
// MODE 5: cross KV (N=1536): K->C0, V^T->C2 [b][768][1024]         (V writes ushort4-packed)
template<int MODE, int BM, typename TA>
__device__ __forceinline__ void gemm_body(char* ldsp, const TA* __restrict__ A, const u16* __restrict__ Bt,
                                          void* __restrict__ C0, void* __restrict__ C1, void* __restrict__ C2,
                                          int wgid, int N, int K){
  constexpr int MI   = BM/32;
  constexpr int NBUF = (BM==128) ? 2 : ((sizeof(TA)==4) ? 2 : 3);
  u16* As = (u16*)ldsp;
  u16* Bs = (u16*)(ldsp + NBUF*(BM*32)*2);
  int nbx = N >> 7;
  int bx = wgid % nbx, by = wgid / nbx;
  int tid = threadIdx.x;
  int w = tid>>6, l = tid&63, g = l>>4, c = l&15;
  int wr = w&1, wc = w>>1;
  f32x4 acc[MI][4] = {};
  float4 rg[4];
  const int NK = K/32;

  auto STAGEB = [&](int buf, int kt){
    #pragma unroll
    for (int p=0;p<2;++p){
      int row = w*32 + p*16 + (l>>2);
      int su  = (l&3) ^ ((row>>1)&3);
      gld16((const void*)(Bt + (size_t)(bx*128+row)*K + kt + su*8), (void*)&Bs[buf*128*32 + (w*32+p*16)*32]);
    }
  };
  auto STAGEA16 = [&](int buf, int kt){
    if constexpr (BM==128){
      #pragma unroll
      for (int p=0;p<2;++p){
        int row = w*32 + p*16 + (l>>2);
        int su  = (l&3) ^ ((row>>1)&3);
        gld16((const void*)((const u16*)A + (size_t)(by*BM+row)*K + kt + su*8), (void*)&As[buf*BM*32 + (w*32+p*16)*32]);
      }
    } else {
      int row = w*16 + (l>>2);
      int su  = (l&3) ^ ((row>>1)&3);
      gld16((const void*)((const u16*)A + (size_t)(by*BM+row)*K + kt + su*8), (void*)&As[buf*BM*32 + (w*16)*32]);
    }
  };
  auto LOADREG = [&](int kt){
    if constexpr (BM==128){
      const float* ap = (const float*)A + (size_t)(by*BM + (tid>>1))*K + kt + (tid&1)*16;
      rg[0]=*(const float4*)ap;     rg[1]=*(const float4*)(ap+4);
      rg[2]=*(const float4*)(ap+8); rg[3]=*(const float4*)(ap+12);
    } else {
      const float* ap = (const float*)A + (size_t)(by*BM + (tid>>2))*K + kt + (tid&3)*8;
      rg[0] = *(const float4*)ap; rg[1] = *(const float4*)(ap+4);
    }
  };
  auto WRITEA = [&](int buf){
    if constexpr (BM==128){
      int row = tid>>1, half = tid&1;
      uint4 w0,w1;
      w0.x=pk2(rg[0].x,rg[0].y); w0.y=pk2(rg[0].z,rg[0].w); w0.z=pk2(rg[1].x,rg[1].y); w0.w=pk2(rg[1].z,rg[1].w);
      w1.x=pk2(rg[2].x,rg[2].y); w1.y=pk2(rg[2].z,rg[2].w); w1.z=pk2(rg[3].x,rg[3].y); w1.w=pk2(rg[3].z,rg[3].w);
      int sw = (row>>1)&3;
      *(uint4*)&As[buf*BM*32 + row*32 + ((half*2  )^sw)*8] = w0;
      *(uint4*)&As[buf*BM*32 + row*32 + ((half*2+1)^sw)*8] = w1;
    } else {
      int row = tid>>2, unit = tid&3;
      uint4 wv;
      wv.x=pk2(rg[0].x,rg[0].y); wv.y=pk2(rg[0].z,rg[0].w); wv.z=pk2(rg[1].x,rg[1].y); wv.w=pk2(rg[1].z,rg[1].w);
      int sw = (row>>1)&3;
      *(uint4*)&As[buf*BM*32 + row*32 + (unit^sw)*8] = wv;
    }
  };
  auto COMPUTE = [&](int buf){
    short8 af[MI], bfr[4];
    #pragma unroll
    for (int mi=0;mi<MI;++mi){ int row = wr*(MI*16) + mi*16 + c; af[mi]  = *(const short8*)&As[buf*BM*32 + row*32 + (g^((row>>1)&3))*8]; }
    #pragma unroll
    for (int ni=0;ni<4;++ni){ int row = wc*64 + ni*16 + c;       bfr[ni] = *(const short8*)&Bs[buf*128*32 + row*32 + (g^((row>>1)&3))*8]; }
    #pragma unroll
    for (int mi=0;mi<MI;++mi)
      #pragma unroll
      for (int ni=0;ni<4;++ni) acc[mi][ni] = MFMA(af[mi], bfr[ni], acc[mi][ni]);
  };

  if constexpr (BM==128 || sizeof(TA)==4){
    if constexpr (sizeof(TA)==4){ LOADREG(0); STAGEB(0,0); WRITEA(0); }
    else { STAGEA16(0,0); STAGEB(0,0); }
    __syncthreads();
    int buf = 0;
    for (int t=0;t<NK;++t){
      int ktn = (t+1)*32;
      if constexpr (sizeof(TA)==4){
        if (t+1<NK){ LOADREG(ktn); STAGEB(buf^1, ktn); }
        COMPUTE(buf);
        if (t+1<NK) WRITEA(buf^1);
      } else {
        if (t+1<NK){ STAGEA16(buf^1, ktn); STAGEB(buf^1, ktn); }
        COMPUTE(buf);
      }
      __syncthreads();
      buf ^= 1;
    }
  } else {
    constexpr int LPS = 3;
    STAGEA16(0,0);  STAGEB(0,0);
    STAGEA16(1,32); STAGEB(1,32);
    vwait<LPS>();
    wgbar();
    int buf = 0;
    for (int t=0;t<NK;++t){
      if (t+2 < NK){
        int nb = buf+2; if (nb>=3) nb-=3;
        STAGEA16(nb,(t+2)*32); STAGEB(nb,(t+2)*32);
      }
      COMPUTE(buf);
      if (t < NK-2) vwait<LPS>(); else vwait<0>();
      wgbar();
      ++buf; if (buf==3) buf=0;
    }
  }

  int row0 = by*BM + wr*(MI*16), col0 = bx*128 + wc*64;
  #pragma unroll
  for (int mi=0;mi<MI;++mi)
    #pragma unroll
    for (int ni=0;ni<4;++ni){
      int rowb = row0 + mi*16 + g*4;
      int col  = col0 + ni*16 + c;
      if (MODE==4 && col >= 1536){
        int vv = col - 1536; int bb = rowb / KCAP; int key = rowb - bb*KCAP;
        ushort4 pk;
        pk.x = ftou16(acc[mi][ni][0]); pk.y = ftou16(acc[mi][ni][1]);
        pk.z = ftou16(acc[mi][ni][2]); pk.w = ftou16(acc[mi][ni][3]);
        *(ushort4*)&((u16*)C2)[((size_t)(bb*768 + vv))*KCAP + key] = pk;
      } else if (MODE==5 && col >= 768){
        int vv = col - 768; int bb = rowb >> 10; int key = rowb & 1023;
        ushort4 pk;
        pk.x = ftou16(acc[mi][ni][0]); pk.y = ftou16(acc[mi][ni][1]);
        pk.z = ftou16(acc[mi][ni][2]); pk.w = ftou16(acc[mi][ni][3]);
        *(ushort4*)&((u16*)C2)[((size_t)(bb*768 + vv))*1024 + key] = pk;
      } else {
        #pragma unroll
        for (int r=0;r<4;++r){
          int row = rowb + r;
          float v = acc[mi][ni][r];
          if (MODE==0){
            ((u16*)C0)[(size_t)row*N + col] = ftou16(v);
          } else if (MODE==1){
            ((float*)C0)[(size_t)row*N + col] += v;
          } else if (MODE==2){
            float z2 = 1.5957691216057308f*(v + 0.044715f*v*v*v);
            float e  = __expf(z2);
            float th = 1.f - 2.f/(e + 1.f);
            ((u16*)C0)[(size_t)row*N + col] = ftou16(0.5f*v*(1.f+th));
          } else if (MODE==6){
            size_t idx = (size_t)row*N + col;
            ((float*)C1)[idx] = ((const float*)C0)[idx] + v;
          } else if (MODE==4){
            if (col < 768)  ((u16*)C0)[(size_t)row*768 + col]       = ftou16(v);
            else            ((u16*)C1)[(size_t)row*768 + col - 768] = ftou16(v);
          } else { // MODE 5, col < 768
            ((u16*)C0)[(size_t)row*768 + col] = ftou16(v);
          }
        }
      }
    }
}

template<int MODE, int BM, typename TA>
__global__ __launch_bounds__(256) void gemm_k(const TA* __restrict__ A, const u16* __restrict__ Bt,
                                              void* __restrict__ C0, void* __restrict__ C1, void* __restrict__ C2,
                                              int N, int K){
  constexpr int NBUF = (BM==128) ? 2 : ((sizeof(TA)==4) ? 2 : 3);
  __shared__ __align__(16) char pool[NBUF*(BM+128)*32*2];
  gemm_body<MODE,BM,TA>(pool, A, Bt, C0, C1, C2, xcd_swz(), N, K);
}

// mega1: self QKV (720 blocks) + cross img KV (768 blocks), both BM=128 bf16-A, one dispatch
__global__ __launch_bounds__(256) void mega1_k(const u16* __restrict__ T0, const u16* __restrict__ wqkv_st,
                                               u16* __restrict__ Qb, u16* __restrict__ Kb, u16* __restrict__ VtS,
                                               const u16* __restrict__ imgB, const u16* __restrict__ wkv_ct,
                                               u16* __restrict__ KbC, u16* __restrict__ VtC){
  __shared__ __align__(16) char pool[2*(128+128)*32*2];
  int wgid = xcd_swz();   // grid = 1488
  if (wgid < 720) gemm_body<4,128,u16>(pool, T0,   wqkv_st, Qb,  Kb,      VtS, wgid,     2304, 768);
  else            gemm_body<5,128,u16>(pool, imgB, wkv_ct,  KbC, nullptr, VtC, wgid-720, 1536, 768);
}

// ---------------- MFMA flash attention: 128 q / block (4 waves x 32 q), 3-buf counted-vmcnt ----------------
template<int MASKED>
__global__ __launch_bounds__(256) void attn_k(const u16* __restrict__ Q, const u16* __restrict__ Kb,
                                              const u16* __restrict__ Vt, u16* __restrict__ O,
                                              const int* __restrict__ counts, int Lk){
  __shared__ __align__(16) u16 Ks[3][64*64];
  __shared__ __align__(16) u16 Vs[3][64*64];
  __shared__ __align__(16) u16 P[4][16][72];
  int tid = threadIdx.x;
  int w = tid>>6, l = tid&63, g = l>>4, c = l&15;
  int wgid = xcd_swz();
  int qc = wgid % 5;
  int bh = wgid / 5;
  int h = bh % H_, b = bh / H_;
  int q0 = qc*128 + w*32;
  int cnt = MASKED ? counts[b] : Lk;
  int nt = (cnt + 63) >> 6;

  short8 qf[2][2];
  #pragma unroll
  for (int mi=0;mi<2;++mi){
    const u16* Qrow = Q + ((size_t)(b*KCAP + q0 + mi*16 + c))*D_ + h*DH_;
    qf[mi][0] = *(const short8*)(Qrow + g*8);
    qf[mi][1] = *(const short8*)(Qrow + 32 + g*8);
  }

  int srow8 = (l>>3);
  int sunit = l&7;
  auto STAGE = [&](int buf, int kb){
    #pragma unroll
    for (int p=0;p<2;++p){
      int r0 = w*16 + p*8;
      int rowK = r0 + srow8;
      int su = sunit ^ (rowK&7);
      gld16((const void*)(Kb + ((size_t)(b*Lk + kb + rowK))*D_ + h*DH_ + su*8), (void*)&Ks[buf][r0*64]);
      gld16((const void*)(Vt + ((size_t)(b*D_ + h*DH_ + rowK))*Lk + kb + su*8), (void*)&Vs[buf][r0*64]);
    }
  };

  f32x4 o[2][4] = {};
  float m_[2][4], l_[2][4] = {};
  #pragma unroll
  for (int mi=0;mi<2;++mi)
    #pragma unroll
    for (int r=0;r<4;++r) m_[mi][r] = -1e30f;

  STAGE(0, 0);
  if (nt > 1){ STAGE(1, 64); vwait<4>(); } else { vwait<0>(); }
  wgbar();
  int buf = 0;
  for (int t=0; t<nt; ++t){
    int kb = t*64;
    if (t+2 < nt){
      int nb = buf+2; if (nb>=3) nb-=3;
      STAGE(nb, kb+128);
    }
    short8 fr[4][2];
    #pragma unroll
    for (int nb=0;nb<4;++nb)
      #pragma unroll
      for (int kh=0;kh<2;++kh)
        fr[nb][kh] = *(const short8*)&Ks[buf][(nb*16+c)*64 + (((kh<<2)|g) ^ (c&7))*8];
    f32x4 z[2][4];
    #pragma unroll
    for (int mi=0;mi<2;++mi)
      #pragma unroll
      for (int nb=0;nb<4;++nb){
        f32x4 zz = {0.f,0.f,0.f,0.f};
        zz = MFMA(qf[mi][0], fr[nb][0], zz);
        zz = MFMA(qf[mi][1], fr[nb][1], zz);
        z[mi][nb] = zz;
      }
    float pv[2][4][4];
    #pragma unroll
    for (int nb=0;nb<4;++nb){
      bool msk = MASKED && (kb + nb*16 + c >= cnt);
      #pragma unroll
      for (int mi=0;mi<2;++mi)
        #pragma unroll
        for (int r=0;r<4;++r) pv[mi][nb][r] = msk ? -1e30f : z[mi][nb][r]*0.125f;
    }
    float scl[2][4];
    #pragma unroll
    for (int mi=0;mi<2;++mi){
      #pragma unroll
      for (int r=0;r<4;++r){
        float v = fmaxf(fmaxf(pv[mi][0][r],pv[mi][1][r]), fmaxf(pv[mi][2][r],pv[mi][3][r]));
        v = fmaxf(v, __shfl_xor(v,1)); v = fmaxf(v, __shfl_xor(v,2));
        v = fmaxf(v, __shfl_xor(v,4)); v = fmaxf(v, __shfl_xor(v,8));
        float nm = fmaxf(m_[mi][r], v);
        scl[mi][r] = __expf(m_[mi][r] - nm);
        m_[mi][r] = nm;
      }
      #pragma unroll
      for (int r=0;r<4;++r){
        float acc2 = 0.f;
        #pragma unroll
        for (int nb=0;nb<4;++nb){
          float e = __expf(pv[mi][nb][r] - m_[mi][r]);
          pv[mi][nb][r] = e; acc2 += e;
        }
        acc2 += __shfl_xor(acc2,1); acc2 += __shfl_xor(acc2,2);
        acc2 += __shfl_xor(acc2,4); acc2 += __shfl_xor(acc2,8);
        l_[mi][r] = l_[mi][r]*scl[mi][r] + acc2;
      }
      #pragma unroll
      for (int nbd=0;nbd<4;++nbd)
        #pragma unroll
        for (int r=0;r<4;++r) o[mi][nbd][r] *= scl[mi][r];
    }
    short8 fv[4][2];
    #pragma unroll
    for (int nbd=0;nbd<4;++nbd)
      #pragma unroll
      for (int kh=0;kh<2;++kh)
        fv[nbd][kh] = *(const short8*)&Vs[buf][(nbd*16+c)*64 + (((kh<<2)|g) ^ (c&7))*8];
    #pragma unroll
    for (int mi=0;mi<2;++mi){
      #pragma unroll
      for (int nb=0;nb<4;++nb)
        #pragma unroll
        for (int r=0;r<4;++r) P[w][g*4+r][nb*16+c] = ftou16(pv[mi][nb][r]);
      short8 pa0 = *(const short8*)&P[w][c][g*8];
      short8 pa1 = *(const short8*)&P[w][c][32 + g*8];
      #pragma unroll
      for (int nbd=0;nbd<4;++nbd){
        o[mi][nbd] = MFMA(pa0, fv[nbd][0], o[mi][nbd]);
        o[mi][nbd] = MFMA(pa1, fv[nbd][1], o[mi][nbd]);
      }
    }
    if (t < nt-2) vwait<4>(); else vwait<0>();
    wgbar();
    ++buf; if (buf==3) buf=0;
  }
  #pragma unroll
  for (int mi=0;mi<2;++mi)
    #pragma unroll
    for (int nbd=0;nbd<4;++nbd)
      #pragma unroll
      for (int r=0;r<4;++r)
        O[((size_t)(b*KCAP + q0 + mi*16 + g*4 + r))*D_ + h*DH_ + nbd*16 + c] = ftou16(o[mi][nbd][r] / l_[mi][r]);
}

// ---------------- final scatter: SOC rows only, from out1 (= x final, f32) ----------------
__global__ __launch_bounds__(256) void scatter_soc_k(const int* __restrict__ pos,
                                                     const float* __restrict__ out1,
                                                     float* __restrict__ out0){
  int base = blockIdx.x*4; int tid = threadIdx.x;
  #pragma unroll
  for (int r2=0;r2<4;++r2){
    int bs = base + r2;
    int p = pos[bs];
    if (p < 0) continue;
    int pc = p < KCAP ? p : (KCAP-1);
    int b = bs >> 12;
    const float* xr = out1 + ((size_t)(b*KCAP + pc))*D_;
    float* orow = out0 + (size_t)bs*D_;
    orow[tid]     = xr[tid];
    orow[tid+256] = xr[tid+256];
    orow[tid+512] = xr[tid+512];
  }
}

extern "C" void kernel_launch(void* const* d_in, const int* in_sizes, int n_in,
                              void* d_out, int out_size, void* d_ws, size_t ws_size,
                              hipStream_t stream){
  const float* img  = (const float*)d_in[0];
  const float* hid  = (const float*)d_in[1];
  const int*   seq  = (const int*)  d_in[2];
  const float* W[10] = { (const float*)d_in[3], (const float*)d_in[4], (const float*)d_in[5], (const float*)d_in[6],
                         (const float*)d_in[7], (const float*)d_in[8], (const float*)d_in[9], (const float*)d_in[10],
                         (const float*)d_in[11], (const float*)d_in[12] };
  const float* ln1s = (const float*)d_in[13];
  const float* ln1b = (const float*)d_in[14];
  const float* ln2s = (const float*)d_in[15];
  const float* ln2b = (const float*)d_in[16];
  const float* ln3s = (const float*)d_in[17];
  const float* ln3b = (const float*)d_in[18];

  char* ws = (char*)d_ws;
  int*   pos    = (int*)  (ws + 0);
  int*   src    = (int*)  (ws + 131072);
  int*   counts = (int*)  (ws + 151552);
  float* X      = (float*)(ws + 151808);
  u16*   T0     = (u16*)  (ws + 15880448);
  u16*   Qb     = (u16*)  (ws + 23744768);
  u16*   Kb     = (u16*)  (ws + 31609088);
  u16*   VtS    = (u16*)  (ws + 39473408);
  u16*   KbC    = (u16*)  (ws + 47337728);
  u16*   VtC    = (u16*)  (ws + 59920640);
  u16*   AO     = (u16*)  (ws + 72503552);
  u16*   Wt     = (u16*)  (ws + 80367872);
  u16*   MID    = Qb;

  u16* wqkv_st = Wt + 0ull*589824;
  u16* wo_st   = Wt + 3ull*589824;
  u16* wq_ct   = Wt + 4ull*589824;
  u16* wkv_ct  = Wt + 5ull*589824;
  u16* wo_ct   = Wt + 7ull*589824;
  u16* wff1t   = Wt + 8ull*589824;
  u16* wff2t   = wff1t + 2359296;

  float* out0 = (float*)d_out;
  float* out1 = out0 + (size_t)B_*S_*D_;
  u16* imgB = (u16*)out1;   // scratch in out1 region; FF2 rewrites out1 fully

  TransArgs ta;
  for (int i=0;i<10;++i) ta.w[i] = W[i];
  for (int i=0;i<8;++i)  ta.o[i] = Wt + (size_t)i*589824;
  ta.o[8] = wff1t; ta.o[9] = wff2t;

  transpose_scan_k<<<12296, 256, 0, stream>>>(ta, seq, pos, src, counts, img, imgB);
  prep_k<<<13312, 256, 0, stream>>>(hid, src, counts, pos, ln1s, ln1b, X, T0, out0);

  const int G_MEGA1 = 720 + 768;             // 1488
  const int G_N768  = (5120/64)*(768/128);   // 480
  const int G_FF1   = (5120/128)*(3072/128); // 960
  const int G_ATT   = B_*H_*5;               // 480

  // ---- self-attention block (+ independent img KV projection fused) ----
  mega1_k<<<G_MEGA1, 256, 0, stream>>>(T0, wqkv_st, Qb, Kb, VtS, imgB, wkv_ct, KbC, VtC);
  attn_k<1><<<G_ATT, 256, 0, stream>>>(Qb, Kb, VtS, AO, counts, KCAP);
  gemm_k<1,64,u16><<<G_N768, 256, 0, stream>>>(AO, wo_st, X, nullptr, nullptr, 768, 768);

  // ---- cross-attention block ----
  ln_k<<<5120, 256, 0, stream>>>(X, T0, ln2s, ln2b);
  gemm_k<0,64,u16><<<G_N768, 256, 0, stream>>>(T0, wq_ct, Qb, nullptr, nullptr, 768, 768);
  attn_k<0><<<G_ATT, 256, 0, stream>>>(Qb, KbC, VtC, AO, counts, N_);
  gemm_k<1,64,u16><<<G_N768, 256, 0, stream>>>(AO, wo_ct, X, nullptr, nullptr, 768, 768);

  // ---- FFN block (FF2 writes out1 = X + ff2) ----
  ln_k<<<5120, 256, 0, stream>>>(X, T0, ln3s, ln3b);
  gemm_k<2,128,u16><<<G_FF1, 256, 0, stream>>>(T0, wff1t, MID, nullptr, nullptr, 3072, 768);
  gemm_k<6,64,u16><<<G_N768, 256, 0, stream>>>(MID, wff2t, X, out1, nullptr, 768, 3072);

  // ---- final: SOC rows of out0 from out1 ----
  scatter_soc_k<<<8192, 256, 0, stream>>>(pos, out1, out0);
}

// Round 14
// 392.442 us; speedup vs baseline: 6.6548x; 1.0532x over previous
//
#include <hip/hip_runtime.h>
#include <hip/hip_bf16.h>

// Fetcher: SOC extraction -> [self-attn + cross-attn(img) + GELU-FFN] -> scatter-back.
// Round 14: attn softmax VALU diet — exp2-domain scores, defer-max (THR=8) rescale skip,
//           per-thread deferred l-reduction (end-of-loop shuffle sum), rcp normalize.

#define B_    8
#define S_    4096
#define D_    768
#define N_    1024
#define FF_   3072
#define H_    12
#define DH_   64
#define KCAP  640
#define SOC_TOK 3
#define EOS_TOK 2

typedef __hip_bfloat16 bf16;
typedef unsigned short u16;
typedef __attribute__((ext_vector_type(8))) short short8;
typedef __attribute__((ext_vector_type(4))) float f32x4;

__device__ __forceinline__ u16 ftou16(float x){ union{bf16 b; u16 s;} c; c.b = __float2bfloat16(x); return c.s; }
__device__ __forceinline__ unsigned pk2(float lo, float hi){ return (unsigned)ftou16(lo) | ((unsigned)ftou16(hi)<<16); }

__device__ __forceinline__ f32x4 MFMA(short8 a, short8 b, f32x4 c){
  return __builtin_amdgcn_mfma_f32_16x16x32_bf16(a, b, c, 0, 0, 0);
}

__device__ __forceinline__ void gld16(const void* gp, void* lp){
  __builtin_amdgcn_global_load_lds(
    reinterpret_cast<const __attribute__((address_space(1))) unsigned int*>((size_t)gp),
    reinterpret_cast<__attribute__((address_space(3))) unsigned int*>((size_t)lp),
    16, 0, 0);
}

template<int N> __device__ __forceinline__ void vwait(){
  asm volatile("s_waitcnt vmcnt(%0)" :: "i"(N) : "memory");
}
__device__ __forceinline__ void wgbar(){ asm volatile("s_barrier" ::: "memory"); }

// v_exp_f32 computes 2^x natively
__device__ __forceinline__ float fexp2(float x){ float r; asm("v_exp_f32 %0, %1" : "=v"(r) : "v"(x)); return r; }

__device__ __forceinline__ int xcd_swz(){
  int id = blockIdx.x;
  return (id & 7) * ((int)gridDim.x >> 3) + (id >> 3);
}

// ---------------- scan body ----------------
__device__ void scan_body(const int* __restrict__ seq, int* __restrict__ pos,
                          int* __restrict__ src, int* __restrict__ counts, int b){
  int tid = threadIdx.x;
  __shared__ int sd[256];
  __shared__ int carryE, carryS;
  if (tid==0){ carryE=0; carryS=0; }
  __syncthreads();
  for (int c=0; c<S_; c+=256){
    int s   = c + tid;
    int tok = seq[b*S_ + s];
    int isE = (tok==EOS_TOK) ? 1 : 0;
    int isS = (tok==SOC_TOK) ? 1 : 0;
    sd[tid]=isE; __syncthreads();
    for (int off=1; off<256; off<<=1){ int t_=(tid>=off)?sd[tid-off]:0; __syncthreads(); sd[tid]+=t_; __syncthreads(); }
    int eIncl = sd[tid];
    int eTot  = sd[255];
    int valid = (isS && (carryE + eIncl)==0) ? 1 : 0;
    __syncthreads();
    sd[tid]=valid; __syncthreads();
    for (int off=1; off<256; off<<=1){ int t_=(tid>=off)?sd[tid-off]:0; __syncthreads(); sd[tid]+=t_; __syncthreads(); }
    int vIncl = sd[tid];
    int vTot  = sd[255];
    if (valid){
      int slot = carryS + vIncl - 1;
      pos[b*S_ + s] = slot;
      if (slot < KCAP) src[b*KCAP + slot] = s;
    } else {
      pos[b*S_ + s] = -1;
    }
    __syncthreads();
    if (tid==0){ carryE += eTot; carryS += vTot; }
    __syncthreads();
  }
  if (tid==0) counts[b] = (carryS < KCAP) ? carryS : KCAP;
}

// ---------------- transpose + scan + img->bf16 convert, one launch ----------------
struct TransArgs { const float* w[10]; u16* o[10]; };
__global__ __launch_bounds__(256) void transpose_scan_k(TransArgs a, const int* __restrict__ seq,
                                                        int* __restrict__ pos, int* __restrict__ src,
                                                        int* __restrict__ counts,
                                                        const float* __restrict__ img, u16* __restrict__ imgB){
  int id = blockIdx.x;
  if (id >= 9224){
    int base = (id - 9224)*2048 + threadIdx.x*8;
    float4 a0 = *(const float4*)(img + base);
    float4 a1 = *(const float4*)(img + base + 4);
    uint4 wv;
    wv.x = pk2(a0.x,a0.y); wv.y = pk2(a0.z,a0.w); wv.z = pk2(a1.x,a1.y); wv.w = pk2(a1.z,a1.w);
    *(uint4*)(imgB + base) = wv;
    return;
  }
  if (id >= 9216){ scan_body(seq, pos, src, counts, id - 9216); return; }
  __shared__ float tile[32][33];
  int wi, t, K, N;
  if (id < 4608){ wi = id/576; t = id%576; K = 768; N = 768; }
  else if (id < 6912){ wi = 8; t = id-4608; K = 768; N = 3072; }
  else { wi = 9; t = id-6912; K = 3072; N = 768; }
  const float* in = a.w[wi]; u16* out = a.o[wi];
  int nbx = N >> 5;
  int bx = t % nbx, by = t / nbx;
  int tx = threadIdx.x & 31, ty = threadIdx.x >> 5;
  #pragma unroll
  for (int i=0;i<4;++i)
    tile[ty + i*8][tx] = in[(size_t)(by*32 + ty + i*8)*N + bx*32 + tx];
  __syncthreads();
  #pragma unroll
  for (int i=0;i<4;++i)
    out[(size_t)(bx*32 + ty + i*8)*K + by*32 + tx] = ftou16(tile[tx][ty + i*8]);
}

// ---------------- prep: gather+LN1 (blocks 0..5119) + hid-copy of non-SOC rows ----------------
__global__ __launch_bounds__(256) void prep_k(const float* __restrict__ hid,
                                              const int* __restrict__ src,
                                              const int* __restrict__ counts,
                                              const int* __restrict__ pos,
                                              const float* __restrict__ g, const float* __restrict__ bt,
                                              float* __restrict__ X, u16* __restrict__ T0,
                                              float* __restrict__ out0){
  int id = blockIdx.x; int tid = threadIdx.x;
  if (id >= 5120){
    int base = (id - 5120)*4;
    #pragma unroll
    for (int r2=0;r2<4;++r2){
      int bs = base + r2;
      if (pos[bs] >= 0) continue;
      const float* hr = hid + (size_t)bs*D_;
      float* orow = out0 + (size_t)bs*D_;
      orow[tid]     = hr[tid];
      orow[tid+256] = hr[tid+256];
      orow[tid+512] = hr[tid+512];
    }
    return;
  }
  int bk = id; int b = bk / KCAP; int k = bk % KCAP;
  float v0, v1, v2;
  if (k < counts[b]){
    const float* hr = hid + ((size_t)b*S_ + src[b*KCAP + k])*D_;
    v0 = hr[tid]; v1 = hr[tid+256]; v2 = hr[tid+512];
  } else { v0 = v1 = v2 = 0.f; }
  float* xr = X + (size_t)bk*D_;
  xr[tid] = v0; xr[tid+256] = v1; xr[tid+512] = v2;
  float s1=v0+v1+v2, s2=v0*v0+v1*v1+v2*v2;
  for (int off=32; off; off>>=1){ s1+=__shfl_xor(s1,off); s2+=__shfl_xor(s2,off); }
  __shared__ float red[8];
  __shared__ float mu_s, rs_s;
  int w=tid>>6, ln=tid&63;
  if (ln==0){ red[w]=s1; red[4+w]=s2; }
  __syncthreads();
  if (tid==0){
    float S1=red[0]+red[1]+red[2]+red[3];
    float S2=red[4]+red[5]+red[6]+red[7];
    float mu = S1*(1.f/D_);
    float var= S2*(1.f/D_) - mu*mu;
    mu_s=mu; rs_s=rsqrtf(var + 1e-5f);
  }
  __syncthreads();
  float mu=mu_s, rs=rs_s;
  u16* yr = T0 + (size_t)bk*D_;
  yr[tid]     = ftou16((v0-mu)*rs*g[tid]     + bt[tid]);
  yr[tid+256] = ftou16((v1-mu)*rs*g[tid+256] + bt[tid+256]);
  yr[tid+512] = ftou16((v2-mu)*rs*g[tid+512] + bt[tid+512]);
}

// ---------------- layernorm ----------------
__global__ __launch_bounds__(256) void ln_k(const float* __restrict__ X, u16* __restrict__ Y,
                                            const float* __restrict__ g, const float* __restrict__ bt){
  int r = blockIdx.x; int tid = threadIdx.x;
  const float* xr = X + (size_t)r*D_;
  float v0=xr[tid], v1=xr[tid+256], v2=xr[tid+512];
  float s1=v0+v1+v2, s2=v0*v0+v1*v1+v2*v2;
  for (int off=32; off; off>>=1){ s1+=__shfl_xor(s1,off); s2+=__shfl_xor(s2,off); }
  __shared__ float red[8];
  __shared__ float mu_s, rs_s;
  int w=tid>>6, ln=tid&63;
  if (ln==0){ red[w]=s1; red[4+w]=s2; }
  __syncthreads();
  if (tid==0){
    float S1=red[0]+red[1]+red[2]+red[3];
    float S2=red[4]+red[5]+red[6]+red[7];
    float mu = S1*(1.f/D_);
    float var= S2*(1.f/D_) - mu*mu;
    mu_s=mu; rs_s=rsqrtf(var + 1e-5f);
  }
  __syncthreads();
  float mu=mu_s, rs=rs_s;
  u16* yr = Y + (size_t)r*D_;
  yr[tid]     = ftou16((v0-mu)*rs*g[tid]     + bt[tid]);
  yr[tid+256] = ftou16((v1-mu)*rs*g[tid+256] + bt[tid+256]);
  yr[tid+512] = ftou16((v2-mu)*rs*g[tid+512] + bt[tid+512]);
}

// ---------------- MFMA GEMM body ----------------
// MODE 0: C0_bf16 ; 1: C0_f32 += ; 2: C0_bf16 = gelu ; 6: C1_f32 = C0_f32 + result (C0 read-only)
// MODE 4: self QKV (N=2304): Q->C0, K->C1, V^T->C2 [b][768][KCAP]  (V writes ushort4-packed)
// MODE 5: cross KV (N=1536): K->C0, V^T->C2 [b][768][1024]         (V writes ushort4-packed)
template<int MODE, int BM, typename TA>
__device__ __forceinline__ void gemm_body(char* ldsp, const TA* __restrict__ A, const u16* __restrict__ Bt,
                                          void* __restrict__ C0, void* __restrict__ C1, void* __restrict__ C2,
                                          int wgid, int N, int K){
  constexpr int MI   = BM/32;
  constexpr int NBUF = (BM==128) ? 2 : ((sizeof(TA)==4) ? 2 : 3);
  u16* As = (u16*)ldsp;
  u16* Bs = (u16*)(ldsp + NBUF*(BM*32)*2);
  int nbx = N >> 7;
  int bx = wgid % nbx, by = wgid / nbx;
  int tid = threadIdx.x;
  int w = tid>>6, l = tid&63, g = l>>4, c = l&15;
  int wr = w&1, wc = w>>1;
  f32x4 acc[MI][4] = {};
  float4 rg[4];
  const int NK = K/32;

  auto STAGEB = [&](int buf, int kt){
    #pragma unroll
    for (int p=0;p<2;++p){
      int row = w*32 + p*16 + (l>>2);
      int su  = (l&3) ^ ((row>>1)&3);
      gld16((const void*)(Bt + (size_t)(bx*128+row)*K + kt + su*8), (void*)&Bs[buf*128*32 + (w*32+p*16)*32]);
    }
  };
  auto STAGEA16 = [&](int buf, int kt){
    if constexpr (BM==128){
      #pragma unroll
      for (int p=0;p<2;++p){
        int row = w*32 + p*16 + (l>>2);
        int su  = (l&3) ^ ((row>>1)&3);
        gld16((const void*)((const u16*)A + (size_t)(by*BM+row)*K + kt + su*8), (void*)&As[buf*BM*32 + (w*32+p*16)*32]);
      }
    } else {
      int row = w*16 + (l>>2);
      int su  = (l&3) ^ ((row>>1)&3);
      gld16((const void*)((const u16*)A + (size_t)(by*BM+row)*K + kt + su*8), (void*)&As[buf*BM*32 + (w*16)*32]);
    }
  };
  auto LOADREG = [&](int kt){
    if constexpr (BM==128){
      const float* ap = (const float*)A + (size_t)(by*BM + (tid>>1))*K + kt + (tid&1)*16;
      rg[0]=*(const float4*)ap;     rg[1]=*(const float4*)(ap+4);
      rg[2]=*(const float4*)(ap+8); rg[3]=*(const float4*)(ap+12);
    } else {
      const float* ap = (const float*)A + (size_t)(by*BM + (tid>>2))*K + kt + (tid&3)*8;
      rg[0] = *(const float4*)ap; rg[1] = *(const float4*)(ap+4);
    }
  };
  auto WRITEA = [&](int buf){
    if constexpr (BM==128){
      int row = tid>>1, half = tid&1;
      uint4 w0,w1;
      w0.x=pk2(rg[0].x,rg[0].y); w0.y=pk2(rg[0].z,rg[0].w); w0.z=pk2(rg[1].x,rg[1].y); w0.w=pk2(rg[1].z,rg[1].w);
      w1.x=pk2(rg[2].x,rg[2].y); w1.y=pk2(rg[2].z,rg[2].w); w1.z=pk2(rg[3].x,rg[3].y); w1.w=pk2(rg[3].z,rg[3].w);
      int sw = (row>>1)&3;
      *(uint4*)&As[buf*BM*32 + row*32 + ((half*2  )^sw)*8] = w0;
      *(uint4*)&As[buf*BM*32 + row*32 + ((half*2+1)^sw)*8] = w1;
    } else {
      int row = tid>>2, unit = tid&3;
      uint4 wv;
      wv.x=pk2(rg[0].x,rg[0].y); wv.y=pk2(rg[0].z,rg[0].w); wv.z=pk2(rg[1].x,rg[1].y); wv.w=pk2(rg[1].z,rg[1].w);
      int sw = (row>>1)&3;
      *(uint4*)&As[buf*BM*32 + row*32 + (unit^sw)*8] = wv;
    }
  };
  auto COMPUTE = [&](int buf){
    short8 af[MI], bfr[4];
    #pragma unroll
    for (int mi=0;mi<MI;++mi){ int row = wr*(MI*16) + mi*16 + c; af[mi]  = *(const short8*)&As[buf*BM*32 + row*32 + (g^((row>>1)&3))*8]; }
    #pragma unroll
    for (int ni=0;ni<4;++ni){ int row = wc*64 + ni*16 + c;       bfr[ni] = *(const short8*)&Bs[buf*128*32 + row*32 + (g^((row>>1)&3))*8]; }
    #pragma unroll
    for (int mi=0;mi<MI;++mi)
      #pragma unroll
      for (int ni=0;ni<4;++ni) acc[mi][ni] = MFMA(af[mi], bfr[ni], acc[mi][ni]);
  };

  if constexpr (BM==128 || sizeof(TA)==4){
    if constexpr (sizeof(TA)==4){ LOADREG(0); STAGEB(0,0); WRITEA(0); }
    else { STAGEA16(0,0); STAGEB(0,0); }
    __syncthreads();
    int buf = 0;
    for (int t=0;t<NK;++t){
      int ktn = (t+1)*32;
      if constexpr (sizeof(TA)==4){
        if (t+1<NK){ LOADREG(ktn); STAGEB(buf^1, ktn); }
        COMPUTE(buf);
        if (t+1<NK) WRITEA(buf^1);
      } else {
        if (t+1<NK){ STAGEA16(buf^1, ktn); STAGEB(buf^1, ktn); }
        COMPUTE(buf);
      }
      __syncthreads();
      buf ^= 1;
    }
  } else {
    constexpr int LPS = 3;
    STAGEA16(0,0);  STAGEB(0,0);
    STAGEA16(1,32); STAGEB(1,32);
    vwait<LPS>();
    wgbar();
    int buf = 0;
    for (int t=0;t<NK;++t){
      if (t+2 < NK){
        int nb = buf+2; if (nb>=3) nb-=3;
        STAGEA16(nb,(t+2)*32); STAGEB(nb,(t+2)*32);
      }
      COMPUTE(buf);
      if (t < NK-2) vwait<LPS>(); else vwait<0>();
      wgbar();
      ++buf; if (buf==3) buf=0;
    }
  }

  int row0 = by*BM + wr*(MI*16), col0 = bx*128 + wc*64;
  #pragma unroll
  for (int mi=0;mi<MI;++mi)
    #pragma unroll
    for (int ni=0;ni<4;++ni){
      int rowb = row0 + mi*16 + g*4;
      int col  = col0 + ni*16 + c;
      if (MODE==4 && col >= 1536){
        int vv = col - 1536; int bb = rowb / KCAP; int key = rowb - bb*KCAP;
        ushort4 pk;
        pk.x = ftou16(acc[mi][ni][0]); pk.y = ftou16(acc[mi][ni][1]);
        pk.z = ftou16(acc[mi][ni][2]); pk.w = ftou16(acc[mi][ni][3]);
        *(ushort4*)&((u16*)C2)[((size_t)(bb*768 + vv))*KCAP + key] = pk;
      } else if (MODE==5 && col >= 768){
        int vv = col - 768; int bb = rowb >> 10; int key = rowb & 1023;
        ushort4 pk;
        pk.x = ftou16(acc[mi][ni][0]); pk.y = ftou16(acc[mi][ni][1]);
        pk.z = ftou16(acc[mi][ni][2]); pk.w = ftou16(acc[mi][ni][3]);
        *(ushort4*)&((u16*)C2)[((size_t)(bb*768 + vv))*1024 + key] = pk;
      } else {
        #pragma unroll
        for (int r=0;r<4;++r){
          int row = rowb + r;
          float v = acc[mi][ni][r];
          if (MODE==0){
            ((u16*)C0)[(size_t)row*N + col] = ftou16(v);
          } else if (MODE==1){
            ((float*)C0)[(size_t)row*N + col] += v;
          } else if (MODE==2){
            float z2 = 1.5957691216057308f*(v + 0.044715f*v*v*v);
            float e  = __expf(z2);
            float th = 1.f - 2.f/(e + 1.f);
            ((u16*)C0)[(size_t)row*N + col] = ftou16(0.5f*v*(1.f+th));
          } else if (MODE==6){
            size_t idx = (size_t)row*N + col;
            ((float*)C1)[idx] = ((const float*)C0)[idx] + v;
          } else if (MODE==4){
            if (col < 768)  ((u16*)C0)[(size_t)row*768 + col]       = ftou16(v);
            else            ((u16*)C1)[(size_t)row*768 + col - 768] = ftou16(v);
          } else { // MODE 5, col < 768
            ((u16*)C0)[(size_t)row*768 + col] = ftou16(v);
          }
        }
      }
    }
}

template<int MODE, int BM, typename TA>
__global__ __launch_bounds__(256) void gemm_k(const TA* __restrict__ A, const u16* __restrict__ Bt,
                                              void* __restrict__ C0, void* __restrict__ C1, void* __restrict__ C2,
                                              int N, int K){
  constexpr int NBUF = (BM==128) ? 2 : ((sizeof(TA)==4) ? 2 : 3);
  __shared__ __align__(16) char pool[NBUF*(BM+128)*32*2];
  gemm_body<MODE,BM,TA>(pool, A, Bt, C0, C1, C2, xcd_swz(), N, K);
}

// mega1: self QKV (720 blocks) + cross img KV (768 blocks), both BM=128 bf16-A, one dispatch
__global__ __launch_bounds__(256) void mega1_k(const u16* __restrict__ T0, const u16* __restrict__ wqkv_st,
                                               u16* __restrict__ Qb, u16* __restrict__ Kb, u16* __restrict__ VtS,
                                               const u16* __restrict__ imgB, const u16* __restrict__ wkv_ct,
                                               u16* __restrict__ KbC, u16* __restrict__ VtC){
  __shared__ __align__(16) char pool[2*(128+128)*32*2];
  int wgid = xcd_swz();   // grid = 1488
  if (wgid < 720) gemm_body<4,128,u16>(pool, T0,   wqkv_st, Qb,  Kb,      VtS, wgid,     2304, 768);
  else            gemm_body<5,128,u16>(pool, imgB, wkv_ct,  KbC, nullptr, VtC, wgid-720, 1536, 768);
}

// ---------------- MFMA flash attention: 128 q / block, exp2-domain deferred softmax ----------------
template<int MASKED>
__global__ __launch_bounds__(256) void attn_k(const u16* __restrict__ Q, const u16* __restrict__ Kb,
                                              const u16* __restrict__ Vt, u16* __restrict__ O,
                                              const int* __restrict__ counts, int Lk){
  constexpr float C2E  = 0.18033688011112043f;  // 0.125 * log2(e)
  constexpr float THR2 = 11.541560327111707f;   // 8 * log2(e)
  __shared__ __align__(16) u16 Ks[3][64*64];
  __shared__ __align__(16) u16 Vs[3][64*64];
  __shared__ __align__(16) u16 P[4][16][72];
  int tid = threadIdx.x;
  int w = tid>>6, l = tid&63, g = l>>4, c = l&15;
  int wgid = xcd_swz();
  int qc = wgid % 5;
  int bh = wgid / 5;
  int h = bh % H_, b = bh / H_;
  int q0 = qc*128 + w*32;
  int cnt = MASKED ? counts[b] : Lk;
  int nt = (cnt + 63) >> 6;

  short8 qf[2][2];
  #pragma unroll
  for (int mi=0;mi<2;++mi){
    const u16* Qrow = Q + ((size_t)(b*KCAP + q0 + mi*16 + c))*D_ + h*DH_;
    qf[mi][0] = *(const short8*)(Qrow + g*8);
    qf[mi][1] = *(const short8*)(Qrow + 32 + g*8);
  }

  int srow8 = (l>>3);
  int sunit = l&7;
  auto STAGE = [&](int buf, int kb){
    #pragma unroll
    for (int p=0;p<2;++p){
      int r0 = w*16 + p*8;
      int rowK = r0 + srow8;
      int su = sunit ^ (rowK&7);
      gld16((const void*)(Kb + ((size_t)(b*Lk + kb + rowK))*D_ + h*DH_ + su*8), (void*)&Ks[buf][r0*64]);
      gld16((const void*)(Vt + ((size_t)(b*D_ + h*DH_ + rowK))*Lk + kb + su*8), (void*)&Vs[buf][r0*64]);
    }
  };

  f32x4 o[2][4] = {};
  float m_[2][4], lp[2][4] = {};   // lp: per-thread partial denominator
  #pragma unroll
  for (int mi=0;mi<2;++mi)
    #pragma unroll
    for (int r=0;r<4;++r) m_[mi][r] = -1e30f;

  STAGE(0, 0);
  if (nt > 1){ STAGE(1, 64); vwait<4>(); } else { vwait<0>(); }
  wgbar();
  int buf = 0;
  for (int t=0; t<nt; ++t){
    int kb = t*64;
    if (t+2 < nt){
      int nb = buf+2; if (nb>=3) nb-=3;
      STAGE(nb, kb+128);
    }
    short8 fr[4][2];
    #pragma unroll
    for (int nb=0;nb<4;++nb)
      #pragma unroll
      for (int kh=0;kh<2;++kh)
        fr[nb][kh] = *(const short8*)&Ks[buf][(nb*16+c)*64 + (((kh<<2)|g) ^ (c&7))*8];
    // QK^T -> scores in log2 domain
    float pv[2][4][4];
    #pragma unroll
    for (int mi=0;mi<2;++mi)
      #pragma unroll
      for (int nb=0;nb<4;++nb){
        f32x4 zz = {0.f,0.f,0.f,0.f};
        zz = MFMA(qf[mi][0], fr[nb][0], zz);
        zz = MFMA(qf[mi][1], fr[nb][1], zz);
        bool msk = MASKED && (kb + nb*16 + c >= cnt);
        #pragma unroll
        for (int r=0;r<4;++r) pv[mi][nb][r] = msk ? -1e30f : zz[r]*C2E;
      }
    // tile max per row + defer-max check
    float tm[2][4];
    bool need = false;
    #pragma unroll
    for (int mi=0;mi<2;++mi)
      #pragma unroll
      for (int r=0;r<4;++r){
        float v = fmaxf(fmaxf(pv[mi][0][r],pv[mi][1][r]), fmaxf(pv[mi][2][r],pv[mi][3][r]));
        v = fmaxf(v, __shfl_xor(v,1)); v = fmaxf(v, __shfl_xor(v,2));
        v = fmaxf(v, __shfl_xor(v,4)); v = fmaxf(v, __shfl_xor(v,8));
        tm[mi][r] = v;
        need = need || (v > m_[mi][r] + THR2);
      }
    if (__any(need)){
      #pragma unroll
      for (int mi=0;mi<2;++mi)
        #pragma unroll
        for (int r=0;r<4;++r){
          float nm = fmaxf(m_[mi][r], tm[mi][r]);
          float scl = fexp2(m_[mi][r] - nm);
          m_[mi][r] = nm;
          lp[mi][r] *= scl;
          #pragma unroll
          for (int nbd=0;nbd<4;++nbd) o[mi][nbd][r] *= scl;
        }
    }
    // exp2 + per-thread partial denominator
    #pragma unroll
    for (int mi=0;mi<2;++mi)
      #pragma unroll
      for (int r=0;r<4;++r){
        float acc2 = lp[mi][r];
        #pragma unroll
        for (int nb=0;nb<4;++nb){
          float e = fexp2(pv[mi][nb][r] - m_[mi][r]);
          pv[mi][nb][r] = e; acc2 += e;
        }
        lp[mi][r] = acc2;
      }
    // V fragments + PV
    short8 fv[4][2];
    #pragma unroll
    for (int nbd=0;nbd<4;++nbd)
      #pragma unroll
      for (int kh=0;kh<2;++kh)
        fv[nbd][kh] = *(const short8*)&Vs[buf][(nbd*16+c)*64 + (((kh<<2)|g) ^ (c&7))*8];
    #pragma unroll
    for (int mi=0;mi<2;++mi){
      #pragma unroll
      for (int nb=0;nb<4;++nb)
        #pragma unroll
        for (int r=0;r<4;++r) P[w][g*4+r][nb*16+c] = ftou16(pv[mi][nb][r]);
      short8 pa0 = *(const short8*)&P[w][c][g*8];
      short8 pa1 = *(const short8*)&P[w][c][32 + g*8];
      #pragma unroll
      for (int nbd=0;nbd<4;++nbd){
        o[mi][nbd] = MFMA(pa0, fv[nbd][0], o[mi][nbd]);
        o[mi][nbd] = MFMA(pa1, fv[nbd][1], o[mi][nbd]);
      }
    }
    if (t < nt-2) vwait<4>(); else vwait<0>();
    wgbar();
    ++buf; if (buf==3) buf=0;
  }
  // final: one cross-lane l reduction + reciprocal per row
  float linv[2][4];
  #pragma unroll
  for (int mi=0;mi<2;++mi)
    #pragma unroll
    for (int r=0;r<4;++r){
      float lf = lp[mi][r];
      lf += __shfl_xor(lf,1); lf += __shfl_xor(lf,2);
      lf += __shfl_xor(lf,4); lf += __shfl_xor(lf,8);
      linv[mi][r] = 1.f/lf;
    }
  #pragma unroll
  for (int mi=0;mi<2;++mi)
    #pragma unroll
    for (int nbd=0;nbd<4;++nbd)
      #pragma unroll
      for (int r=0;r<4;++r)
        O[((size_t)(b*KCAP + q0 + mi*16 + g*4 + r))*D_ + h*DH_ + nbd*16 + c] = ftou16(o[mi][nbd][r] * linv[mi][r]);
}

// ---------------- final scatter: SOC rows only, from out1 (= x final, f32) ----------------
__global__ __launch_bounds__(256) void scatter_soc_k(const int* __restrict__ pos,
                                                     const float* __restrict__ out1,
                                                     float* __restrict__ out0){
  int base = blockIdx.x*4; int tid = threadIdx.x;
  #pragma unroll
  for (int r2=0;r2<4;++r2){
    int bs = base + r2;
    int p = pos[bs];
    if (p < 0) continue;
    int pc = p < KCAP ? p : (KCAP-1);
    int b = bs >> 12;
    const float* xr = out1 + ((size_t)(b*KCAP + pc))*D_;
    float* orow = out0 + (size_t)bs*D_;
    orow[tid]     = xr[tid];
    orow[tid+256] = xr[tid+256];
    orow[tid+512] = xr[tid+512];
  }
}

extern "C" void kernel_launch(void* const* d_in, const int* in_sizes, int n_in,
                              void* d_out, int out_size, void* d_ws, size_t ws_size,
                              hipStream_t stream){
  const float* img  = (const float*)d_in[0];
  const float* hid  = (const float*)d_in[1];
  const int*   seq  = (const int*)  d_in[2];
  const float* W[10] = { (const float*)d_in[3], (const float*)d_in[4], (const float*)d_in[5], (const float*)d_in[6],
                         (const float*)d_in[7], (const float*)d_in[8], (const float*)d_in[9], (const float*)d_in[10],
                         (const float*)d_in[11], (const float*)d_in[12] };
  const float* ln1s = (const float*)d_in[13];
  const float* ln1b = (const float*)d_in[14];
  const float* ln2s = (const float*)d_in[15];
  const float* ln2b = (const float*)d_in[16];
  const float* ln3s = (const float*)d_in[17];
  const float* ln3b = (const float*)d_in[18];

  char* ws = (char*)d_ws;
  int*   pos    = (int*)  (ws + 0);
  int*   src    = (int*)  (ws + 131072);
  int*   counts = (int*)  (ws + 151552);
  float* X      = (float*)(ws + 151808);
  u16*   T0     = (u16*)  (ws + 15880448);
  u16*   Qb     = (u16*)  (ws + 23744768);
  u16*   Kb     = (u16*)  (ws + 31609088);
  u16*   VtS    = (u16*)  (ws + 39473408);
  u16*   KbC    = (u16*)  (ws + 47337728);
  u16*   VtC    = (u16*)  (ws + 59920640);
  u16*   AO     = (u16*)  (ws + 72503552);
  u16*   Wt     = (u16*)  (ws + 80367872);
  u16*   MID    = Qb;

  u16* wqkv_st = Wt + 0ull*589824;
  u16* wo_st   = Wt + 3ull*589824;
  u16* wq_ct   = Wt + 4ull*589824;
  u16* wkv_ct  = Wt + 5ull*589824;
  u16* wo_ct   = Wt + 7ull*589824;
  u16* wff1t   = Wt + 8ull*589824;
  u16* wff2t   = wff1t + 2359296;

  float* out0 = (float*)d_out;
  float* out1 = out0 + (size_t)B_*S_*D_;
  u16* imgB = (u16*)out1;   // scratch in out1 region; FF2 rewrites out1 fully

  TransArgs ta;
  for (int i=0;i<10;++i) ta.w[i] = W[i];
  for (int i=0;i<8;++i)  ta.o[i] = Wt + (size_t)i*589824;
  ta.o[8] = wff1t; ta.o[9] = wff2t;

  transpose_scan_k<<<12296, 256, 0, stream>>>(ta, seq, pos, src, counts, img, imgB);
  prep_k<<<13312, 256, 0, stream>>>(hid, src, counts, pos, ln1s, ln1b, X, T0, out0);

  const int G_MEGA1 = 720 + 768;             // 1488
  const int G_N768  = (5120/64)*(768/128);   // 480
  const int G_FF1   = (5120/128)*(3072/128); // 960
  const int G_ATT   = B_*H_*5;               // 480

  // ---- self-attention block (+ independent img KV projection fused) ----
  mega1_k<<<G_MEGA1, 256, 0, stream>>>(T0, wqkv_st, Qb, Kb, VtS, imgB, wkv_ct, KbC, VtC);
  attn_k<1><<<G_ATT, 256, 0, stream>>>(Qb, Kb, VtS, AO, counts, KCAP);
  gemm_k<1,64,u16><<<G_N768, 256, 0, stream>>>(AO, wo_st, X, nullptr, nullptr, 768, 768);

  // ---- cross-attention block ----
  ln_k<<<5120, 256, 0, stream>>>(X, T0, ln2s, ln2b);
  gemm_k<0,64,u16><<<G_N768, 256, 0, stream>>>(T0, wq_ct, Qb, nullptr, nullptr, 768, 768);
  attn_k<0><<<G_ATT, 256, 0, stream>>>(Qb, KbC, VtC, AO, counts, N_);
  gemm_k<1,64,u16><<<G_N768, 256, 0, stream>>>(AO, wo_ct, X, nullptr, nullptr, 768, 768);

  // ---- FFN block (FF2 writes out1 = X + ff2) ----
  ln_k<<<5120, 256, 0, stream>>>(X, T0, ln3s, ln3b);
  gemm_k<2,128,u16><<<G_FF1, 256, 0, stream>>>(T0, wff1t, MID, nullptr, nullptr, 3072, 768);
  gemm_k<6,64,u16><<<G_N768, 256, 0, stream>>>(MID, wff2t, X, out1, nullptr, 768, 3072);

  // ---- final: SOC rows of out0 from out1 ----
  scatter_soc_k<<<8192, 256, 0, stream>>>(pos, out1, out0);
}

// Round 15
// 392.438 us; speedup vs baseline: 6.6548x; 1.0000x over previous
//
#include <hip/hip_runtime.h>
#include <hip/hip_bf16.h>

// Fetcher: SOC extraction -> [self-attn + cross-attn(img) + GELU-FFN] -> scatter-back.
// Round 15: wave-per-row LN (1280 blocks), s_setprio around attn MFMA clusters (T5),
//           GELU exp2-constant fold. Everything else = round-14 (392us baseline).

#define B_    8
#define S_    4096
#define D_    768
#define N_    1024
#define FF_   3072
#define H_    12
#define DH_   64
#define KCAP  640
#define SOC_TOK 3
#define EOS_TOK 2

typedef __hip_bfloat16 bf16;
typedef unsigned short u16;
typedef __attribute__((ext_vector_type(8))) short short8;
typedef __attribute__((ext_vector_type(4))) float f32x4;

__device__ __forceinline__ u16 ftou16(float x){ union{bf16 b; u16 s;} c; c.b = __float2bfloat16(x); return c.s; }
__device__ __forceinline__ unsigned pk2(float lo, float hi){ return (unsigned)ftou16(lo) | ((unsigned)ftou16(hi)<<16); }

__device__ __forceinline__ f32x4 MFMA(short8 a, short8 b, f32x4 c){
  return __builtin_amdgcn_mfma_f32_16x16x32_bf16(a, b, c, 0, 0, 0);
}

__device__ __forceinline__ void gld16(const void* gp, void* lp){
  __builtin_amdgcn_global_load_lds(
    reinterpret_cast<const __attribute__((address_space(1))) unsigned int*>((size_t)gp),
    reinterpret_cast<__attribute__((address_space(3))) unsigned int*>((size_t)lp),
    16, 0, 0);
}

template<int N> __device__ __forceinline__ void vwait(){
  asm volatile("s_waitcnt vmcnt(%0)" :: "i"(N) : "memory");
}
__device__ __forceinline__ void wgbar(){ asm volatile("s_barrier" ::: "memory"); }

// v_exp_f32 computes 2^x natively
__device__ __forceinline__ float fexp2(float x){ float r; asm("v_exp_f32 %0, %1" : "=v"(r) : "v"(x)); return r; }

__device__ __forceinline__ int xcd_swz(){
  int id = blockIdx.x;
  return (id & 7) * ((int)gridDim.x >> 3) + (id >> 3);
}

// ---------------- scan body ----------------
__device__ void scan_body(const int* __restrict__ seq, int* __restrict__ pos,
                          int* __restrict__ src, int* __restrict__ counts, int b){
  int tid = threadIdx.x;
  __shared__ int sd[256];
  __shared__ int carryE, carryS;
  if (tid==0){ carryE=0; carryS=0; }
  __syncthreads();
  for (int c=0; c<S_; c+=256){
    int s   = c + tid;
    int tok = seq[b*S_ + s];
    int isE = (tok==EOS_TOK) ? 1 : 0;
    int isS = (tok==SOC_TOK) ? 1 : 0;
    sd[tid]=isE; __syncthreads();
    for (int off=1; off<256; off<<=1){ int t_=(tid>=off)?sd[tid-off]:0; __syncthreads(); sd[tid]+=t_; __syncthreads(); }
    int eIncl = sd[tid];
    int eTot  = sd[255];
    int valid = (isS && (carryE + eIncl)==0) ? 1 : 0;
    __syncthreads();
    sd[tid]=valid; __syncthreads();
    for (int off=1; off<256; off<<=1){ int t_=(tid>=off)?sd[tid-off]:0; __syncthreads(); sd[tid]+=t_; __syncthreads(); }
    int vIncl = sd[tid];
    int vTot  = sd[255];
    if (valid){
      int slot = carryS + vIncl - 1;
      pos[b*S_ + s] = slot;
      if (slot < KCAP) src[b*KCAP + slot] = s;
    } else {
      pos[b*S_ + s] = -1;
    }
    __syncthreads();
    if (tid==0){ carryE += eTot; carryS += vTot; }
    __syncthreads();
  }
  if (tid==0) counts[b] = (carryS < KCAP) ? carryS : KCAP;
}

// ---------------- transpose + scan + img->bf16 convert, one launch ----------------
struct TransArgs { const float* w[10]; u16* o[10]; };
__global__ __launch_bounds__(256) void transpose_scan_k(TransArgs a, const int* __restrict__ seq,
                                                        int* __restrict__ pos, int* __restrict__ src,
                                                        int* __restrict__ counts,
                                                        const float* __restrict__ img, u16* __restrict__ imgB){
  int id = blockIdx.x;
  if (id >= 9224){
    int base = (id - 9224)*2048 + threadIdx.x*8;
    float4 a0 = *(const float4*)(img + base);
    float4 a1 = *(const float4*)(img + base + 4);
    uint4 wv;
    wv.x = pk2(a0.x,a0.y); wv.y = pk2(a0.z,a0.w); wv.z = pk2(a1.x,a1.y); wv.w = pk2(a1.z,a1.w);
    *(uint4*)(imgB + base) = wv;
    return;
  }
  if (id >= 9216){ scan_body(seq, pos, src, counts, id - 9216); return; }
  __shared__ float tile[32][33];
  int wi, t, K, N;
  if (id < 4608){ wi = id/576; t = id%576; K = 768; N = 768; }
  else if (id < 6912){ wi = 8; t = id-4608; K = 768; N = 3072; }
  else { wi = 9; t = id-6912; K = 3072; N = 768; }
  const float* in = a.w[wi]; u16* out = a.o[wi];
  int nbx = N >> 5;
  int bx = t % nbx, by = t / nbx;
  int tx = threadIdx.x & 31, ty = threadIdx.x >> 5;
  #pragma unroll
  for (int i=0;i<4;++i)
    tile[ty + i*8][tx] = in[(size_t)(by*32 + ty + i*8)*N + bx*32 + tx];
  __syncthreads();
  #pragma unroll
  for (int i=0;i<4;++i)
    out[(size_t)(bx*32 + ty + i*8)*K + by*32 + tx] = ftou16(tile[tx][ty + i*8]);
}

// ---------------- prep: gather+LN1 (blocks 0..5119) + hid-copy of non-SOC rows ----------------
__global__ __launch_bounds__(256) void prep_k(const float* __restrict__ hid,
                                              const int* __restrict__ src,
                                              const int* __restrict__ counts,
                                              const int* __restrict__ pos,
                                              const float* __restrict__ g, const float* __restrict__ bt,
                                              float* __restrict__ X, u16* __restrict__ T0,
                                              float* __restrict__ out0){
  int id = blockIdx.x; int tid = threadIdx.x;
  if (id >= 5120){
    int base = (id - 5120)*4;
    #pragma unroll
    for (int r2=0;r2<4;++r2){
      int bs = base + r2;
      if (pos[bs] >= 0) continue;
      const float* hr = hid + (size_t)bs*D_;
      float* orow = out0 + (size_t)bs*D_;
      orow[tid]     = hr[tid];
      orow[tid+256] = hr[tid+256];
      orow[tid+512] = hr[tid+512];
    }
    return;
  }
  int bk = id; int b = bk / KCAP; int k = bk % KCAP;
  float v0, v1, v2;
  if (k < counts[b]){
    const float* hr = hid + ((size_t)b*S_ + src[b*KCAP + k])*D_;
    v0 = hr[tid]; v1 = hr[tid+256]; v2 = hr[tid+512];
  } else { v0 = v1 = v2 = 0.f; }
  float* xr = X + (size_t)bk*D_;
  xr[tid] = v0; xr[tid+256] = v1; xr[tid+512] = v2;
  float s1=v0+v1+v2, s2=v0*v0+v1*v1+v2*v2;
  for (int off=32; off; off>>=1){ s1+=__shfl_xor(s1,off); s2+=__shfl_xor(s2,off); }
  __shared__ float red[8];
  __shared__ float mu_s, rs_s;
  int w=tid>>6, ln=tid&63;
  if (ln==0){ red[w]=s1; red[4+w]=s2; }
  __syncthreads();
  if (tid==0){
    float S1=red[0]+red[1]+red[2]+red[3];
    float S2=red[4]+red[5]+red[6]+red[7];
    float mu = S1*(1.f/D_);
    float var= S2*(1.f/D_) - mu*mu;
    mu_s=mu; rs_s=rsqrtf(var + 1e-5f);
  }
  __syncthreads();
  float mu=mu_s, rs=rs_s;
  u16* yr = T0 + (size_t)bk*D_;
  yr[tid]     = ftou16((v0-mu)*rs*g[tid]     + bt[tid]);
  yr[tid+256] = ftou16((v1-mu)*rs*g[tid+256] + bt[tid+256]);
  yr[tid+512] = ftou16((v2-mu)*rs*g[tid+512] + bt[tid+512]);
}

// ---------------- layernorm: wave-per-row (4 rows/block) ----------------
__global__ __launch_bounds__(256) void ln_k(const float* __restrict__ X, u16* __restrict__ Y,
                                            const float* __restrict__ g, const float* __restrict__ bt){
  int w = threadIdx.x>>6, l = threadIdx.x&63;
  size_t r = (size_t)blockIdx.x*4 + w;
  const float* xr = X + r*D_;
  float4 v[3];
  #pragma unroll
  for (int i=0;i<3;++i) v[i] = *(const float4*)(xr + (l + 64*i)*4);
  float s1=0.f, s2=0.f;
  #pragma unroll
  for (int i=0;i<3;++i){
    s1 += v[i].x + v[i].y + v[i].z + v[i].w;
    s2 += v[i].x*v[i].x + v[i].y*v[i].y + v[i].z*v[i].z + v[i].w*v[i].w;
  }
  #pragma unroll
  for (int off=32; off; off>>=1){ s1+=__shfl_xor(s1,off); s2+=__shfl_xor(s2,off); }
  float mu = s1*(1.f/D_);
  float rs = rsqrtf(s2*(1.f/D_) - mu*mu + 1e-5f);
  u16* yr = Y + r*D_;
  #pragma unroll
  for (int i=0;i<3;++i){
    float4 gv = *(const float4*)(g  + (l + 64*i)*4);
    float4 bv = *(const float4*)(bt + (l + 64*i)*4);
    ushort4 o;
    o.x = ftou16((v[i].x-mu)*rs*gv.x + bv.x);
    o.y = ftou16((v[i].y-mu)*rs*gv.y + bv.y);
    o.z = ftou16((v[i].z-mu)*rs*gv.z + bv.z);
    o.w = ftou16((v[i].w-mu)*rs*gv.w + bv.w);
    *(ushort4*)(yr + (l + 64*i)*4) = o;
  }
}

// ---------------- MFMA GEMM body ----------------
// MODE 0: C0_bf16 ; 1: C0_f32 += ; 2: C0_bf16 = gelu ; 6: C1_f32 = C0_f32 + result (C0 read-only)
// MODE 4: self QKV (N=2304): Q->C0, K->C1, V^T->C2 [b][768][KCAP]  (V writes ushort4-packed)
// MODE 5: cross KV (N=1536): K->C0, V^T->C2 [b][768][1024]         (V writes ushort4-packed)
template<int MODE, int BM, typename TA>
__device__ __forceinline__ void gemm_body(char* ldsp, const TA* __restrict__ A, const u16* __restrict__ Bt,
                                          void* __restrict__ C0, void* __restrict__ C1, void* __restrict__ C2,
                                          int wgid, int N, int K){
  constexpr int MI   = BM/32;
  constexpr int NBUF = (BM==128) ? 2 : ((sizeof(TA)==4) ? 2 : 3);
  u16* As = (u16*)ldsp;
  u16* Bs = (u16*)(ldsp + NBUF*(BM*32)*2);
  int nbx = N >> 7;
  int bx = wgid % nbx, by = wgid / nbx;
  int tid = threadIdx.x;
  int w = tid>>6, l = tid&63, g = l>>4, c = l&15;
  int wr = w&1, wc = w>>1;
  f32x4 acc[MI][4] = {};
  float4 rg[4];
  const int NK = K/32;

  auto STAGEB = [&](int buf, int kt){
    #pragma unroll
    for (int p=0;p<2;++p){
      int row = w*32 + p*16 + (l>>2);
      int su  = (l&3) ^ ((row>>1)&3);
      gld16((const void*)(Bt + (size_t)(bx*128+row)*K + kt + su*8), (void*)&Bs[buf*128*32 + (w*32+p*16)*32]);
    }
  };
  auto STAGEA16 = [&](int buf, int kt){
    if constexpr (BM==128){
      #pragma unroll
      for (int p=0;p<2;++p){
        int row = w*32 + p*16 + (l>>2);
        int su  = (l&3) ^ ((row>>1)&3);
        gld16((const void*)((const u16*)A + (size_t)(by*BM+row)*K + kt + su*8), (void*)&As[buf*BM*32 + (w*32+p*16)*32]);
      }
    } else {
      int row = w*16 + (l>>2);
      int su  = (l&3) ^ ((row>>1)&3);
      gld16((const void*)((const u16*)A + (size_t)(by*BM+row)*K + kt + su*8), (void*)&As[buf*BM*32 + (w*16)*32]);
    }
  };
  auto LOADREG = [&](int kt){
    if constexpr (BM==128){
      const float* ap = (const float*)A + (size_t)(by*BM + (tid>>1))*K + kt + (tid&1)*16;
      rg[0]=*(const float4*)ap;     rg[1]=*(const float4*)(ap+4);
      rg[2]=*(const float4*)(ap+8); rg[3]=*(const float4*)(ap+12);
    } else {
      const float* ap = (const float*)A + (size_t)(by*BM + (tid>>2))*K + kt + (tid&3)*8;
      rg[0] = *(const float4*)ap; rg[1] = *(const float4*)(ap+4);
    }
  };
  auto WRITEA = [&](int buf){
    if constexpr (BM==128){
      int row = tid>>1, half = tid&1;
      uint4 w0,w1;
      w0.x=pk2(rg[0].x,rg[0].y); w0.y=pk2(rg[0].z,rg[0].w); w0.z=pk2(rg[1].x,rg[1].y); w0.w=pk2(rg[1].z,rg[1].w);
      w1.x=pk2(rg[2].x,rg[2].y); w1.y=pk2(rg[2].z,rg[2].w); w1.z=pk2(rg[3].x,rg[3].y); w1.w=pk2(rg[3].z,rg[3].w);
      int sw = (row>>1)&3;
      *(uint4*)&As[buf*BM*32 + row*32 + ((half*2  )^sw)*8] = w0;
      *(uint4*)&As[buf*BM*32 + row*32 + ((half*2+1)^sw)*8] = w1;
    } else {
      int row = tid>>2, unit = tid&3;
      uint4 wv;
      wv.x=pk2(rg[0].x,rg[0].y); wv.y=pk2(rg[0].z,rg[0].w); wv.z=pk2(rg[1].x,rg[1].y); wv.w=pk2(rg[1].z,rg[1].w);
      int sw = (row>>1)&3;
      *(uint4*)&As[buf*BM*32 + row*32 + (unit^sw)*8] = wv;
    }
  };
  auto COMPUTE = [&](int buf){
    short8 af[MI], bfr[4];
    #pragma unroll
    for (int mi=0;mi<MI;++mi){ int row = wr*(MI*16) + mi*16 + c; af[mi]  = *(const short8*)&As[buf*BM*32 + row*32 + (g^((row>>1)&3))*8]; }
    #pragma unroll
    for (int ni=0;ni<4;++ni){ int row = wc*64 + ni*16 + c;       bfr[ni] = *(const short8*)&Bs[buf*128*32 + row*32 + (g^((row>>1)&3))*8]; }
    #pragma unroll
    for (int mi=0;mi<MI;++mi)
      #pragma unroll
      for (int ni=0;ni<4;++ni) acc[mi][ni] = MFMA(af[mi], bfr[ni], acc[mi][ni]);
  };

  if constexpr (BM==128 || sizeof(TA)==4){
    if constexpr (sizeof(TA)==4){ LOADREG(0); STAGEB(0,0); WRITEA(0); }
    else { STAGEA16(0,0); STAGEB(0,0); }
    __syncthreads();
    int buf = 0;
    for (int t=0;t<NK;++t){
      int ktn = (t+1)*32;
      if constexpr (sizeof(TA)==4){
        if (t+1<NK){ LOADREG(ktn); STAGEB(buf^1, ktn); }
        COMPUTE(buf);
        if (t+1<NK) WRITEA(buf^1);
      } else {
        if (t+1<NK){ STAGEA16(buf^1, ktn); STAGEB(buf^1, ktn); }
        COMPUTE(buf);
      }
      __syncthreads();
      buf ^= 1;
    }
  } else {
    constexpr int LPS = 3;
    STAGEA16(0,0);  STAGEB(0,0);
    STAGEA16(1,32); STAGEB(1,32);
    vwait<LPS>();
    wgbar();
    int buf = 0;
    for (int t=0;t<NK;++t){
      if (t+2 < NK){
        int nb = buf+2; if (nb>=3) nb-=3;
        STAGEA16(nb,(t+2)*32); STAGEB(nb,(t+2)*32);
      }
      COMPUTE(buf);
      if (t < NK-2) vwait<LPS>(); else vwait<0>();
      wgbar();
      ++buf; if (buf==3) buf=0;
    }
  }

  int row0 = by*BM + wr*(MI*16), col0 = bx*128 + wc*64;
  #pragma unroll
  for (int mi=0;mi<MI;++mi)
    #pragma unroll
    for (int ni=0;ni<4;++ni){
      int rowb = row0 + mi*16 + g*4;
      int col  = col0 + ni*16 + c;
      if (MODE==4 && col >= 1536){
        int vv = col - 1536; int bb = rowb / KCAP; int key = rowb - bb*KCAP;
        ushort4 pk;
        pk.x = ftou16(acc[mi][ni][0]); pk.y = ftou16(acc[mi][ni][1]);
        pk.z = ftou16(acc[mi][ni][2]); pk.w = ftou16(acc[mi][ni][3]);
        *(ushort4*)&((u16*)C2)[((size_t)(bb*768 + vv))*KCAP + key] = pk;
      } else if (MODE==5 && col >= 768){
        int vv = col - 768; int bb = rowb >> 10; int key = rowb & 1023;
        ushort4 pk;
        pk.x = ftou16(acc[mi][ni][0]); pk.y = ftou16(acc[mi][ni][1]);
        pk.z = ftou16(acc[mi][ni][2]); pk.w = ftou16(acc[mi][ni][3]);
        *(ushort4*)&((u16*)C2)[((size_t)(bb*768 + vv))*1024 + key] = pk;
      } else {
        #pragma unroll
        for (int r=0;r<4;++r){
          int row = rowb + r;
          float v = acc[mi][ni][r];
          if (MODE==0){
            ((u16*)C0)[(size_t)row*N + col] = ftou16(v);
          } else if (MODE==1){
            ((float*)C0)[(size_t)row*N + col] += v;
          } else if (MODE==2){
            float z = v + 0.044715f*v*v*v;
            float e = fexp2(z * 2.3022082551f);   // == exp(1.59576912*z)
            float th = 1.f - 2.f/(e + 1.f);
            ((u16*)C0)[(size_t)row*N + col] = ftou16(0.5f*v*(1.f+th));
          } else if (MODE==6){
            size_t idx = (size_t)row*N + col;
            ((float*)C1)[idx] = ((const float*)C0)[idx] + v;
          } else if (MODE==4){
            if (col < 768)  ((u16*)C0)[(size_t)row*768 + col]       = ftou16(v);
            else            ((u16*)C1)[(size_t)row*768 + col - 768] = ftou16(v);
          } else { // MODE 5, col < 768
            ((u16*)C0)[(size_t)row*768 + col] = ftou16(v);
          }
        }
      }
    }
}

template<int MODE, int BM, typename TA>
__global__ __launch_bounds__(256) void gemm_k(const TA* __restrict__ A, const u16* __restrict__ Bt,
                                              void* __restrict__ C0, void* __restrict__ C1, void* __restrict__ C2,
                                              int N, int K){
  constexpr int NBUF = (BM==128) ? 2 : ((sizeof(TA)==4) ? 2 : 3);
  __shared__ __align__(16) char pool[NBUF*(BM+128)*32*2];
  gemm_body<MODE,BM,TA>(pool, A, Bt, C0, C1, C2, xcd_swz(), N, K);
}

// mega1: self QKV (720 blocks) + cross img KV (768 blocks), both BM=128 bf16-A, one dispatch
__global__ __launch_bounds__(256) void mega1_k(const u16* __restrict__ T0, const u16* __restrict__ wqkv_st,
                                               u16* __restrict__ Qb, u16* __restrict__ Kb, u16* __restrict__ VtS,
                                               const u16* __restrict__ imgB, const u16* __restrict__ wkv_ct,
                                               u16* __restrict__ KbC, u16* __restrict__ VtC){
  __shared__ __align__(16) char pool[2*(128+128)*32*2];
  int wgid = xcd_swz();   // grid = 1488
  if (wgid < 720) gemm_body<4,128,u16>(pool, T0,   wqkv_st, Qb,  Kb,      VtS, wgid,     2304, 768);
  else            gemm_body<5,128,u16>(pool, imgB, wkv_ct,  KbC, nullptr, VtC, wgid-720, 1536, 768);
}

// ---------------- MFMA flash attention: 128 q / block, exp2-domain deferred softmax + setprio ----------------
template<int MASKED>
__global__ __launch_bounds__(256) void attn_k(const u16* __restrict__ Q, const u16* __restrict__ Kb,
                                              const u16* __restrict__ Vt, u16* __restrict__ O,
                                              const int* __restrict__ counts, int Lk){
  constexpr float C2E  = 0.18033688011112043f;  // 0.125 * log2(e)
  constexpr float THR2 = 11.541560327111707f;   // 8 * log2(e)
  __shared__ __align__(16) u16 Ks[3][64*64];
  __shared__ __align__(16) u16 Vs[3][64*64];
  __shared__ __align__(16) u16 P[4][16][72];
  int tid = threadIdx.x;
  int w = tid>>6, l = tid&63, g = l>>4, c = l&15;
  int wgid = xcd_swz();
  int qc = wgid % 5;
  int bh = wgid / 5;
  int h = bh % H_, b = bh / H_;
  int q0 = qc*128 + w*32;
  int cnt = MASKED ? counts[b] : Lk;
  int nt = (cnt + 63) >> 6;

  short8 qf[2][2];
  #pragma unroll
  for (int mi=0;mi<2;++mi){
    const u16* Qrow = Q + ((size_t)(b*KCAP + q0 + mi*16 + c))*D_ + h*DH_;
    qf[mi][0] = *(const short8*)(Qrow + g*8);
    qf[mi][1] = *(const short8*)(Qrow + 32 + g*8);
  }

  int srow8 = (l>>3);
  int sunit = l&7;
  auto STAGE = [&](int buf, int kb){
    #pragma unroll
    for (int p=0;p<2;++p){
      int r0 = w*16 + p*8;
      int rowK = r0 + srow8;
      int su = sunit ^ (rowK&7);
      gld16((const void*)(Kb + ((size_t)(b*Lk + kb + rowK))*D_ + h*DH_ + su*8), (void*)&Ks[buf][r0*64]);
      gld16((const void*)(Vt + ((size_t)(b*D_ + h*DH_ + rowK))*Lk + kb + su*8), (void*)&Vs[buf][r0*64]);
    }
  };

  f32x4 o[2][4] = {};
  float m_[2][4], lp[2][4] = {};
  #pragma unroll
  for (int mi=0;mi<2;++mi)
    #pragma unroll
    for (int r=0;r<4;++r) m_[mi][r] = -1e30f;

  STAGE(0, 0);
  if (nt > 1){ STAGE(1, 64); vwait<4>(); } else { vwait<0>(); }
  wgbar();
  int buf = 0;
  for (int t=0; t<nt; ++t){
    int kb = t*64;
    if (t+2 < nt){
      int nb = buf+2; if (nb>=3) nb-=3;
      STAGE(nb, kb+128);
    }
    short8 fr[4][2];
    #pragma unroll
    for (int nb=0;nb<4;++nb)
      #pragma unroll
      for (int kh=0;kh<2;++kh)
        fr[nb][kh] = *(const short8*)&Ks[buf][(nb*16+c)*64 + (((kh<<2)|g) ^ (c&7))*8];
    // QK^T -> scores in log2 domain
    float pv[2][4][4];
    __builtin_amdgcn_s_setprio(1);
    #pragma unroll
    for (int mi=0;mi<2;++mi)
      #pragma unroll
      for (int nb=0;nb<4;++nb){
        f32x4 zz = {0.f,0.f,0.f,0.f};
        zz = MFMA(qf[mi][0], fr[nb][0], zz);
        zz = MFMA(qf[mi][1], fr[nb][1], zz);
        bool msk = MASKED && (kb + nb*16 + c >= cnt);
        #pragma unroll
        for (int r=0;r<4;++r) pv[mi][nb][r] = msk ? -1e30f : zz[r]*C2E;
      }
    __builtin_amdgcn_s_setprio(0);
    // tile max per row + defer-max check
    float tm[2][4];
    bool need = false;
    #pragma unroll
    for (int mi=0;mi<2;++mi)
      #pragma unroll
      for (int r=0;r<4;++r){
        float v = fmaxf(fmaxf(pv[mi][0][r],pv[mi][1][r]), fmaxf(pv[mi][2][r],pv[mi][3][r]));
        v = fmaxf(v, __shfl_xor(v,1)); v = fmaxf(v, __shfl_xor(v,2));
        v = fmaxf(v, __shfl_xor(v,4)); v = fmaxf(v, __shfl_xor(v,8));
        tm[mi][r] = v;
        need = need || (v > m_[mi][r] + THR2);
      }
    if (__any(need)){
      #pragma unroll
      for (int mi=0;mi<2;++mi)
        #pragma unroll
        for (int r=0;r<4;++r){
          float nm = fmaxf(m_[mi][r], tm[mi][r]);
          float scl = fexp2(m_[mi][r] - nm);
          m_[mi][r] = nm;
          lp[mi][r] *= scl;
          #pragma unroll
          for (int nbd=0;nbd<4;++nbd) o[mi][nbd][r] *= scl;
        }
    }
    // exp2 + per-thread partial denominator
    #pragma unroll
    for (int mi=0;mi<2;++mi)
      #pragma unroll
      for (int r=0;r<4;++r){
        float acc2 = lp[mi][r];
        #pragma unroll
        for (int nb=0;nb<4;++nb){
          float e = fexp2(pv[mi][nb][r] - m_[mi][r]);
          pv[mi][nb][r] = e; acc2 += e;
        }
        lp[mi][r] = acc2;
      }
    // V fragments + PV
    short8 fv[4][2];
    #pragma unroll
    for (int nbd=0;nbd<4;++nbd)
      #pragma unroll
      for (int kh=0;kh<2;++kh)
        fv[nbd][kh] = *(const short8*)&Vs[buf][(nbd*16+c)*64 + (((kh<<2)|g) ^ (c&7))*8];
    #pragma unroll
    for (int mi=0;mi<2;++mi){
      #pragma unroll
      for (int nb=0;nb<4;++nb)
        #pragma unroll
        for (int r=0;r<4;++r) P[w][g*4+r][nb*16+c] = ftou16(pv[mi][nb][r]);
      short8 pa0 = *(const short8*)&P[w][c][g*8];
      short8 pa1 = *(const short8*)&P[w][c][32 + g*8];
      __builtin_amdgcn_s_setprio(1);
      #pragma unroll
      for (int nbd=0;nbd<4;++nbd){
        o[mi][nbd] = MFMA(pa0, fv[nbd][0], o[mi][nbd]);
        o[mi][nbd] = MFMA(pa1, fv[nbd][1], o[mi][nbd]);
      }
      __builtin_amdgcn_s_setprio(0);
    }
    if (t < nt-2) vwait<4>(); else vwait<0>();
    wgbar();
    ++buf; if (buf==3) buf=0;
  }
  // final: one cross-lane l reduction + reciprocal per row
  float linv[2][4];
  #pragma unroll
  for (int mi=0;mi<2;++mi)
    #pragma unroll
    for (int r=0;r<4;++r){
      float lf = lp[mi][r];
      lf += __shfl_xor(lf,1); lf += __shfl_xor(lf,2);
      lf += __shfl_xor(lf,4); lf += __shfl_xor(lf,8);
      linv[mi][r] = 1.f/lf;
    }
  #pragma unroll
  for (int mi=0;mi<2;++mi)
    #pragma unroll
    for (int nbd=0;nbd<4;++nbd)
      #pragma unroll
      for (int r=0;r<4;++r)
        O[((size_t)(b*KCAP + q0 + mi*16 + g*4 + r))*D_ + h*DH_ + nbd*16 + c] = ftou16(o[mi][nbd][r] * linv[mi][r]);
}

// ---------------- final scatter: SOC rows only, from out1 (= x final, f32) ----------------
__global__ __launch_bounds__(256) void scatter_soc_k(const int* __restrict__ pos,
                                                     const float* __restrict__ out1,
                                                     float* __restrict__ out0){
  int base = blockIdx.x*4; int tid = threadIdx.x;
  #pragma unroll
  for (int r2=0;r2<4;++r2){
    int bs = base + r2;
    int p = pos[bs];
    if (p < 0) continue;
    int pc = p < KCAP ? p : (KCAP-1);
    int b = bs >> 12;
    const float* xr = out1 + ((size_t)(b*KCAP + pc))*D_;
    float* orow = out0 + (size_t)bs*D_;
    orow[tid]     = xr[tid];
    orow[tid+256] = xr[tid+256];
    orow[tid+512] = xr[tid+512];
  }
}

extern "C" void kernel_launch(void* const* d_in, const int* in_sizes, int n_in,
                              void* d_out, int out_size, void* d_ws, size_t ws_size,
                              hipStream_t stream){
  const float* img  = (const float*)d_in[0];
  const float* hid  = (const float*)d_in[1];
  const int*   seq  = (const int*)  d_in[2];
  const float* W[10] = { (const float*)d_in[3], (const float*)d_in[4], (const float*)d_in[5], (const float*)d_in[6],
                         (const float*)d_in[7], (const float*)d_in[8], (const float*)d_in[9], (const float*)d_in[10],
                         (const float*)d_in[11], (const float*)d_in[12] };
  const float* ln1s = (const float*)d_in[13];
  const float* ln1b = (const float*)d_in[14];
  const float* ln2s = (const float*)d_in[15];
  const float* ln2b = (const float*)d_in[16];
  const float* ln3s = (const float*)d_in[17];
  const float* ln3b = (const float*)d_in[18];

  char* ws = (char*)d_ws;
  int*   pos    = (int*)  (ws + 0);
  int*   src    = (int*)  (ws + 131072);
  int*   counts = (int*)  (ws + 151552);
  float* X      = (float*)(ws + 151808);
  u16*   T0     = (u16*)  (ws + 15880448);
  u16*   Qb     = (u16*)  (ws + 23744768);
  u16*   Kb     = (u16*)  (ws + 31609088);
  u16*   VtS    = (u16*)  (ws + 39473408);
  u16*   KbC    = (u16*)  (ws + 47337728);
  u16*   VtC    = (u16*)  (ws + 59920640);
  u16*   AO     = (u16*)  (ws + 72503552);
  u16*   Wt     = (u16*)  (ws + 80367872);
  u16*   MID    = Qb;

  u16* wqkv_st = Wt + 0ull*589824;
  u16* wo_st   = Wt + 3ull*589824;
  u16* wq_ct   = Wt + 4ull*589824;
  u16* wkv_ct  = Wt + 5ull*589824;
  u16* wo_ct   = Wt + 7ull*589824;
  u16* wff1t   = Wt + 8ull*589824;
  u16* wff2t   = wff1t + 2359296;

  float* out0 = (float*)d_out;
  float* out1 = out0 + (size_t)B_*S_*D_;
  u16* imgB = (u16*)out1;   // scratch in out1 region; FF2 rewrites out1 fully

  TransArgs ta;
  for (int i=0;i<10;++i) ta.w[i] = W[i];
  for (int i=0;i<8;++i)  ta.o[i] = Wt + (size_t)i*589824;
  ta.o[8] = wff1t; ta.o[9] = wff2t;

  transpose_scan_k<<<12296, 256, 0, stream>>>(ta, seq, pos, src, counts, img, imgB);
  prep_k<<<13312, 256, 0, stream>>>(hid, src, counts, pos, ln1s, ln1b, X, T0, out0);

  const int G_MEGA1 = 720 + 768;             // 1488
  const int G_N768  = (5120/64)*(768/128);   // 480
  const int G_FF1   = (5120/128)*(3072/128); // 960
  const int G_ATT   = B_*H_*5;               // 480
  const int G_LN    = 5120/4;                // 1280

  // ---- self-attention block (+ independent img KV projection fused) ----
  mega1_k<<<G_MEGA1, 256, 0, stream>>>(T0, wqkv_st, Qb, Kb, VtS, imgB, wkv_ct, KbC, VtC);
  attn_k<1><<<G_ATT, 256, 0, stream>>>(Qb, Kb, VtS, AO, counts, KCAP);
  gemm_k<1,64,u16><<<G_N768, 256, 0, stream>>>(AO, wo_st, X, nullptr, nullptr, 768, 768);

  // ---- cross-attention block ----
  ln_k<<<G_LN, 256, 0, stream>>>(X, T0, ln2s, ln2b);
  gemm_k<0,64,u16><<<G_N768, 256, 0, stream>>>(T0, wq_ct, Qb, nullptr, nullptr, 768, 768);
  attn_k<0><<<G_ATT, 256, 0, stream>>>(Qb, KbC, VtC, AO, counts, N_);
  gemm_k<1,64,u16><<<G_N768, 256, 0, stream>>>(AO, wo_ct, X, nullptr, nullptr, 768, 768);

  // ---- FFN block (FF2 writes out1 = X + ff2) ----
  ln_k<<<G_LN, 256, 0, stream>>>(X, T0, ln3s, ln3b);
  gemm_k<2,128,u16><<<G_FF1, 256, 0, stream>>>(T0, wff1t, MID, nullptr, nullptr, 3072, 768);
  gemm_k<6,64,u16><<<G_N768, 256, 0, stream>>>(MID, wff2t, X, out1, nullptr, 768, 3072);

  // ---- final: SOC rows of out0 from out1 ----
  scatter_soc_k<<<8192, 256, 0, stream>>>(pos, out1, out0);
}